// Round 10
// baseline (191.186 us; speedup 1.0000x reference)
//
#include <hip/hip_runtime.h>
#include <hip/hip_bf16.h>

#define HW 16384
#define NB 8
#define CIN 64

// snake tile geometry
#define WIN_R 18
#define WIN_C 26
#define CELLS (WIN_R * WIN_C)     // 468
#define CHUNKS (CELLS * 4)        // 1872 x 16B per ci-half
#define BUFB (CELLS * 64)         // 29952 bytes (one ci-half window)

typedef short short8 __attribute__((ext_vector_type(8)));
typedef float f32x4 __attribute__((ext_vector_type(4)));

// ---------------- ws layout (BYTE offsets) ----------------
#define XT_OFF   0
#define WRH_OFF  16777216
#define WOH_OFF  16924672
#define RAW_OFF  17000448
#define BNS_OFF  26437632
#define GNP_OFF  26439168
#define GNS_OFF  27487744

__device__ inline unsigned short f2b(float v) {
    __hip_bfloat16 h = __float2bfloat16(v);
    unsigned short u; __builtin_memcpy(&u, &h, 2);
    return u;
}
__device__ inline float bperm_f(int srclane, float v) {
    int r = __builtin_amdgcn_ds_bpermute(srclane << 2, __builtin_bit_cast(int, v));
    return __builtin_bit_cast(float, r);
}
__device__ inline int bperm_i(int srclane, int v) {
    return __builtin_amdgcn_ds_bpermute(srclane << 2, v);
}

// x [b][ci][px] f32  ->  xt2 [b][half][px][32ci] bf16
__global__ __launch_bounds__(256) void cvt_x(const float* __restrict__ x,
                                             unsigned short* __restrict__ xt2) {
    int blk = blockIdx.x;              // 512 = 8b * 64 tiles(256px)
    int b = blk >> 6;
    int px0 = (blk & 63) * 256;
    int t = threadIdx.x;
    __shared__ unsigned short lds[256][72];
    const float* xb = x + (size_t)b * CIN * HW + px0;
    for (int ci = 0; ci < 64; ++ci)
        lds[t][ci] = f2b(xb[ci * HW + t]);
    __syncthreads();
    int wv = t >> 6, l = t & 63;
    int chunk = l & 7;                 // 8 chunks of 8 ci
    int half = chunk >> 2, ci8 = chunk & 3;
    for (int it = 0; it < 8; ++it) {
        int row = it * 32 + wv * 8 + (l >> 3);
        short8 v = *(const short8*)&lds[row][chunk * 8];
        unsigned short* dst = xt2 + ((size_t)(b * 2 + half) * HW + px0 + row) * 32 + ci8 * 8;
        *(short8*)dst = v;
    }
}

__global__ __launch_bounds__(256) void repack_w(const float* __restrict__ w0,
                                                const float* __restrict__ w1,
                                                unsigned short* __restrict__ wrh) {
    int i = blockIdx.x * 256 + threadIdx.x;
    if (i >= 2 * 9 * 64 * 64) return;
    int ci = i & 63;
    int co = (i >> 6) & 63;
    int k  = (i >> 12) % 9;
    int br = i / 36864;
    const float* w = br ? w1 : w0;
    wrh[i] = f2b(w[(co * 64 + ci) * 9 + k]);
}

__global__ __launch_bounds__(256) void repack_wo(const float* __restrict__ w0,
                                                 const float* __restrict__ w1,
                                                 unsigned short* __restrict__ woh) {
    int i = blockIdx.x * 256 + threadIdx.x;
    if (i >= 32 * 9 * 64) return;
    int ci = i & 63;
    int tap = (i >> 6) % 9;
    int co = i / 576;
    float v = 0.f;
    if (co < 9)       v = w0[(co * 64 + ci) * 9 + tap];
    else if (co < 18) v = w1[(co * 64 + ci) * 9 + tap];
    woh[i] = f2b(v);
}

// offset 3x3 conv MFMA + fused BN partials. 1024 blocks x 256
__global__ __launch_bounds__(256, 4) void off_mfma(const unsigned short* __restrict__ xt2,
                                                   const unsigned short* __restrict__ woh,
                                                   float* __restrict__ off_raw,
                                                   float* __restrict__ bnp) {
    int b = blockIdx.x & 7;
    int tgrp = blockIdx.x >> 3;
    int t = threadIdx.x;
    int wid = t >> 6, l = t & 63;
    int tile = tgrp * 4 + wid;
    int l15 = l & 15, kg = l >> 4;
    int px0 = tile * 32;
    int h = px0 >> 7;
    int w0 = px0 & 127;

    f32x4 acc[2][2];
#pragma unroll
    for (int m = 0; m < 2; ++m)
#pragma unroll
        for (int nn = 0; nn < 2; ++nn) acc[m][nn] = (f32x4)(0.f);

#pragma unroll
    for (int s = 0; s < 18; ++s) {
        const int tap = s >> 1, half = s & 1;
        const int dy = tap / 3 - 1, dx = tap % 3 - 1;
        const unsigned short* plane = xt2 + (size_t)(b * 2 + half) * HW * 32;
        int y = h + dy;
        bool yok = (unsigned)y < 128u;
        int yc = min(max(y, 0), 127);
        short8 af[2];
#pragma unroll
        for (int m = 0; m < 2; ++m) {
            int xx = w0 + m * 16 + l15 + dx;
            bool ok = yok && ((unsigned)xx < 128u);
            int xc = min(max(xx, 0), 127);
            int o = yc * 128 + xc;
            short8 a = *(const short8*)&plane[(size_t)o * 32 + kg * 8];
            if (!ok) a = (short8)(0);
            af[m] = a;
        }
        short8 bf[2];
#pragma unroll
        for (int nn = 0; nn < 2; ++nn)
            bf[nn] = *(const short8*)&woh[((nn * 16 + l15) * 9 + tap) * 64 + half * 32 + kg * 8];
#pragma unroll
        for (int m = 0; m < 2; ++m)
#pragma unroll
            for (int nn = 0; nn < 2; ++nn)
                acc[m][nn] = __builtin_amdgcn_mfma_f32_16x16x32_bf16(af[m], bf[nn], acc[m][nn], 0, 0, 0);
    }

    float s1[2] = {0.f, 0.f}, s2[2] = {0.f, 0.f};
#pragma unroll
    for (int m = 0; m < 2; ++m)
#pragma unroll
        for (int nn = 0; nn < 2; ++nn) {
            int co = nn * 16 + l15;
            f32x4 v = acc[m][nn];
            s1[nn] += v.x + v.y + v.z + v.w;
            s2[nn] += v.x * v.x + v.y * v.y + v.z * v.z + v.w * v.w;
            if (co < 18) {
                int br = co < 9 ? 0 : 1;
                int k = co - br * 9;
                int plane = (br * 8 + b) * 9 + k;
                int px = px0 + m * 16 + kg * 4;
                *(f32x4*)&off_raw[(size_t)plane * HW + px] = v;
            }
        }
#pragma unroll
    for (int off = 16; off <= 32; off <<= 1)
#pragma unroll
        for (int nn = 0; nn < 2; ++nn) {
            s1[nn] += __shfl_xor(s1[nn], off);
            s2[nn] += __shfl_xor(s2[nn], off);
        }
    if (l < 16) {
        int idx = ((l15 * 8 + b) * 512 + tile) * 2;
        bnp[idx] = s1[0]; bnp[idx + 1] = s2[0];
        if (l15 < 2) {
            int idx2 = (((16 + l15) * 8 + b) * 512 + tile) * 2;
            bnp[idx2] = s1[1]; bnp[idx2 + 1] = s2[1];
        }
    }
}

__device__ inline void block_reduce2(float& s1, float& s2) {
    __shared__ float sh[4][2];
#pragma unroll
    for (int o = 32; o > 0; o >>= 1) {
        s1 += __shfl_down(s1, o);
        s2 += __shfl_down(s2, o);
    }
    int wid = threadIdx.x >> 6, lane = threadIdx.x & 63;
    if (lane == 0) { sh[wid][0] = s1; sh[wid][1] = s2; }
    __syncthreads();
    if (threadIdx.x == 0)
        for (int i = 1; i < 4; ++i) { s1 += sh[i][0]; s2 += sh[i][1]; }
}

__global__ __launch_bounds__(256) void bn_fin2(const float* __restrict__ bnp,
                                               float* __restrict__ bn_stat) {
    int c = blockIdx.x;
    float s1 = 0.f, s2 = 0.f;
    for (int i = threadIdx.x; i < 4096; i += 256) {
        s1 += bnp[(c * 4096 + i) * 2];
        s2 += bnp[(c * 4096 + i) * 2 + 1];
    }
    block_reduce2(s1, s2);
    if (threadIdx.x == 0) {
        const float N = 8.f * 16384.f;
        float m = s1 / N;
        float var = s2 / N - m * m;
        bn_stat[c * 2] = m;
        bn_stat[c * 2 + 1] = rsqrtf(var + 1e-5f);
    }
}

// ---------------- snake conv: hoisted-descriptor, fully-unrolled MFMA ----------
// 2048 blocks x 256 thr (4 waves). b=n&7 (XCD-pinned), br=(n>>3)>>7,
// tile=(n>>3)&127 -> 8h x 16w pixel tile. Both 30KB ci-half windows resident.
// R9: all 18 cm-bpermutes hoisted to a pre-pass; k-loop fully unrolled so the
// 8 ds_reads + 8 w-loads of each k issue together and overlap MFMAs of k-1.
__global__ __launch_bounds__(256) void snake5(const unsigned short* __restrict__ xt2,
                                              const unsigned short* __restrict__ wrh,
                                              const float* __restrict__ cb0,
                                              const float* __restrict__ cb1,
                                              const float* __restrict__ off_raw,
                                              const float* __restrict__ bn_stat,
                                              const float* __restrict__ bng0,
                                              const float* __restrict__ bnb0,
                                              const float* __restrict__ bng1,
                                              const float* __restrict__ bnb1,
                                              float* __restrict__ out,
                                              float* __restrict__ gnp) {
    __shared__ __align__(16) unsigned char winbuf[2][BUFB];

    int n = blockIdx.x;
    int b = n & 7;
    int rest = n >> 3;
    int br = rest >> 7;
    int tile = rest & 127;
    int h0 = (tile >> 3) * 8;
    int w0 = (tile & 7) * 16;
    int t = threadIdx.x;
    int wv = t >> 6, l = t & 63;
    int l15 = l & 15, kg = l >> 4;
    int lp = l & 31;                   // own pixel (lanes 32-63 duplicate)

    int hrow = h0 + 2 * wv + (lp >> 4);
    int wcol = w0 + (lp & 15);
    int pxo = hrow * 128 + wcol;
    const float* bng = br ? bng1 : bng0;
    const float* bnb = br ? bnb1 : bnb0;

    // ---- stage both ci-half windows (async, swizzled source) ----
#pragma unroll
    for (int half = 0; half < 2; ++half) {
        const unsigned short* plane = xt2 + (size_t)(b * 2 + half) * HW * 32;
#pragma unroll
        for (int it = 0; it < 8; ++it) {
            int d = it * 256 + wv * 64 + l;
            if (d < CHUNKS) {
                int cell = d >> 2;
                int ci8 = (d & 3) ^ (cell & 3);      // inverse swizzle on source
                int s = cell / WIN_C;
                int c = cell - s * WIN_C;
                int row = min(max(h0 - 5 + s, 0), 127);
                int col = min(max(w0 - 5 + c, 0), 127);
                const unsigned short* src = plane + ((size_t)(row * 128 + col)) * 32 + ci8 * 8;
                __builtin_amdgcn_global_load_lds(
                    (const __attribute__((address_space(1))) unsigned int*)src,
                    (__attribute__((address_space(3))) unsigned int*)(&winbuf[half][0] + (it * 256 + wv * 64) * 16),
                    16, 0, 0);
            }
        }
    }

    // ---- prologue: own-pixel cumulative offsets (global reads; pre-barrier) ----
    float cum[9];
    {
        float tt[9];
#pragma unroll
        for (int k = 0; k < 9; ++k) {
            float raw = off_raw[(size_t)((br * 8 + b) * 9 + k) * HW + pxo];
            float mn = bn_stat[(br * 9 + k) * 2];
            float rs = bn_stat[(br * 9 + k) * 2 + 1];
            int ch = br ? k + 9 : k;
            tt[k] = tanhf((raw - mn) * rs * bng[ch] + bnb[ch]);
        }
        cum[4] = 0.f;
        cum[3] = tt[3]; cum[2] = tt[2] + cum[3]; cum[1] = tt[1] + cum[2]; cum[0] = tt[0] + cum[1];
        cum[5] = tt[5]; cum[6] = cum[5] + tt[6]; cum[7] = cum[6] + tt[7]; cum[8] = cum[7] + tt[8];
    }

    __syncthreads();   // staging complete (compiler drains vmcnt before barrier)

    // ---- descriptor pre-pass: all cm bpermutes hoisted (27 regs) ----
    int cm0a[9], cm1a[9];
    float fwa[9];
#pragma unroll
    for (int k = 0; k < 9; ++k) {
        int cell0, cell1; float fw;
        if (br == 0) {
            int col = min(max(wcol + k - 4, 0), 127);
            float yc = fminf(fmaxf((float)hrow + cum[k], 0.f), 127.f);
            int y0 = (int)floorf(yc);
            int y1 = min(y0 + 1, 127);
            fw = yc - (float)y0;
            int cs = col - (w0 - 5);
            cell0 = (y0 - (h0 - 5)) * WIN_C + cs;
            cell1 = (y1 - (h0 - 5)) * WIN_C + cs;
        } else {
            int row = min(max(hrow + k - 4, 0), 127);
            float xcf = fminf(fmaxf((float)wcol + cum[k], 0.f), 127.f);
            int x0 = (int)floorf(xcf);
            int x1 = min(x0 + 1, 127);
            fw = xcf - (float)x0;
            int rs = (row - (h0 - 5)) * WIN_C;
            cell0 = rs + (x0 - (w0 - 5));
            cell1 = rs + (x1 - (w0 - 5));
        }
        int cpk = cell0 | (cell1 << 16);
        cm0a[k] = bperm_i(l15, cpk);
        cm1a[k] = bperm_i(l15 + 16, cpk);
        fwa[k] = fw;
    }

    f32x4 acc00 = (f32x4)(0.f), acc01 = (f32x4)(0.f), acc02 = (f32x4)(0.f), acc03 = (f32x4)(0.f);
    f32x4 acc10 = (f32x4)(0.f), acc11 = (f32x4)(0.f), acc12 = (f32x4)(0.f), acc13 = (f32x4)(0.f);
    const f32x4 zero = (f32x4)(0.f);
    const f32x4 ones = (f32x4)(1.f);

#define BLND(ACC, A0, A1, BF, OMF, FVV)                                          \
    {                                                                            \
        f32x4 p0 = __builtin_amdgcn_mfma_f32_16x16x32_bf16(A0, BF, zero, 0, 0, 0); \
        f32x4 p1 = __builtin_amdgcn_mfma_f32_16x16x32_bf16(A1, BF, zero, 0, 0, 0); \
        ACC += OMF * p0;                                                         \
        ACC += FVV * p1;                                                         \
    }
#define K_STEP(K)                                                                \
    {                                                                            \
        int c00 = cm0a[K] & 0xffff, c01 = ((unsigned)cm0a[K]) >> 16;             \
        int c10 = cm1a[K] & 0xffff, c11 = ((unsigned)cm1a[K]) >> 16;             \
        const unsigned char* b0p = &winbuf[0][0];                                \
        const unsigned char* b1p = &winbuf[1][0];                                \
        short8 a00h0 = *(const short8*)(b0p + c00 * 64 + ((kg ^ (c00 & 3)) << 4)); \
        short8 a01h0 = *(const short8*)(b0p + c01 * 64 + ((kg ^ (c01 & 3)) << 4)); \
        short8 a10h0 = *(const short8*)(b0p + c10 * 64 + ((kg ^ (c10 & 3)) << 4)); \
        short8 a11h0 = *(const short8*)(b0p + c11 * 64 + ((kg ^ (c11 & 3)) << 4)); \
        short8 a00h1 = *(const short8*)(b1p + c00 * 64 + ((kg ^ (c00 & 3)) << 4)); \
        short8 a01h1 = *(const short8*)(b1p + c01 * 64 + ((kg ^ (c01 & 3)) << 4)); \
        short8 a10h1 = *(const short8*)(b1p + c10 * 64 + ((kg ^ (c10 & 3)) << 4)); \
        short8 a11h1 = *(const short8*)(b1p + c11 * 64 + ((kg ^ (c11 & 3)) << 4)); \
        float fw = fwa[K];                                                       \
        f32x4 fv0, fv1;                                                          \
        _Pragma("unroll")                                                        \
        for (int j = 0; j < 4; ++j) {                                            \
            fv0[j] = bperm_f(kg * 4 + j, fw);                                    \
            fv1[j] = bperm_f(16 + kg * 4 + j, fw);                               \
        }                                                                        \
        f32x4 om0 = ones - fv0;                                                  \
        f32x4 om1 = ones - fv1;                                                  \
        const unsigned short* wk = wrh + (size_t)((br * 9 + (K)) * 64) * 64 + kg * 8; \
        short8 bf0h0 = *(const short8*)&wk[(0 * 16 + l15) * 64];                 \
        short8 bf1h0 = *(const short8*)&wk[(1 * 16 + l15) * 64];                 \
        short8 bf2h0 = *(const short8*)&wk[(2 * 16 + l15) * 64];                 \
        short8 bf3h0 = *(const short8*)&wk[(3 * 16 + l15) * 64];                 \
        short8 bf0h1 = *(const short8*)&wk[(0 * 16 + l15) * 64 + 32];            \
        short8 bf1h1 = *(const short8*)&wk[(1 * 16 + l15) * 64 + 32];            \
        short8 bf2h1 = *(const short8*)&wk[(2 * 16 + l15) * 64 + 32];            \
        short8 bf3h1 = *(const short8*)&wk[(3 * 16 + l15) * 64 + 32];            \
        BLND(acc00, a00h0, a01h0, bf0h0, om0, fv0)                               \
        BLND(acc01, a00h0, a01h0, bf1h0, om0, fv0)                               \
        BLND(acc02, a00h0, a01h0, bf2h0, om0, fv0)                               \
        BLND(acc03, a00h0, a01h0, bf3h0, om0, fv0)                               \
        BLND(acc10, a10h0, a11h0, bf0h0, om1, fv1)                               \
        BLND(acc11, a10h0, a11h0, bf1h0, om1, fv1)                               \
        BLND(acc12, a10h0, a11h0, bf2h0, om1, fv1)                               \
        BLND(acc13, a10h0, a11h0, bf3h0, om1, fv1)                               \
        BLND(acc00, a00h1, a01h1, bf0h1, om0, fv0)                               \
        BLND(acc01, a00h1, a01h1, bf1h1, om0, fv0)                               \
        BLND(acc02, a00h1, a01h1, bf2h1, om0, fv0)                               \
        BLND(acc03, a00h1, a01h1, bf3h1, om0, fv0)                               \
        BLND(acc10, a10h1, a11h1, bf0h1, om1, fv1)                               \
        BLND(acc11, a10h1, a11h1, bf1h1, om1, fv1)                               \
        BLND(acc12, a10h1, a11h1, bf2h1, om1, fv1)                               \
        BLND(acc13, a10h1, a11h1, bf3h1, om1, fv1)                               \
    }

    K_STEP(0) K_STEP(1) K_STEP(2) K_STEP(3) K_STEP(4)
    K_STEP(5) K_STEP(6) K_STEP(7) K_STEP(8)
#undef K_STEP
#undef BLND

    // epilogue: bias, store, GN partials
    f32x4 accA[2][4] = {{acc00, acc01, acc02, acc03}, {acc10, acc11, acc12, acc13}};
    const float* cb = br ? cb1 : cb0;
    float s1[4], s2[4];
#pragma unroll
    for (int nn = 0; nn < 4; ++nn) { s1[nn] = 0.f; s2[nn] = 0.f; }
#pragma unroll
    for (int m = 0; m < 2; ++m) {
        int hm = h0 + 2 * wv + m;
#pragma unroll
        for (int nn = 0; nn < 4; ++nn) {
            int co = nn * 16 + l15;
            float bias = cb[co];
            f32x4 v = accA[m][nn];
            f32x4 r;
            r.x = v.x + bias; r.y = v.y + bias; r.z = v.z + bias; r.w = v.w + bias;
            s1[nn] += r.x + r.y + r.z + r.w;
            s2[nn] += r.x * r.x + r.y * r.y + r.z * r.z + r.w * r.w;
            size_t base = ((size_t)(b * 128 + br * 64 + co) << 14) + hm * 128 + w0 + kg * 4;
            *(f32x4*)&out[base] = r;
        }
    }
#pragma unroll
    for (int off = 16; off <= 32; off <<= 1)
#pragma unroll
        for (int nn = 0; nn < 4; ++nn) {
            s1[nn] += __shfl_xor(s1[nn], off);
            s2[nn] += __shfl_xor(s2[nn], off);
        }
#pragma unroll
    for (int off = 1; off <= 2; off <<= 1)
#pragma unroll
        for (int nn = 0; nn < 4; ++nn) {
            s1[nn] += __shfl_xor(s1[nn], off);
            s2[nn] += __shfl_xor(s2[nn], off);
        }
    if ((l & 0x33) == 0) {             // lanes 0,4,8,12
#pragma unroll
        for (int nn = 0; nn < 4; ++nn) {
            int g = nn * 4 + (l >> 2);
            size_t gi = ((size_t)((br * 8 + b) * 512 + tile * 4 + wv)) * 32 + g * 2;
            gnp[gi] = s1[nn];
            gnp[gi + 1] = s2[nn];
        }
    }
}

__global__ __launch_bounds__(256) void gn_reduce(const float* __restrict__ gnp,
                                                 float* __restrict__ gn_stat) {
    int sid = blockIdx.x;              // (br*8+b)*16+g
    int bb = sid >> 4;
    int g = sid & 15;
    float s1 = 0.f, s2 = 0.f;
    int t = threadIdx.x;
#pragma unroll
    for (int j = 0; j < 2; ++j) {
        size_t gi = ((size_t)(bb * 512 + t * 2 + j)) * 32 + g * 2;
        s1 += gnp[gi];
        s2 += gnp[gi + 1];
    }
    block_reduce2(s1, s2);
    if (t == 0) {
        const float N = 4.f * 16384.f;
        float m = s1 / N;
        float var = s2 / N - m * m;
        gn_stat[sid * 2] = m;
        gn_stat[sid * 2 + 1] = rsqrtf(var + 1e-5f);
    }
}

__global__ __launch_bounds__(256) void gn_apply(float* __restrict__ out,
                                                const float* __restrict__ gn_stat,
                                                const float* __restrict__ g0,
                                                const float* __restrict__ b0,
                                                const float* __restrict__ g1,
                                                const float* __restrict__ b1) {
    int i = blockIdx.x * 256 + threadIdx.x;
    size_t base = (size_t)i * 4;
    int c = (int)((base >> 14) & 127);
    int b = (int)(base >> 21);
    int br = c >> 6;
    int co = c & 63;
    int sid = (br * 8 + b) * 16 + (co >> 2);
    float m = gn_stat[sid * 2];
    float rs = gn_stat[sid * 2 + 1];
    const float* gg = br ? g1 : g0;
    const float* bb = br ? b1 : b0;
    float ga = gg[co] * rs, be = bb[co] - m * gg[co] * rs;
    f32x4 v = *(f32x4*)&out[base];
    f32x4 r;
    r.x = fmaxf(fmaf(v.x, ga, be), 0.f);
    r.y = fmaxf(fmaf(v.y, ga, be), 0.f);
    r.z = fmaxf(fmaf(v.z, ga, be), 0.f);
    r.w = fmaxf(fmaf(v.w, ga, be), 0.f);
    *(f32x4*)&out[base] = r;
}

extern "C" void kernel_launch(void* const* d_in, const int* in_sizes, int n_in,
                              void* d_out, int out_size, void* d_ws, size_t ws_size,
                              hipStream_t stream) {
    const float* x       = (const float*)d_in[0];
    const float* off_w0  = (const float*)d_in[1];
    const float* bn_g0   = (const float*)d_in[3];
    const float* bn_b0   = (const float*)d_in[4];
    const float* conv_w0 = (const float*)d_in[5];
    const float* conv_b0 = (const float*)d_in[6];
    const float* gn_g0   = (const float*)d_in[7];
    const float* gn_b0   = (const float*)d_in[8];
    const float* off_w1  = (const float*)d_in[9];
    const float* bn_g1   = (const float*)d_in[11];
    const float* bn_b1   = (const float*)d_in[12];
    const float* conv_w1 = (const float*)d_in[13];
    const float* conv_b1 = (const float*)d_in[14];
    const float* gn_g1   = (const float*)d_in[15];
    const float* gn_b1   = (const float*)d_in[16];

    char* ws = (char*)d_ws;
    unsigned short* xt2 = (unsigned short*)(ws + XT_OFF);
    unsigned short* wrh = (unsigned short*)(ws + WRH_OFF);
    unsigned short* woh = (unsigned short*)(ws + WOH_OFF);
    float* off_raw = (float*)(ws + RAW_OFF);
    float* bn_stat = (float*)(ws + BNS_OFF);
    float* gnp     = (float*)(ws + GNP_OFF);   // also bnp (early phase, stream-ordered)
    float* gn_stat = (float*)(ws + GNS_OFF);
    float* out = (float*)d_out;

    cvt_x<<<512, 256, 0, stream>>>(x, xt2);
    repack_w<<<288, 256, 0, stream>>>(conv_w0, conv_w1, wrh);
    repack_wo<<<72, 256, 0, stream>>>(off_w0, off_w1, woh);
    off_mfma<<<1024, 256, 0, stream>>>(xt2, woh, off_raw, gnp);
    bn_fin2<<<18, 256, 0, stream>>>(gnp, bn_stat);
    snake5<<<2048, 256, 0, stream>>>(xt2, wrh, conv_b0, conv_b1, off_raw, bn_stat,
                                     bn_g0, bn_b0, bn_g1, bn_b1, out, gnp);
    gn_reduce<<<256, 256, 0, stream>>>(gnp, gn_stat);
    gn_apply<<<16384, 256, 0, stream>>>(out, gn_stat, gn_g0, gn_b0, gn_g1, gn_b1);
}

// Round 11
// 168.703 us; speedup vs baseline: 1.1333x; 1.1333x over previous
//
#include <hip/hip_runtime.h>
#include <hip/hip_bf16.h>

#define HW 16384
#define NB 8
#define CIN 64

// snake tile geometry
#define WIN_R 18
#define WIN_C 26
#define CELLS (WIN_R * WIN_C)     // 468
#define CHUNKS (CELLS * 4)        // 1872 x 16B per ci-half
#define BUFB (CELLS * 64)         // 29952 bytes (one ci-half window)

typedef short short8 __attribute__((ext_vector_type(8)));
typedef float f32x4 __attribute__((ext_vector_type(4)));

// ---------------- ws layout (BYTE offsets) ----------------
#define XT_OFF   0
#define WRH_OFF  16777216
#define WOH_OFF  16924672
#define RAW_OFF  17000448
#define BNS_OFF  26437632
#define GNP_OFF  26439168
#define GNS_OFF  27487744

__device__ inline unsigned short f2b(float v) {
    __hip_bfloat16 h = __float2bfloat16(v);
    unsigned short u; __builtin_memcpy(&u, &h, 2);
    return u;
}

// x [b][ci][px] f32  ->  xt2 [b][half][px][32ci] bf16
__global__ __launch_bounds__(256) void cvt_x(const float* __restrict__ x,
                                             unsigned short* __restrict__ xt2) {
    int blk = blockIdx.x;              // 512 = 8b * 64 tiles(256px)
    int b = blk >> 6;
    int px0 = (blk & 63) * 256;
    int t = threadIdx.x;
    __shared__ unsigned short lds[256][72];
    const float* xb = x + (size_t)b * CIN * HW + px0;
    for (int ci = 0; ci < 64; ++ci)
        lds[t][ci] = f2b(xb[ci * HW + t]);
    __syncthreads();
    int wv = t >> 6, l = t & 63;
    int chunk = l & 7;                 // 8 chunks of 8 ci
    int half = chunk >> 2, ci8 = chunk & 3;
    for (int it = 0; it < 8; ++it) {
        int row = it * 32 + wv * 8 + (l >> 3);
        short8 v = *(const short8*)&lds[row][chunk * 8];
        unsigned short* dst = xt2 + ((size_t)(b * 2 + half) * HW + px0 + row) * 32 + ci8 * 8;
        *(short8*)dst = v;
    }
}

__global__ __launch_bounds__(256) void repack_w(const float* __restrict__ w0,
                                                const float* __restrict__ w1,
                                                unsigned short* __restrict__ wrh) {
    int i = blockIdx.x * 256 + threadIdx.x;
    if (i >= 2 * 9 * 64 * 64) return;
    int ci = i & 63;
    int co = (i >> 6) & 63;
    int k  = (i >> 12) % 9;
    int br = i / 36864;
    const float* w = br ? w1 : w0;
    wrh[i] = f2b(w[(co * 64 + ci) * 9 + k]);
}

__global__ __launch_bounds__(256) void repack_wo(const float* __restrict__ w0,
                                                 const float* __restrict__ w1,
                                                 unsigned short* __restrict__ woh) {
    int i = blockIdx.x * 256 + threadIdx.x;
    if (i >= 32 * 9 * 64) return;
    int ci = i & 63;
    int tap = (i >> 6) % 9;
    int co = i / 576;
    float v = 0.f;
    if (co < 9)       v = w0[(co * 64 + ci) * 9 + tap];
    else if (co < 18) v = w1[(co * 64 + ci) * 9 + tap];
    woh[i] = f2b(v);
}

// offset 3x3 conv MFMA + fused BN partials. 1024 blocks x 256
__global__ __launch_bounds__(256, 4) void off_mfma(const unsigned short* __restrict__ xt2,
                                                   const unsigned short* __restrict__ woh,
                                                   float* __restrict__ off_raw,
                                                   float* __restrict__ bnp) {
    int b = blockIdx.x & 7;
    int tgrp = blockIdx.x >> 3;
    int t = threadIdx.x;
    int wid = t >> 6, l = t & 63;
    int tile = tgrp * 4 + wid;
    int l15 = l & 15, kg = l >> 4;
    int px0 = tile * 32;
    int h = px0 >> 7;
    int w0 = px0 & 127;

    f32x4 acc[2][2];
#pragma unroll
    for (int m = 0; m < 2; ++m)
#pragma unroll
        for (int nn = 0; nn < 2; ++nn) acc[m][nn] = (f32x4)(0.f);

#pragma unroll
    for (int s = 0; s < 18; ++s) {
        const int tap = s >> 1, half = s & 1;
        const int dy = tap / 3 - 1, dx = tap % 3 - 1;
        const unsigned short* plane = xt2 + (size_t)(b * 2 + half) * HW * 32;
        int y = h + dy;
        bool yok = (unsigned)y < 128u;
        int yc = min(max(y, 0), 127);
        short8 af[2];
#pragma unroll
        for (int m = 0; m < 2; ++m) {
            int xx = w0 + m * 16 + l15 + dx;
            bool ok = yok && ((unsigned)xx < 128u);
            int xc = min(max(xx, 0), 127);
            int o = yc * 128 + xc;
            short8 a = *(const short8*)&plane[(size_t)o * 32 + kg * 8];
            if (!ok) a = (short8)(0);
            af[m] = a;
        }
        short8 bf[2];
#pragma unroll
        for (int nn = 0; nn < 2; ++nn)
            bf[nn] = *(const short8*)&woh[((nn * 16 + l15) * 9 + tap) * 64 + half * 32 + kg * 8];
#pragma unroll
        for (int m = 0; m < 2; ++m)
#pragma unroll
            for (int nn = 0; nn < 2; ++nn)
                acc[m][nn] = __builtin_amdgcn_mfma_f32_16x16x32_bf16(af[m], bf[nn], acc[m][nn], 0, 0, 0);
    }

    float s1[2] = {0.f, 0.f}, s2[2] = {0.f, 0.f};
#pragma unroll
    for (int m = 0; m < 2; ++m)
#pragma unroll
        for (int nn = 0; nn < 2; ++nn) {
            int co = nn * 16 + l15;
            f32x4 v = acc[m][nn];
            s1[nn] += v.x + v.y + v.z + v.w;
            s2[nn] += v.x * v.x + v.y * v.y + v.z * v.z + v.w * v.w;
            if (co < 18) {
                int br = co < 9 ? 0 : 1;
                int k = co - br * 9;
                int plane = (br * 8 + b) * 9 + k;
                int px = px0 + m * 16 + kg * 4;
                *(f32x4*)&off_raw[(size_t)plane * HW + px] = v;
            }
        }
#pragma unroll
    for (int off = 16; off <= 32; off <<= 1)
#pragma unroll
        for (int nn = 0; nn < 2; ++nn) {
            s1[nn] += __shfl_xor(s1[nn], off);
            s2[nn] += __shfl_xor(s2[nn], off);
        }
    if (l < 16) {
        int idx = ((l15 * 8 + b) * 512 + tile) * 2;
        bnp[idx] = s1[0]; bnp[idx + 1] = s2[0];
        if (l15 < 2) {
            int idx2 = (((16 + l15) * 8 + b) * 512 + tile) * 2;
            bnp[idx2] = s1[1]; bnp[idx2 + 1] = s2[1];
        }
    }
}

__device__ inline void block_reduce2(float& s1, float& s2) {
    __shared__ float sh[4][2];
#pragma unroll
    for (int o = 32; o > 0; o >>= 1) {
        s1 += __shfl_down(s1, o);
        s2 += __shfl_down(s2, o);
    }
    int wid = threadIdx.x >> 6, lane = threadIdx.x & 63;
    if (lane == 0) { sh[wid][0] = s1; sh[wid][1] = s2; }
    __syncthreads();
    if (threadIdx.x == 0)
        for (int i = 1; i < 4; ++i) { s1 += sh[i][0]; s2 += sh[i][1]; }
}

__global__ __launch_bounds__(256) void bn_fin2(const float* __restrict__ bnp,
                                               float* __restrict__ bn_stat) {
    int c = blockIdx.x;
    float s1 = 0.f, s2 = 0.f;
    for (int i = threadIdx.x; i < 4096; i += 256) {
        s1 += bnp[(c * 4096 + i) * 2];
        s2 += bnp[(c * 4096 + i) * 2 + 1];
    }
    block_reduce2(s1, s2);
    if (threadIdx.x == 0) {
        const float N = 8.f * 16384.f;
        float m = s1 / N;
        float var = s2 / N - m * m;
        bn_stat[c * 2] = m;
        bn_stat[c * 2 + 1] = rsqrtf(var + 1e-5f);
    }
}

// ---------------- snake conv: LDS desc tables, rolled prefetch loop -----------
// 2048 blocks x 256 thr (4 waves). b=n&7, br=(n>>3)>>7, tile=(n>>3)&127.
// R10: descriptors (cells, fw) precomputed into per-wave LDS tables in the
// prologue -> NO bperms / desc-VALU in the k-loop; next-k cell pair prefetched
// into named scalars (no runtime-indexed arrays -> no scratch; rolled loop
// keeps VGPR ~150, avoiding R9's 184-VGPR occupancy collapse).
__global__ __launch_bounds__(256) void snake6(const unsigned short* __restrict__ xt2,
                                              const unsigned short* __restrict__ wrh,
                                              const float* __restrict__ cb0,
                                              const float* __restrict__ cb1,
                                              const float* __restrict__ off_raw,
                                              const float* __restrict__ bn_stat,
                                              const float* __restrict__ bng0,
                                              const float* __restrict__ bnb0,
                                              const float* __restrict__ bng1,
                                              const float* __restrict__ bnb1,
                                              float* __restrict__ out,
                                              float* __restrict__ gnp) {
    __shared__ __align__(16) unsigned char winbuf[2][BUFB];   // 59904 B
    __shared__ __align__(16) float fw_tab[4][9][32];          // 4608 B
    __shared__ int cell_tab[4][9][32];                        // 4608 B

    int n = blockIdx.x;
    int b = n & 7;
    int rest = n >> 3;
    int br = rest >> 7;
    int tile = rest & 127;
    int h0 = (tile >> 3) * 8;
    int w0 = (tile & 7) * 16;
    int t = threadIdx.x;
    int wv = t >> 6, l = t & 63;
    int l15 = l & 15, kg = l >> 4;
    int lp = l & 31;                   // own pixel (lanes 32-63 duplicate)

    int hrow = h0 + 2 * wv + (lp >> 4);
    int wcol = w0 + (lp & 15);
    int pxo = hrow * 128 + wcol;
    const float* bng = br ? bng1 : bng0;
    const float* bnb = br ? bnb1 : bnb0;

    // ---- stage both ci-half windows (async, swizzled source) ----
#pragma unroll
    for (int half = 0; half < 2; ++half) {
        const unsigned short* plane = xt2 + (size_t)(b * 2 + half) * HW * 32;
#pragma unroll
        for (int it = 0; it < 8; ++it) {
            int d = it * 256 + wv * 64 + l;
            if (d < CHUNKS) {
                int cell = d >> 2;
                int ci8 = (d & 3) ^ (cell & 3);      // inverse swizzle on source
                int s = cell / WIN_C;
                int c = cell - s * WIN_C;
                int row = min(max(h0 - 5 + s, 0), 127);
                int col = min(max(w0 - 5 + c, 0), 127);
                const unsigned short* src = plane + ((size_t)(row * 128 + col)) * 32 + ci8 * 8;
                __builtin_amdgcn_global_load_lds(
                    (const __attribute__((address_space(1))) unsigned int*)src,
                    (__attribute__((address_space(3))) unsigned int*)(&winbuf[half][0] + (it * 256 + wv * 64) * 16),
                    16, 0, 0);
            }
        }
    }

    // ---- prologue: own-pixel cumulative offsets -> LDS desc tables ----
    {
        float tt[9];
#pragma unroll
        for (int k = 0; k < 9; ++k) {
            float raw = off_raw[(size_t)((br * 8 + b) * 9 + k) * HW + pxo];
            float mn = bn_stat[(br * 9 + k) * 2];
            float rs = bn_stat[(br * 9 + k) * 2 + 1];
            int ch = br ? k + 9 : k;
            tt[k] = tanhf((raw - mn) * rs * bng[ch] + bnb[ch]);
        }
        float cum[9];
        cum[4] = 0.f;
        cum[3] = tt[3]; cum[2] = tt[2] + cum[3]; cum[1] = tt[1] + cum[2]; cum[0] = tt[0] + cum[1];
        cum[5] = tt[5]; cum[6] = cum[5] + tt[6]; cum[7] = cum[6] + tt[7]; cum[8] = cum[7] + tt[8];
#pragma unroll
        for (int k = 0; k < 9; ++k) {
            int cell0, cell1; float fw;
            if (br == 0) {
                int col = min(max(wcol + k - 4, 0), 127);
                float yc = fminf(fmaxf((float)hrow + cum[k], 0.f), 127.f);
                int y0 = (int)floorf(yc);
                int y1 = min(y0 + 1, 127);
                fw = yc - (float)y0;
                int cs = col - (w0 - 5);
                cell0 = (y0 - (h0 - 5)) * WIN_C + cs;
                cell1 = (y1 - (h0 - 5)) * WIN_C + cs;
            } else {
                int row = min(max(hrow + k - 4, 0), 127);
                float xcf = fminf(fmaxf((float)wcol + cum[k], 0.f), 127.f);
                int x0 = (int)floorf(xcf);
                int x1 = min(x0 + 1, 127);
                fw = xcf - (float)x0;
                int rs = (row - (h0 - 5)) * WIN_C;
                cell0 = rs + (x0 - (w0 - 5));
                cell1 = rs + (x1 - (w0 - 5));
            }
            if (l < 32) {
                cell_tab[wv][k][lp] = cell0 | (cell1 << 16);
                fw_tab[wv][k][lp] = fw;
            }
        }
    }

    __syncthreads();   // staging + desc tables complete

    f32x4 acc00 = (f32x4)(0.f), acc01 = (f32x4)(0.f), acc02 = (f32x4)(0.f), acc03 = (f32x4)(0.f);
    f32x4 acc10 = (f32x4)(0.f), acc11 = (f32x4)(0.f), acc12 = (f32x4)(0.f), acc13 = (f32x4)(0.f);
    const f32x4 zero = (f32x4)(0.f);
    const f32x4 ones = (f32x4)(1.f);

    // preload k=0 cell pair
    int cm0 = cell_tab[wv][0][l15];
    int cm1 = cell_tab[wv][0][l15 + 16];

#define BLND(ACC, A0, A1, BF, OMF, FVV)                                          \
    {                                                                            \
        f32x4 p0 = __builtin_amdgcn_mfma_f32_16x16x32_bf16(A0, BF, zero, 0, 0, 0); \
        f32x4 p1 = __builtin_amdgcn_mfma_f32_16x16x32_bf16(A1, BF, zero, 0, 0, 0); \
        ACC += OMF * p0;                                                         \
        ACC += FVV * p1;                                                         \
    }

#pragma unroll 1
    for (int k = 0; k < 9; ++k) {
        // prefetch next-k cell pair (lands during this iteration's compute)
        int kn = (k < 8) ? k + 1 : 8;
        int nc0 = cell_tab[wv][kn][l15];
        int nc1 = cell_tab[wv][kn][l15 + 16];

        f32x4 fv0 = *(const f32x4*)&fw_tab[wv][k][kg * 4];
        f32x4 fv1 = *(const f32x4*)&fw_tab[wv][k][16 + kg * 4];
        f32x4 om0 = ones - fv0;
        f32x4 om1 = ones - fv1;

        int c00 = cm0 & 0xffff, c01 = ((unsigned)cm0) >> 16;
        int c10 = cm1 & 0xffff, c11 = ((unsigned)cm1) >> 16;
        int o00 = c00 * 64 + ((kg ^ (c00 & 3)) << 4);
        int o01 = c01 * 64 + ((kg ^ (c01 & 3)) << 4);
        int o10 = c10 * 64 + ((kg ^ (c10 & 3)) << 4);
        int o11 = c11 * 64 + ((kg ^ (c11 & 3)) << 4);
        const unsigned short* wk = wrh + (size_t)((br * 9 + k) * 64) * 64 + kg * 8;

        // half 0
        {
            const unsigned char* buf = &winbuf[0][0];
            short8 a00 = *(const short8*)(buf + o00);
            short8 a01 = *(const short8*)(buf + o01);
            short8 a10 = *(const short8*)(buf + o10);
            short8 a11 = *(const short8*)(buf + o11);
            short8 bf0 = *(const short8*)&wk[(0 * 16 + l15) * 64];
            short8 bf1 = *(const short8*)&wk[(1 * 16 + l15) * 64];
            short8 bf2 = *(const short8*)&wk[(2 * 16 + l15) * 64];
            short8 bf3 = *(const short8*)&wk[(3 * 16 + l15) * 64];
            BLND(acc00, a00, a01, bf0, om0, fv0)
            BLND(acc01, a00, a01, bf1, om0, fv0)
            BLND(acc02, a00, a01, bf2, om0, fv0)
            BLND(acc03, a00, a01, bf3, om0, fv0)
            BLND(acc10, a10, a11, bf0, om1, fv1)
            BLND(acc11, a10, a11, bf1, om1, fv1)
            BLND(acc12, a10, a11, bf2, om1, fv1)
            BLND(acc13, a10, a11, bf3, om1, fv1)
        }
        // half 1
        {
            const unsigned char* buf = &winbuf[1][0];
            short8 a00 = *(const short8*)(buf + o00);
            short8 a01 = *(const short8*)(buf + o01);
            short8 a10 = *(const short8*)(buf + o10);
            short8 a11 = *(const short8*)(buf + o11);
            short8 bf0 = *(const short8*)&wk[(0 * 16 + l15) * 64 + 32];
            short8 bf1 = *(const short8*)&wk[(1 * 16 + l15) * 64 + 32];
            short8 bf2 = *(const short8*)&wk[(2 * 16 + l15) * 64 + 32];
            short8 bf3 = *(const short8*)&wk[(3 * 16 + l15) * 64 + 32];
            BLND(acc00, a00, a01, bf0, om0, fv0)
            BLND(acc01, a00, a01, bf1, om0, fv0)
            BLND(acc02, a00, a01, bf2, om0, fv0)
            BLND(acc03, a00, a01, bf3, om0, fv0)
            BLND(acc10, a10, a11, bf0, om1, fv1)
            BLND(acc11, a10, a11, bf1, om1, fv1)
            BLND(acc12, a10, a11, bf2, om1, fv1)
            BLND(acc13, a10, a11, bf3, om1, fv1)
        }
        cm0 = nc0;
        cm1 = nc1;
    }
#undef BLND

    // epilogue: bias, store, GN partials
    f32x4 accA[2][4] = {{acc00, acc01, acc02, acc03}, {acc10, acc11, acc12, acc13}};
    const float* cb = br ? cb1 : cb0;
    float s1[4], s2[4];
#pragma unroll
    for (int nn = 0; nn < 4; ++nn) { s1[nn] = 0.f; s2[nn] = 0.f; }
#pragma unroll
    for (int m = 0; m < 2; ++m) {
        int hm = h0 + 2 * wv + m;
#pragma unroll
        for (int nn = 0; nn < 4; ++nn) {
            int co = nn * 16 + l15;
            float bias = cb[co];
            f32x4 v = accA[m][nn];
            f32x4 r;
            r.x = v.x + bias; r.y = v.y + bias; r.z = v.z + bias; r.w = v.w + bias;
            s1[nn] += r.x + r.y + r.z + r.w;
            s2[nn] += r.x * r.x + r.y * r.y + r.z * r.z + r.w * r.w;
            size_t base = ((size_t)(b * 128 + br * 64 + co) << 14) + hm * 128 + w0 + kg * 4;
            *(f32x4*)&out[base] = r;
        }
    }
#pragma unroll
    for (int off = 16; off <= 32; off <<= 1)
#pragma unroll
        for (int nn = 0; nn < 4; ++nn) {
            s1[nn] += __shfl_xor(s1[nn], off);
            s2[nn] += __shfl_xor(s2[nn], off);
        }
#pragma unroll
    for (int off = 1; off <= 2; off <<= 1)
#pragma unroll
        for (int nn = 0; nn < 4; ++nn) {
            s1[nn] += __shfl_xor(s1[nn], off);
            s2[nn] += __shfl_xor(s2[nn], off);
        }
    if ((l & 0x33) == 0) {             // lanes 0,4,8,12
#pragma unroll
        for (int nn = 0; nn < 4; ++nn) {
            int g = nn * 4 + (l >> 2);
            size_t gi = ((size_t)((br * 8 + b) * 512 + tile * 4 + wv)) * 32 + g * 2;
            gnp[gi] = s1[nn];
            gnp[gi + 1] = s2[nn];
        }
    }
}

__global__ __launch_bounds__(256) void gn_reduce(const float* __restrict__ gnp,
                                                 float* __restrict__ gn_stat) {
    int sid = blockIdx.x;              // (br*8+b)*16+g
    int bb = sid >> 4;
    int g = sid & 15;
    float s1 = 0.f, s2 = 0.f;
    int t = threadIdx.x;
#pragma unroll
    for (int j = 0; j < 2; ++j) {
        size_t gi = ((size_t)(bb * 512 + t * 2 + j)) * 32 + g * 2;
        s1 += gnp[gi];
        s2 += gnp[gi + 1];
    }
    block_reduce2(s1, s2);
    if (t == 0) {
        const float N = 4.f * 16384.f;
        float m = s1 / N;
        float var = s2 / N - m * m;
        gn_stat[sid * 2] = m;
        gn_stat[sid * 2 + 1] = rsqrtf(var + 1e-5f);
    }
}

__global__ __launch_bounds__(256) void gn_apply(float* __restrict__ out,
                                                const float* __restrict__ gn_stat,
                                                const float* __restrict__ g0,
                                                const float* __restrict__ b0,
                                                const float* __restrict__ g1,
                                                const float* __restrict__ b1) {
    int i = blockIdx.x * 256 + threadIdx.x;
    size_t base = (size_t)i * 4;
    int c = (int)((base >> 14) & 127);
    int b = (int)(base >> 21);
    int br = c >> 6;
    int co = c & 63;
    int sid = (br * 8 + b) * 16 + (co >> 2);
    float m = gn_stat[sid * 2];
    float rs = gn_stat[sid * 2 + 1];
    const float* gg = br ? g1 : g0;
    const float* bb = br ? b1 : b0;
    float ga = gg[co] * rs, be = bb[co] - m * gg[co] * rs;
    f32x4 v = *(f32x4*)&out[base];
    f32x4 r;
    r.x = fmaxf(fmaf(v.x, ga, be), 0.f);
    r.y = fmaxf(fmaf(v.y, ga, be), 0.f);
    r.z = fmaxf(fmaf(v.z, ga, be), 0.f);
    r.w = fmaxf(fmaf(v.w, ga, be), 0.f);
    *(f32x4*)&out[base] = r;
}

extern "C" void kernel_launch(void* const* d_in, const int* in_sizes, int n_in,
                              void* d_out, int out_size, void* d_ws, size_t ws_size,
                              hipStream_t stream) {
    const float* x       = (const float*)d_in[0];
    const float* off_w0  = (const float*)d_in[1];
    const float* bn_g0   = (const float*)d_in[3];
    const float* bn_b0   = (const float*)d_in[4];
    const float* conv_w0 = (const float*)d_in[5];
    const float* conv_b0 = (const float*)d_in[6];
    const float* gn_g0   = (const float*)d_in[7];
    const float* gn_b0   = (const float*)d_in[8];
    const float* off_w1  = (const float*)d_in[9];
    const float* bn_g1   = (const float*)d_in[11];
    const float* bn_b1   = (const float*)d_in[12];
    const float* conv_w1 = (const float*)d_in[13];
    const float* conv_b1 = (const float*)d_in[14];
    const float* gn_g1   = (const float*)d_in[15];
    const float* gn_b1   = (const float*)d_in[16];

    char* ws = (char*)d_ws;
    unsigned short* xt2 = (unsigned short*)(ws + XT_OFF);
    unsigned short* wrh = (unsigned short*)(ws + WRH_OFF);
    unsigned short* woh = (unsigned short*)(ws + WOH_OFF);
    float* off_raw = (float*)(ws + RAW_OFF);
    float* bn_stat = (float*)(ws + BNS_OFF);
    float* gnp     = (float*)(ws + GNP_OFF);   // also bnp (early phase, stream-ordered)
    float* gn_stat = (float*)(ws + GNS_OFF);
    float* out = (float*)d_out;

    cvt_x<<<512, 256, 0, stream>>>(x, xt2);
    repack_w<<<288, 256, 0, stream>>>(conv_w0, conv_w1, wrh);
    repack_wo<<<72, 256, 0, stream>>>(off_w0, off_w1, woh);
    off_mfma<<<1024, 256, 0, stream>>>(xt2, woh, off_raw, gnp);
    bn_fin2<<<18, 256, 0, stream>>>(gnp, bn_stat);
    snake6<<<2048, 256, 0, stream>>>(xt2, wrh, conv_b0, conv_b1, off_raw, bn_stat,
                                     bn_g0, bn_b0, bn_g1, bn_b1, out, gnp);
    gn_reduce<<<256, 256, 0, stream>>>(gnp, gn_stat);
    gn_apply<<<16384, 256, 0, stream>>>(out, gn_stat, gn_g0, gn_b0, gn_g1, gn_b1);
}

// Round 12
// 167.894 us; speedup vs baseline: 1.1387x; 1.0048x over previous
//
#include <hip/hip_runtime.h>
#include <hip/hip_bf16.h>

#define HW 16384
#define NB 8
#define CIN 64

// snake tile geometry
#define WIN_R 18
#define WIN_C 26
#define CELLS (WIN_R * WIN_C)     // 468
#define CHUNKS (CELLS * 4)        // 1872 x 16B per ci-half
#define BUFB (CELLS * 64)         // 29952 bytes (one ci-half window)

typedef short short8 __attribute__((ext_vector_type(8)));
typedef float f32x4 __attribute__((ext_vector_type(4)));
typedef _Float16 half8 __attribute__((ext_vector_type(8)));

// ---------------- ws layout (BYTE offsets) ----------------
#define XT_OFF   0
#define WRH_OFF  16777216
#define WOH_OFF  16924672
#define RAW_OFF  17000448
#define BNS_OFF  26437632
#define GNP_OFF  26439168
#define GNS_OFF  27487744

__device__ inline unsigned short f2h(float v) {
    _Float16 h = (_Float16)v;
    unsigned short u; __builtin_memcpy(&u, &h, 2);
    return u;
}

// x [b][ci][px] f32  ->  xt2 [b][half][px][32ci] f16
__global__ __launch_bounds__(256) void cvt_x(const float* __restrict__ x,
                                             unsigned short* __restrict__ xt2) {
    int blk = blockIdx.x;              // 512 = 8b * 64 tiles(256px)
    int b = blk >> 6;
    int px0 = (blk & 63) * 256;
    int t = threadIdx.x;
    __shared__ unsigned short lds[256][72];
    const float* xb = x + (size_t)b * CIN * HW + px0;
    for (int ci = 0; ci < 64; ++ci)
        lds[t][ci] = f2h(xb[ci * HW + t]);
    __syncthreads();
    int wv = t >> 6, l = t & 63;
    int chunk = l & 7;                 // 8 chunks of 8 ci
    int half = chunk >> 2, ci8 = chunk & 3;
    for (int it = 0; it < 8; ++it) {
        int row = it * 32 + wv * 8 + (l >> 3);
        short8 v = *(const short8*)&lds[row][chunk * 8];
        unsigned short* dst = xt2 + ((size_t)(b * 2 + half) * HW + px0 + row) * 32 + ci8 * 8;
        *(short8*)dst = v;
    }
}

// merged weight repack (f16): wrh [2][9][64co][64ci] + woh [32co][9tap][64ci]
__global__ __launch_bounds__(256) void repack_all(const float* __restrict__ cw0,
                                                  const float* __restrict__ cw1,
                                                  const float* __restrict__ ow0,
                                                  const float* __restrict__ ow1,
                                                  unsigned short* __restrict__ wrh,
                                                  unsigned short* __restrict__ woh) {
    int i = blockIdx.x * 256 + threadIdx.x;
    if (i < 2 * 9 * 64 * 64) {
        int ci = i & 63;
        int co = (i >> 6) & 63;
        int k  = (i >> 12) % 9;
        int br = i / 36864;
        const float* w = br ? cw1 : cw0;
        wrh[i] = f2h(w[(co * 64 + ci) * 9 + k]);
    }
    int j = i - 2 * 9 * 64 * 64;
    if (j >= 0 && j < 32 * 9 * 64) {
        int ci = j & 63;
        int tap = (j >> 6) % 9;
        int co = j / 576;
        float v = 0.f;
        if (co < 9)       v = ow0[(co * 64 + ci) * 9 + tap];
        else if (co < 18) v = ow1[(co * 64 + ci) * 9 + tap];
        woh[j] = f2h(v);
    }
}

// offset 3x3 conv MFMA (f16) + fused BN partials. 1024 blocks x 256
__global__ __launch_bounds__(256, 4) void off_mfma(const unsigned short* __restrict__ xt2,
                                                   const unsigned short* __restrict__ woh,
                                                   float* __restrict__ off_raw,
                                                   float* __restrict__ bnp) {
    int b = blockIdx.x & 7;
    int tgrp = blockIdx.x >> 3;
    int t = threadIdx.x;
    int wid = t >> 6, l = t & 63;
    int tile = tgrp * 4 + wid;
    int l15 = l & 15, kg = l >> 4;
    int px0 = tile * 32;
    int h = px0 >> 7;
    int w0 = px0 & 127;

    f32x4 acc[2][2];
#pragma unroll
    for (int m = 0; m < 2; ++m)
#pragma unroll
        for (int nn = 0; nn < 2; ++nn) acc[m][nn] = (f32x4)(0.f);

#pragma unroll
    for (int s = 0; s < 18; ++s) {
        const int tap = s >> 1, half = s & 1;
        const int dy = tap / 3 - 1, dx = tap % 3 - 1;
        const unsigned short* plane = xt2 + (size_t)(b * 2 + half) * HW * 32;
        int y = h + dy;
        bool yok = (unsigned)y < 128u;
        int yc = min(max(y, 0), 127);
        half8 af[2];
#pragma unroll
        for (int m = 0; m < 2; ++m) {
            int xx = w0 + m * 16 + l15 + dx;
            bool ok = yok && ((unsigned)xx < 128u);
            int xc = min(max(xx, 0), 127);
            int o = yc * 128 + xc;
            half8 a = *(const half8*)&plane[(size_t)o * 32 + kg * 8];
            if (!ok) a = (half8)((_Float16)0.f);
            af[m] = a;
        }
        half8 bf[2];
#pragma unroll
        for (int nn = 0; nn < 2; ++nn)
            bf[nn] = *(const half8*)&woh[((nn * 16 + l15) * 9 + tap) * 64 + half * 32 + kg * 8];
#pragma unroll
        for (int m = 0; m < 2; ++m)
#pragma unroll
            for (int nn = 0; nn < 2; ++nn)
                acc[m][nn] = __builtin_amdgcn_mfma_f32_16x16x32_f16(af[m], bf[nn], acc[m][nn], 0, 0, 0);
    }

    float s1[2] = {0.f, 0.f}, s2[2] = {0.f, 0.f};
#pragma unroll
    for (int m = 0; m < 2; ++m)
#pragma unroll
        for (int nn = 0; nn < 2; ++nn) {
            int co = nn * 16 + l15;
            f32x4 v = acc[m][nn];
            s1[nn] += v.x + v.y + v.z + v.w;
            s2[nn] += v.x * v.x + v.y * v.y + v.z * v.z + v.w * v.w;
            if (co < 18) {
                int br = co < 9 ? 0 : 1;
                int k = co - br * 9;
                int plane = (br * 8 + b) * 9 + k;
                int px = px0 + m * 16 + kg * 4;
                *(f32x4*)&off_raw[(size_t)plane * HW + px] = v;
            }
        }
#pragma unroll
    for (int off = 16; off <= 32; off <<= 1)
#pragma unroll
        for (int nn = 0; nn < 2; ++nn) {
            s1[nn] += __shfl_xor(s1[nn], off);
            s2[nn] += __shfl_xor(s2[nn], off);
        }
    if (l < 16) {
        int idx = ((l15 * 8 + b) * 512 + tile) * 2;
        bnp[idx] = s1[0]; bnp[idx + 1] = s2[0];
        if (l15 < 2) {
            int idx2 = (((16 + l15) * 8 + b) * 512 + tile) * 2;
            bnp[idx2] = s1[1]; bnp[idx2 + 1] = s2[1];
        }
    }
}

__device__ inline void block_reduce2(float& s1, float& s2) {
    __shared__ float sh[4][2];
#pragma unroll
    for (int o = 32; o > 0; o >>= 1) {
        s1 += __shfl_down(s1, o);
        s2 += __shfl_down(s2, o);
    }
    int wid = threadIdx.x >> 6, lane = threadIdx.x & 63;
    if (lane == 0) { sh[wid][0] = s1; sh[wid][1] = s2; }
    __syncthreads();
    if (threadIdx.x == 0)
        for (int i = 1; i < 4; ++i) { s1 += sh[i][0]; s2 += sh[i][1]; }
}

__global__ __launch_bounds__(256) void bn_fin2(const float* __restrict__ bnp,
                                               float* __restrict__ bn_stat) {
    int c = blockIdx.x;
    float s1 = 0.f, s2 = 0.f;
    for (int i = threadIdx.x; i < 4096; i += 256) {
        s1 += bnp[(c * 4096 + i) * 2];
        s2 += bnp[(c * 4096 + i) * 2 + 1];
    }
    block_reduce2(s1, s2);
    if (threadIdx.x == 0) {
        const float N = 8.f * 16384.f;
        float m = s1 / N;
        float var = s2 / N - m * m;
        bn_stat[c * 2] = m;
        bn_stat[c * 2 + 1] = rsqrtf(var + 1e-5f);
    }
}

// ---------------- snake conv: f16 A-side lerp scale, MFMA C-accumulation ------
// 2048 blocks x 256 thr (4 waves). R11: lerp weight is lane-uniform in
// A-fragment space -> pre-scale A fragments with packed-f16 muls and use plain
// C-accumulating MFMA. Removes the f32x4 blend (128 VALU/k) from the MFMA
// dependency chain entirely.
__global__ __launch_bounds__(256) void snake7(const unsigned short* __restrict__ xt2,
                                              const unsigned short* __restrict__ wrh,
                                              const float* __restrict__ cb0,
                                              const float* __restrict__ cb1,
                                              const float* __restrict__ off_raw,
                                              const float* __restrict__ bn_stat,
                                              const float* __restrict__ bng0,
                                              const float* __restrict__ bnb0,
                                              const float* __restrict__ bng1,
                                              const float* __restrict__ bnb1,
                                              float* __restrict__ out,
                                              float* __restrict__ gnp) {
    __shared__ __align__(16) unsigned char winbuf[2][BUFB];   // 59904 B
    __shared__ __align__(16) float fw_tab[4][9][32];
    __shared__ int cell_tab[4][9][32];

    int n = blockIdx.x;
    int b = n & 7;
    int rest = n >> 3;
    int br = rest >> 7;
    int tile = rest & 127;
    int h0 = (tile >> 3) * 8;
    int w0 = (tile & 7) * 16;
    int t = threadIdx.x;
    int wv = t >> 6, l = t & 63;
    int l15 = l & 15, kg = l >> 4;
    int lp = l & 31;                   // own pixel (lanes 32-63 duplicate)

    int hrow = h0 + 2 * wv + (lp >> 4);
    int wcol = w0 + (lp & 15);
    int pxo = hrow * 128 + wcol;
    const float* bng = br ? bng1 : bng0;
    const float* bnb = br ? bnb1 : bnb0;

    // ---- stage both ci-half windows (async, swizzled source) ----
#pragma unroll
    for (int half = 0; half < 2; ++half) {
        const unsigned short* plane = xt2 + (size_t)(b * 2 + half) * HW * 32;
#pragma unroll
        for (int it = 0; it < 8; ++it) {
            int d = it * 256 + wv * 64 + l;
            if (d < CHUNKS) {
                int cell = d >> 2;
                int ci8 = (d & 3) ^ (cell & 3);      // inverse swizzle on source
                int s = cell / WIN_C;
                int c = cell - s * WIN_C;
                int row = min(max(h0 - 5 + s, 0), 127);
                int col = min(max(w0 - 5 + c, 0), 127);
                const unsigned short* src = plane + ((size_t)(row * 128 + col)) * 32 + ci8 * 8;
                __builtin_amdgcn_global_load_lds(
                    (const __attribute__((address_space(1))) unsigned int*)src,
                    (__attribute__((address_space(3))) unsigned int*)(&winbuf[half][0] + (it * 256 + wv * 64) * 16),
                    16, 0, 0);
            }
        }
    }

    // ---- prologue: own-pixel cumulative offsets -> LDS desc tables ----
    {
        float tt[9];
#pragma unroll
        for (int k = 0; k < 9; ++k) {
            float raw = off_raw[(size_t)((br * 8 + b) * 9 + k) * HW + pxo];
            float mn = bn_stat[(br * 9 + k) * 2];
            float rs = bn_stat[(br * 9 + k) * 2 + 1];
            int ch = br ? k + 9 : k;
            tt[k] = tanhf((raw - mn) * rs * bng[ch] + bnb[ch]);
        }
        float cum[9];
        cum[4] = 0.f;
        cum[3] = tt[3]; cum[2] = tt[2] + cum[3]; cum[1] = tt[1] + cum[2]; cum[0] = tt[0] + cum[1];
        cum[5] = tt[5]; cum[6] = cum[5] + tt[6]; cum[7] = cum[6] + tt[7]; cum[8] = cum[7] + tt[8];
#pragma unroll
        for (int k = 0; k < 9; ++k) {
            int cell0, cell1; float fw;
            if (br == 0) {
                int col = min(max(wcol + k - 4, 0), 127);
                float yc = fminf(fmaxf((float)hrow + cum[k], 0.f), 127.f);
                int y0 = (int)floorf(yc);
                int y1 = min(y0 + 1, 127);
                fw = yc - (float)y0;
                int cs = col - (w0 - 5);
                cell0 = (y0 - (h0 - 5)) * WIN_C + cs;
                cell1 = (y1 - (h0 - 5)) * WIN_C + cs;
            } else {
                int row = min(max(hrow + k - 4, 0), 127);
                float xcf = fminf(fmaxf((float)wcol + cum[k], 0.f), 127.f);
                int x0 = (int)floorf(xcf);
                int x1 = min(x0 + 1, 127);
                fw = xcf - (float)x0;
                int rs = (row - (h0 - 5)) * WIN_C;
                cell0 = rs + (x0 - (w0 - 5));
                cell1 = rs + (x1 - (w0 - 5));
            }
            if (l < 32) {
                cell_tab[wv][k][lp] = cell0 | (cell1 << 16);
                fw_tab[wv][k][lp] = fw;
            }
        }
    }

    __syncthreads();   // staging + desc tables complete

    f32x4 acc00 = (f32x4)(0.f), acc01 = (f32x4)(0.f), acc02 = (f32x4)(0.f), acc03 = (f32x4)(0.f);
    f32x4 acc10 = (f32x4)(0.f), acc11 = (f32x4)(0.f), acc12 = (f32x4)(0.f), acc13 = (f32x4)(0.f);

    // preload k=0 cell pair
    int cm0 = cell_tab[wv][0][l15];
    int cm1 = cell_tab[wv][0][l15 + 16];

#pragma unroll 1
    for (int k = 0; k < 9; ++k) {
        // prefetch next-k cell pair
        int kn = (k < 8) ? k + 1 : 8;
        int nc0 = cell_tab[wv][kn][l15];
        int nc1 = cell_tab[wv][kn][l15 + 16];

        // lane-uniform lerp weights for this lane's A rows (pixels l15, l15+16)
        float fw0 = fw_tab[wv][k][l15];
        float fw1 = fw_tab[wv][k][l15 + 16];
        half8 f0s = (half8)((_Float16)fw0);
        half8 f0c = (half8)((_Float16)(1.f - fw0));
        half8 f1s = (half8)((_Float16)fw1);
        half8 f1c = (half8)((_Float16)(1.f - fw1));

        int c00 = cm0 & 0xffff, c01 = ((unsigned)cm0) >> 16;
        int c10 = cm1 & 0xffff, c11 = ((unsigned)cm1) >> 16;
        int o00 = c00 * 64 + ((kg ^ (c00 & 3)) << 4);
        int o01 = c01 * 64 + ((kg ^ (c01 & 3)) << 4);
        int o10 = c10 * 64 + ((kg ^ (c10 & 3)) << 4);
        int o11 = c11 * 64 + ((kg ^ (c11 & 3)) << 4);
        const unsigned short* wk = wrh + (size_t)((br * 9 + k) * 64) * 64 + kg * 8;

#pragma unroll
        for (int half = 0; half < 2; ++half) {
            const unsigned char* buf = &winbuf[half][0];
            half8 a00 = *(const half8*)(buf + o00);
            half8 a01 = *(const half8*)(buf + o01);
            half8 a10 = *(const half8*)(buf + o10);
            half8 a11 = *(const half8*)(buf + o11);
            // A-side lerp scaling (packed f16 muls, out of the MFMA chain)
            half8 af00 = a00 * f0c;
            half8 af01 = a01 * f0s;
            half8 af10 = a10 * f1c;
            half8 af11 = a11 * f1s;
            const unsigned short* wkh = wk + half * 32;
            half8 bf0 = *(const half8*)&wkh[(0 * 16 + l15) * 64];
            half8 bf1 = *(const half8*)&wkh[(1 * 16 + l15) * 64];
            half8 bf2 = *(const half8*)&wkh[(2 * 16 + l15) * 64];
            half8 bf3 = *(const half8*)&wkh[(3 * 16 + l15) * 64];
            acc00 = __builtin_amdgcn_mfma_f32_16x16x32_f16(af00, bf0, acc00, 0, 0, 0);
            acc01 = __builtin_amdgcn_mfma_f32_16x16x32_f16(af00, bf1, acc01, 0, 0, 0);
            acc02 = __builtin_amdgcn_mfma_f32_16x16x32_f16(af00, bf2, acc02, 0, 0, 0);
            acc03 = __builtin_amdgcn_mfma_f32_16x16x32_f16(af00, bf3, acc03, 0, 0, 0);
            acc00 = __builtin_amdgcn_mfma_f32_16x16x32_f16(af01, bf0, acc00, 0, 0, 0);
            acc01 = __builtin_amdgcn_mfma_f32_16x16x32_f16(af01, bf1, acc01, 0, 0, 0);
            acc02 = __builtin_amdgcn_mfma_f32_16x16x32_f16(af01, bf2, acc02, 0, 0, 0);
            acc03 = __builtin_amdgcn_mfma_f32_16x16x32_f16(af01, bf3, acc03, 0, 0, 0);
            acc10 = __builtin_amdgcn_mfma_f32_16x16x32_f16(af10, bf0, acc10, 0, 0, 0);
            acc11 = __builtin_amdgcn_mfma_f32_16x16x32_f16(af10, bf1, acc11, 0, 0, 0);
            acc12 = __builtin_amdgcn_mfma_f32_16x16x32_f16(af10, bf2, acc12, 0, 0, 0);
            acc13 = __builtin_amdgcn_mfma_f32_16x16x32_f16(af10, bf3, acc13, 0, 0, 0);
            acc10 = __builtin_amdgcn_mfma_f32_16x16x32_f16(af11, bf0, acc10, 0, 0, 0);
            acc11 = __builtin_amdgcn_mfma_f32_16x16x32_f16(af11, bf1, acc11, 0, 0, 0);
            acc12 = __builtin_amdgcn_mfma_f32_16x16x32_f16(af11, bf2, acc12, 0, 0, 0);
            acc13 = __builtin_amdgcn_mfma_f32_16x16x32_f16(af11, bf3, acc13, 0, 0, 0);
        }
        cm0 = nc0;
        cm1 = nc1;
    }

    // epilogue: bias, store, GN partials
    f32x4 accA[2][4] = {{acc00, acc01, acc02, acc03}, {acc10, acc11, acc12, acc13}};
    const float* cb = br ? cb1 : cb0;
    float s1[4], s2[4];
#pragma unroll
    for (int nn = 0; nn < 4; ++nn) { s1[nn] = 0.f; s2[nn] = 0.f; }
#pragma unroll
    for (int m = 0; m < 2; ++m) {
        int hm = h0 + 2 * wv + m;
#pragma unroll
        for (int nn = 0; nn < 4; ++nn) {
            int co = nn * 16 + l15;
            float bias = cb[co];
            f32x4 v = accA[m][nn];
            f32x4 r;
            r.x = v.x + bias; r.y = v.y + bias; r.z = v.z + bias; r.w = v.w + bias;
            s1[nn] += r.x + r.y + r.z + r.w;
            s2[nn] += r.x * r.x + r.y * r.y + r.z * r.z + r.w * r.w;
            size_t base = ((size_t)(b * 128 + br * 64 + co) << 14) + hm * 128 + w0 + kg * 4;
            *(f32x4*)&out[base] = r;
        }
    }
#pragma unroll
    for (int off = 16; off <= 32; off <<= 1)
#pragma unroll
        for (int nn = 0; nn < 4; ++nn) {
            s1[nn] += __shfl_xor(s1[nn], off);
            s2[nn] += __shfl_xor(s2[nn], off);
        }
#pragma unroll
    for (int off = 1; off <= 2; off <<= 1)
#pragma unroll
        for (int nn = 0; nn < 4; ++nn) {
            s1[nn] += __shfl_xor(s1[nn], off);
            s2[nn] += __shfl_xor(s2[nn], off);
        }
    if ((l & 0x33) == 0) {             // lanes 0,4,8,12
#pragma unroll
        for (int nn = 0; nn < 4; ++nn) {
            int g = nn * 4 + (l >> 2);
            size_t gi = ((size_t)((br * 8 + b) * 512 + tile * 4 + wv)) * 32 + g * 2;
            gnp[gi] = s1[nn];
            gnp[gi + 1] = s2[nn];
        }
    }
}

__global__ __launch_bounds__(256) void gn_reduce(const float* __restrict__ gnp,
                                                 float* __restrict__ gn_stat) {
    int sid = blockIdx.x;              // (br*8+b)*16+g
    int bb = sid >> 4;
    int g = sid & 15;
    float s1 = 0.f, s2 = 0.f;
    int t = threadIdx.x;
#pragma unroll
    for (int j = 0; j < 2; ++j) {
        size_t gi = ((size_t)(bb * 512 + t * 2 + j)) * 32 + g * 2;
        s1 += gnp[gi];
        s2 += gnp[gi + 1];
    }
    block_reduce2(s1, s2);
    if (t == 0) {
        const float N = 4.f * 16384.f;
        float m = s1 / N;
        float var = s2 / N - m * m;
        gn_stat[sid * 2] = m;
        gn_stat[sid * 2 + 1] = rsqrtf(var + 1e-5f);
    }
}

__global__ __launch_bounds__(256) void gn_apply(float* __restrict__ out,
                                                const float* __restrict__ gn_stat,
                                                const float* __restrict__ g0,
                                                const float* __restrict__ b0,
                                                const float* __restrict__ g1,
                                                const float* __restrict__ b1) {
    int i = blockIdx.x * 256 + threadIdx.x;
    size_t base = (size_t)i * 4;
    int c = (int)((base >> 14) & 127);
    int b = (int)(base >> 21);
    int br = c >> 6;
    int co = c & 63;
    int sid = (br * 8 + b) * 16 + (co >> 2);
    float m = gn_stat[sid * 2];
    float rs = gn_stat[sid * 2 + 1];
    const float* gg = br ? g1 : g0;
    const float* bb = br ? b1 : b0;
    float ga = gg[co] * rs, be = bb[co] - m * gg[co] * rs;
    f32x4 v = *(f32x4*)&out[base];
    f32x4 r;
    r.x = fmaxf(fmaf(v.x, ga, be), 0.f);
    r.y = fmaxf(fmaf(v.y, ga, be), 0.f);
    r.z = fmaxf(fmaf(v.z, ga, be), 0.f);
    r.w = fmaxf(fmaf(v.w, ga, be), 0.f);
    *(f32x4*)&out[base] = r;
}

extern "C" void kernel_launch(void* const* d_in, const int* in_sizes, int n_in,
                              void* d_out, int out_size, void* d_ws, size_t ws_size,
                              hipStream_t stream) {
    const float* x       = (const float*)d_in[0];
    const float* off_w0  = (const float*)d_in[1];
    const float* bn_g0   = (const float*)d_in[3];
    const float* bn_b0   = (const float*)d_in[4];
    const float* conv_w0 = (const float*)d_in[5];
    const float* conv_b0 = (const float*)d_in[6];
    const float* gn_g0   = (const float*)d_in[7];
    const float* gn_b0   = (const float*)d_in[8];
    const float* off_w1  = (const float*)d_in[9];
    const float* bn_g1   = (const float*)d_in[11];
    const float* bn_b1   = (const float*)d_in[12];
    const float* conv_w1 = (const float*)d_in[13];
    const float* conv_b1 = (const float*)d_in[14];
    const float* gn_g1   = (const float*)d_in[15];
    const float* gn_b1   = (const float*)d_in[16];

    char* ws = (char*)d_ws;
    unsigned short* xt2 = (unsigned short*)(ws + XT_OFF);
    unsigned short* wrh = (unsigned short*)(ws + WRH_OFF);
    unsigned short* woh = (unsigned short*)(ws + WOH_OFF);
    float* off_raw = (float*)(ws + RAW_OFF);
    float* bn_stat = (float*)(ws + BNS_OFF);
    float* gnp     = (float*)(ws + GNP_OFF);   // also bnp (early phase, stream-ordered)
    float* gn_stat = (float*)(ws + GNS_OFF);
    float* out = (float*)d_out;

    cvt_x<<<512, 256, 0, stream>>>(x, xt2);
    repack_all<<<360, 256, 0, stream>>>(conv_w0, conv_w1, off_w0, off_w1, wrh, woh);
    off_mfma<<<1024, 256, 0, stream>>>(xt2, woh, off_raw, gnp);
    bn_fin2<<<18, 256, 0, stream>>>(gnp, bn_stat);
    snake7<<<2048, 256, 0, stream>>>(xt2, wrh, conv_b0, conv_b1, off_raw, bn_stat,
                                     bn_g0, bn_b0, bn_g1, bn_b1, out, gnp);
    gn_reduce<<<256, 256, 0, stream>>>(gnp, gn_stat);
    gn_apply<<<16384, 256, 0, stream>>>(out, gn_stat, gn_g0, gn_b0, gn_g1, gn_b1);
}

// Round 13
// 136.391 us; speedup vs baseline: 1.4017x; 1.2310x over previous
//
#include <hip/hip_runtime.h>
#include <hip/hip_bf16.h>

#define HW 16384
#define NB 8
#define CIN 64

// snake tile geometry
#define WIN_R 18
#define WIN_C 26
#define CELLS (WIN_R * WIN_C)     // 468
#define CHUNKS (CELLS * 4)        // 1872 x 16B per ci-half
#define BUFB (CELLS * 64)         // 29952 bytes (one ci-half window)
#define WSLAB 18432               // shorts per (br,half) weight slab (9*64*32)

typedef short short8 __attribute__((ext_vector_type(8)));
typedef float f32x4 __attribute__((ext_vector_type(4)));
typedef _Float16 half8 __attribute__((ext_vector_type(8)));

// ---------------- ws layout (BYTE offsets) ----------------
// xt2     : [8][2][HW][32] f16    0           16,777,216
// wrh2    : [2][2][9*64][32] f16  16777216    147,456
// woh     : [32co][9tap][64ci]    16924672    36,864
// off_raw : [16][9][HW] f32       17000448    9,437,184
// bn_stat : [18][2] f32           26437632    144
// gnp     : [16][512][16][2] f32  26439168    1,048,576 (aliased bnp early)
// gn_stat : [256][2] f32          27487744    2,048
#define XT_OFF   0
#define WRH_OFF  16777216
#define WOH_OFF  16924672
#define RAW_OFF  17000448
#define BNS_OFF  26437632
#define GNP_OFF  26439168
#define GNS_OFF  27487744

__device__ inline unsigned short f2h(float v) {
    _Float16 h = (_Float16)v;
    unsigned short u; __builtin_memcpy(&u, &h, 2);
    return u;
}

// x [b][ci][px] f32  ->  xt2 [b][half][px][32ci] f16
__global__ __launch_bounds__(256) void cvt_x(const float* __restrict__ x,
                                             unsigned short* __restrict__ xt2) {
    int blk = blockIdx.x;              // 512 = 8b * 64 tiles(256px)
    int b = blk >> 6;
    int px0 = (blk & 63) * 256;
    int t = threadIdx.x;
    __shared__ unsigned short lds[256][72];
    const float* xb = x + (size_t)b * CIN * HW + px0;
    for (int ci = 0; ci < 64; ++ci)
        lds[t][ci] = f2h(xb[ci * HW + t]);
    __syncthreads();
    int wv = t >> 6, l = t & 63;
    int chunk = l & 7;                 // 8 chunks of 8 ci
    int half = chunk >> 2, ci8 = chunk & 3;
    for (int it = 0; it < 8; ++it) {
        int row = it * 32 + wv * 8 + (l >> 3);
        short8 v = *(const short8*)&lds[row][chunk * 8];
        unsigned short* dst = xt2 + ((size_t)(b * 2 + half) * HW + px0 + row) * 32 + ci8 * 8;
        *(short8*)dst = v;
    }
}

// merged weight repack (f16):
// wrh2 [br][cihalf][r=k*64+co][32ci]  (contiguous 36864B per (br,half) slab)
// woh  [32co][9tap][64ci]
__global__ __launch_bounds__(256) void repack_all(const float* __restrict__ cw0,
                                                  const float* __restrict__ cw1,
                                                  const float* __restrict__ ow0,
                                                  const float* __restrict__ ow1,
                                                  unsigned short* __restrict__ wrh2,
                                                  unsigned short* __restrict__ woh) {
    int i = blockIdx.x * 256 + threadIdx.x;
    if (i < 2 * 2 * WSLAB) {
        int slab = i / WSLAB;          // br*2 + half
        int br = slab >> 1, chalf = slab & 1;
        int rem = i - slab * WSLAB;
        int r = rem >> 5;              // k*64 + co
        int ci32 = rem & 31;
        int k = r >> 6, co = r & 63;
        const float* w = br ? cw1 : cw0;
        wrh2[i] = f2h(w[(co * 64 + chalf * 32 + ci32) * 9 + k]);
    }
    int j = i - 2 * 2 * WSLAB;
    if (j >= 0 && j < 32 * 9 * 64) {
        int ci = j & 63;
        int tap = (j >> 6) % 9;
        int co = j / 576;
        float v = 0.f;
        if (co < 9)       v = ow0[(co * 64 + ci) * 9 + tap];
        else if (co < 18) v = ow1[(co * 64 + ci) * 9 + tap];
        woh[j] = f2h(v);
    }
}

// offset 3x3 conv MFMA (f16) + fused BN partials. 1024 blocks x 256
__global__ __launch_bounds__(256, 4) void off_mfma(const unsigned short* __restrict__ xt2,
                                                   const unsigned short* __restrict__ woh,
                                                   float* __restrict__ off_raw,
                                                   float* __restrict__ bnp) {
    int b = blockIdx.x & 7;
    int tgrp = blockIdx.x >> 3;
    int t = threadIdx.x;
    int wid = t >> 6, l = t & 63;
    int tile = tgrp * 4 + wid;
    int l15 = l & 15, kg = l >> 4;
    int px0 = tile * 32;
    int h = px0 >> 7;
    int w0 = px0 & 127;

    f32x4 acc[2][2];
#pragma unroll
    for (int m = 0; m < 2; ++m)
#pragma unroll
        for (int nn = 0; nn < 2; ++nn) acc[m][nn] = (f32x4)(0.f);

#pragma unroll
    for (int s = 0; s < 18; ++s) {
        const int tap = s >> 1, half = s & 1;
        const int dy = tap / 3 - 1, dx = tap % 3 - 1;
        const unsigned short* plane = xt2 + (size_t)(b * 2 + half) * HW * 32;
        int y = h + dy;
        bool yok = (unsigned)y < 128u;
        int yc = min(max(y, 0), 127);
        half8 af[2];
#pragma unroll
        for (int m = 0; m < 2; ++m) {
            int xx = w0 + m * 16 + l15 + dx;
            bool ok = yok && ((unsigned)xx < 128u);
            int xc = min(max(xx, 0), 127);
            int o = yc * 128 + xc;
            half8 a = *(const half8*)&plane[(size_t)o * 32 + kg * 8];
            if (!ok) a = (half8)((_Float16)0.f);
            af[m] = a;
        }
        half8 bf[2];
#pragma unroll
        for (int nn = 0; nn < 2; ++nn)
            bf[nn] = *(const half8*)&woh[((nn * 16 + l15) * 9 + tap) * 64 + half * 32 + kg * 8];
#pragma unroll
        for (int m = 0; m < 2; ++m)
#pragma unroll
            for (int nn = 0; nn < 2; ++nn)
                acc[m][nn] = __builtin_amdgcn_mfma_f32_16x16x32_f16(af[m], bf[nn], acc[m][nn], 0, 0, 0);
    }

    float s1[2] = {0.f, 0.f}, s2[2] = {0.f, 0.f};
#pragma unroll
    for (int m = 0; m < 2; ++m)
#pragma unroll
        for (int nn = 0; nn < 2; ++nn) {
            int co = nn * 16 + l15;
            f32x4 v = acc[m][nn];
            s1[nn] += v.x + v.y + v.z + v.w;
            s2[nn] += v.x * v.x + v.y * v.y + v.z * v.z + v.w * v.w;
            if (co < 18) {
                int br = co < 9 ? 0 : 1;
                int k = co - br * 9;
                int plane = (br * 8 + b) * 9 + k;
                int px = px0 + m * 16 + kg * 4;
                *(f32x4*)&off_raw[(size_t)plane * HW + px] = v;
            }
        }
#pragma unroll
    for (int off = 16; off <= 32; off <<= 1)
#pragma unroll
        for (int nn = 0; nn < 2; ++nn) {
            s1[nn] += __shfl_xor(s1[nn], off);
            s2[nn] += __shfl_xor(s2[nn], off);
        }
    if (l < 16) {
        int idx = ((l15 * 8 + b) * 512 + tile) * 2;
        bnp[idx] = s1[0]; bnp[idx + 1] = s2[0];
        if (l15 < 2) {
            int idx2 = (((16 + l15) * 8 + b) * 512 + tile) * 2;
            bnp[idx2] = s1[1]; bnp[idx2 + 1] = s2[1];
        }
    }
}

__device__ inline void block_reduce2(float& s1, float& s2) {
    __shared__ float sh[4][2];
#pragma unroll
    for (int o = 32; o > 0; o >>= 1) {
        s1 += __shfl_down(s1, o);
        s2 += __shfl_down(s2, o);
    }
    int wid = threadIdx.x >> 6, lane = threadIdx.x & 63;
    if (lane == 0) { sh[wid][0] = s1; sh[wid][1] = s2; }
    __syncthreads();
    if (threadIdx.x == 0)
        for (int i = 1; i < 4; ++i) { s1 += sh[i][0]; s2 += sh[i][1]; }
}

__global__ __launch_bounds__(256) void bn_fin2(const float* __restrict__ bnp,
                                               float* __restrict__ bn_stat) {
    int c = blockIdx.x;
    float s1 = 0.f, s2 = 0.f;
    for (int i = threadIdx.x; i < 4096; i += 256) {
        s1 += bnp[(c * 4096 + i) * 2];
        s2 += bnp[(c * 4096 + i) * 2 + 1];
    }
    block_reduce2(s1, s2);
    if (threadIdx.x == 0) {
        const float N = 8.f * 16384.f;
        float m = s1 / N;
        float var = s2 / N - m * m;
        bn_stat[c * 2] = m;
        bn_stat[c * 2 + 1] = rsqrtf(var + 1e-5f);
    }
}

// ---------------- snake conv: all-LDS main loop (window + weights staged) -----
// 2048 blocks x 256 thr (4 waves). R12: weights staged to LDS once per
// (block, half) -> the k-loop touches ONLY LDS. Sequential ci-halves through a
// single 30KB window (R7 structure). LDS = 30K win + 36.9K weights + 9K desc.
__global__ __launch_bounds__(256) void snake8(const unsigned short* __restrict__ xt2,
                                              const unsigned short* __restrict__ wrh2,
                                              const float* __restrict__ cb0,
                                              const float* __restrict__ cb1,
                                              const float* __restrict__ off_raw,
                                              const float* __restrict__ bn_stat,
                                              const float* __restrict__ bng0,
                                              const float* __restrict__ bnb0,
                                              const float* __restrict__ bng1,
                                              const float* __restrict__ bnb1,
                                              float* __restrict__ out,
                                              float* __restrict__ gnp) {
    __shared__ __align__(16) unsigned char winbuf[BUFB];      // 29952
    __shared__ __align__(16) unsigned char wbuf[36864];       // weights, one half
    __shared__ __align__(16) float fw_tab[4][9][32];          // 4608
    __shared__ int cell_tab[4][9][32];                        // 4608

    int n = blockIdx.x;
    int b = n & 7;
    int rest = n >> 3;
    int br = rest >> 7;
    int tile = rest & 127;
    int h0 = (tile >> 3) * 8;
    int w0 = (tile & 7) * 16;
    int t = threadIdx.x;
    int wv = t >> 6, l = t & 63;
    int l15 = l & 15, kg = l >> 4;
    int lp = l & 31;                   // own pixel (lanes 32-63 duplicate)
    int wxor = (kg ^ (l15 & 3)) << 4;  // lane-constant weight chunk swizzle

    int hrow = h0 + 2 * wv + (lp >> 4);
    int wcol = w0 + (lp & 15);
    int pxo = hrow * 128 + wcol;
    const float* bng = br ? bng1 : bng0;
    const float* bnb = br ? bnb1 : bnb0;

    f32x4 acc00 = (f32x4)(0.f), acc01 = (f32x4)(0.f), acc02 = (f32x4)(0.f), acc03 = (f32x4)(0.f);
    f32x4 acc10 = (f32x4)(0.f), acc11 = (f32x4)(0.f), acc12 = (f32x4)(0.f), acc13 = (f32x4)(0.f);

#pragma unroll 1
    for (int half = 0; half < 2; ++half) {
        if (half == 1) __syncthreads();          // all reads of prev LDS done

        // ---- stage this ci-half window (async, swizzled source) ----
        {
            const unsigned short* plane = xt2 + (size_t)(b * 2 + half) * HW * 32;
#pragma unroll
            for (int it = 0; it < 8; ++it) {
                int d = it * 256 + wv * 64 + l;
                if (d < CHUNKS) {
                    int cell = d >> 2;
                    int ci8 = (d & 3) ^ (cell & 3);      // inverse swizzle on source
                    int s = cell / WIN_C;
                    int c = cell - s * WIN_C;
                    int row = min(max(h0 - 5 + s, 0), 127);
                    int col = min(max(w0 - 5 + c, 0), 127);
                    const unsigned short* src = plane + ((size_t)(row * 128 + col)) * 32 + ci8 * 8;
                    __builtin_amdgcn_global_load_lds(
                        (const __attribute__((address_space(1))) unsigned int*)src,
                        (__attribute__((address_space(3))) unsigned int*)(&winbuf[0] + (it * 256 + wv * 64) * 16),
                        16, 0, 0);
                }
            }
        }
        // ---- stage this ci-half weight slab (2304 chunks = 9 exact iters) ----
        {
            const unsigned short* slab = wrh2 + (size_t)(br * 2 + half) * WSLAB;
#pragma unroll
            for (int it = 0; it < 9; ++it) {
                int d = it * 256 + wv * 64 + l;
                int r = d >> 2;                          // k*64 + co
                int c = (d & 3) ^ (r & 3);               // inverse swizzle on source
                const unsigned short* src = slab + r * 32 + c * 8;
                __builtin_amdgcn_global_load_lds(
                    (const __attribute__((address_space(1))) unsigned int*)src,
                    (__attribute__((address_space(3))) unsigned int*)(&wbuf[0] + (it * 256 + wv * 64) * 16),
                    16, 0, 0);
            }
        }

        // ---- prologue (first half only): offsets -> LDS desc tables ----
        if (half == 0) {
            float tt[9];
#pragma unroll
            for (int k = 0; k < 9; ++k) {
                float raw = off_raw[(size_t)((br * 8 + b) * 9 + k) * HW + pxo];
                float mn = bn_stat[(br * 9 + k) * 2];
                float rs = bn_stat[(br * 9 + k) * 2 + 1];
                int ch = br ? k + 9 : k;
                tt[k] = tanhf((raw - mn) * rs * bng[ch] + bnb[ch]);
            }
            float cum[9];
            cum[4] = 0.f;
            cum[3] = tt[3]; cum[2] = tt[2] + cum[3]; cum[1] = tt[1] + cum[2]; cum[0] = tt[0] + cum[1];
            cum[5] = tt[5]; cum[6] = cum[5] + tt[6]; cum[7] = cum[6] + tt[7]; cum[8] = cum[7] + tt[8];
#pragma unroll
            for (int k = 0; k < 9; ++k) {
                int cell0, cell1; float fw;
                if (br == 0) {
                    int col = min(max(wcol + k - 4, 0), 127);
                    float yc = fminf(fmaxf((float)hrow + cum[k], 0.f), 127.f);
                    int y0 = (int)floorf(yc);
                    int y1 = min(y0 + 1, 127);
                    fw = yc - (float)y0;
                    int cs = col - (w0 - 5);
                    cell0 = (y0 - (h0 - 5)) * WIN_C + cs;
                    cell1 = (y1 - (h0 - 5)) * WIN_C + cs;
                } else {
                    int row = min(max(hrow + k - 4, 0), 127);
                    float xcf = fminf(fmaxf((float)wcol + cum[k], 0.f), 127.f);
                    int x0 = (int)floorf(xcf);
                    int x1 = min(x0 + 1, 127);
                    fw = xcf - (float)x0;
                    int rs = (row - (h0 - 5)) * WIN_C;
                    cell0 = rs + (x0 - (w0 - 5));
                    cell1 = rs + (x1 - (w0 - 5));
                }
                if (l < 32) {
                    cell_tab[wv][k][lp] = cell0 | (cell1 << 16);
                    fw_tab[wv][k][lp] = fw;
                }
            }
        }

        __syncthreads();   // staging + (half0) desc tables complete

        // preload k=0 cell pair
        int cm0 = cell_tab[wv][0][l15];
        int cm1 = cell_tab[wv][0][l15 + 16];

#pragma unroll 1
        for (int k = 0; k < 9; ++k) {
            int kn = (k < 8) ? k + 1 : 8;
            int nc0 = cell_tab[wv][kn][l15];
            int nc1 = cell_tab[wv][kn][l15 + 16];

            float fw0 = fw_tab[wv][k][l15];
            float fw1 = fw_tab[wv][k][l15 + 16];
            half8 f0s = (half8)((_Float16)fw0);
            half8 f0c = (half8)((_Float16)(1.f - fw0));
            half8 f1s = (half8)((_Float16)fw1);
            half8 f1c = (half8)((_Float16)(1.f - fw1));

            int c00 = cm0 & 0xffff, c01 = ((unsigned)cm0) >> 16;
            int c10 = cm1 & 0xffff, c11 = ((unsigned)cm1) >> 16;
            int o00 = c00 * 64 + ((kg ^ (c00 & 3)) << 4);
            int o01 = c01 * 64 + ((kg ^ (c01 & 3)) << 4);
            int o10 = c10 * 64 + ((kg ^ (c10 & 3)) << 4);
            int o11 = c11 * 64 + ((kg ^ (c11 & 3)) << 4);

            half8 a00 = *(const half8*)(winbuf + o00);
            half8 a01 = *(const half8*)(winbuf + o01);
            half8 a10 = *(const half8*)(winbuf + o10);
            half8 a11 = *(const half8*)(winbuf + o11);
            half8 af00 = a00 * f0c;
            half8 af01 = a01 * f0s;
            half8 af10 = a10 * f1c;
            half8 af11 = a11 * f1s;

            // weights from LDS: row r = k*64 + nn*16 + l15, chunk kg^(l15&3)
            const unsigned char* wkb = wbuf + (k << 12);
            half8 bf0 = *(const half8*)(wkb + (0 * 16 + l15) * 64 + wxor);
            half8 bf1 = *(const half8*)(wkb + (1 * 16 + l15) * 64 + wxor);
            half8 bf2 = *(const half8*)(wkb + (2 * 16 + l15) * 64 + wxor);
            half8 bf3 = *(const half8*)(wkb + (3 * 16 + l15) * 64 + wxor);

            acc00 = __builtin_amdgcn_mfma_f32_16x16x32_f16(af00, bf0, acc00, 0, 0, 0);
            acc01 = __builtin_amdgcn_mfma_f32_16x16x32_f16(af00, bf1, acc01, 0, 0, 0);
            acc02 = __builtin_amdgcn_mfma_f32_16x16x32_f16(af00, bf2, acc02, 0, 0, 0);
            acc03 = __builtin_amdgcn_mfma_f32_16x16x32_f16(af00, bf3, acc03, 0, 0, 0);
            acc00 = __builtin_amdgcn_mfma_f32_16x16x32_f16(af01, bf0, acc00, 0, 0, 0);
            acc01 = __builtin_amdgcn_mfma_f32_16x16x32_f16(af01, bf1, acc01, 0, 0, 0);
            acc02 = __builtin_amdgcn_mfma_f32_16x16x32_f16(af01, bf2, acc02, 0, 0, 0);
            acc03 = __builtin_amdgcn_mfma_f32_16x16x32_f16(af01, bf3, acc03, 0, 0, 0);
            acc10 = __builtin_amdgcn_mfma_f32_16x16x32_f16(af10, bf0, acc10, 0, 0, 0);
            acc11 = __builtin_amdgcn_mfma_f32_16x16x32_f16(af10, bf1, acc11, 0, 0, 0);
            acc12 = __builtin_amdgcn_mfma_f32_16x16x32_f16(af10, bf2, acc12, 0, 0, 0);
            acc13 = __builtin_amdgcn_mfma_f32_16x16x32_f16(af10, bf3, acc13, 0, 0, 0);
            acc10 = __builtin_amdgcn_mfma_f32_16x16x32_f16(af11, bf0, acc10, 0, 0, 0);
            acc11 = __builtin_amdgcn_mfma_f32_16x16x32_f16(af11, bf1, acc11, 0, 0, 0);
            acc12 = __builtin_amdgcn_mfma_f32_16x16x32_f16(af11, bf2, acc12, 0, 0, 0);
            acc13 = __builtin_amdgcn_mfma_f32_16x16x32_f16(af11, bf3, acc13, 0, 0, 0);

            cm0 = nc0;
            cm1 = nc1;
        }
    }

    // epilogue: bias, store, GN partials
    f32x4 accA[2][4] = {{acc00, acc01, acc02, acc03}, {acc10, acc11, acc12, acc13}};
    const float* cb = br ? cb1 : cb0;
    float s1[4], s2[4];
#pragma unroll
    for (int nn = 0; nn < 4; ++nn) { s1[nn] = 0.f; s2[nn] = 0.f; }
#pragma unroll
    for (int m = 0; m < 2; ++m) {
        int hm = h0 + 2 * wv + m;
#pragma unroll
        for (int nn = 0; nn < 4; ++nn) {
            int co = nn * 16 + l15;
            float bias = cb[co];
            f32x4 v = accA[m][nn];
            f32x4 r;
            r.x = v.x + bias; r.y = v.y + bias; r.z = v.z + bias; r.w = v.w + bias;
            s1[nn] += r.x + r.y + r.z + r.w;
            s2[nn] += r.x * r.x + r.y * r.y + r.z * r.z + r.w * r.w;
            size_t base = ((size_t)(b * 128 + br * 64 + co) << 14) + hm * 128 + w0 + kg * 4;
            *(f32x4*)&out[base] = r;
        }
    }
#pragma unroll
    for (int off = 16; off <= 32; off <<= 1)
#pragma unroll
        for (int nn = 0; nn < 4; ++nn) {
            s1[nn] += __shfl_xor(s1[nn], off);
            s2[nn] += __shfl_xor(s2[nn], off);
        }
#pragma unroll
    for (int off = 1; off <= 2; off <<= 1)
#pragma unroll
        for (int nn = 0; nn < 4; ++nn) {
            s1[nn] += __shfl_xor(s1[nn], off);
            s2[nn] += __shfl_xor(s2[nn], off);
        }
    if ((l & 0x33) == 0) {             // lanes 0,4,8,12
#pragma unroll
        for (int nn = 0; nn < 4; ++nn) {
            int g = nn * 4 + (l >> 2);
            size_t gi = ((size_t)((br * 8 + b) * 512 + tile * 4 + wv)) * 32 + g * 2;
            gnp[gi] = s1[nn];
            gnp[gi + 1] = s2[nn];
        }
    }
}

__global__ __launch_bounds__(256) void gn_reduce(const float* __restrict__ gnp,
                                                 float* __restrict__ gn_stat) {
    int sid = blockIdx.x;              // (br*8+b)*16+g
    int bb = sid >> 4;
    int g = sid & 15;
    float s1 = 0.f, s2 = 0.f;
    int t = threadIdx.x;
#pragma unroll
    for (int j = 0; j < 2; ++j) {
        size_t gi = ((size_t)(bb * 512 + t * 2 + j)) * 32 + g * 2;
        s1 += gnp[gi];
        s2 += gnp[gi + 1];
    }
    block_reduce2(s1, s2);
    if (t == 0) {
        const float N = 4.f * 16384.f;
        float m = s1 / N;
        float var = s2 / N - m * m;
        gn_stat[sid * 2] = m;
        gn_stat[sid * 2 + 1] = rsqrtf(var + 1e-5f);
    }
}

__global__ __launch_bounds__(256) void gn_apply(float* __restrict__ out,
                                                const float* __restrict__ gn_stat,
                                                const float* __restrict__ g0,
                                                const float* __restrict__ b0,
                                                const float* __restrict__ g1,
                                                const float* __restrict__ b1) {
    int i = blockIdx.x * 256 + threadIdx.x;
    size_t base = (size_t)i * 4;
    int c = (int)((base >> 14) & 127);
    int b = (int)(base >> 21);
    int br = c >> 6;
    int co = c & 63;
    int sid = (br * 8 + b) * 16 + (co >> 2);
    float m = gn_stat[sid * 2];
    float rs = gn_stat[sid * 2 + 1];
    const float* gg = br ? g1 : g0;
    const float* bb = br ? b1 : b0;
    float ga = gg[co] * rs, be = bb[co] - m * gg[co] * rs;
    f32x4 v = *(f32x4*)&out[base];
    f32x4 r;
    r.x = fmaxf(fmaf(v.x, ga, be), 0.f);
    r.y = fmaxf(fmaf(v.y, ga, be), 0.f);
    r.z = fmaxf(fmaf(v.z, ga, be), 0.f);
    r.w = fmaxf(fmaf(v.w, ga, be), 0.f);
    *(f32x4*)&out[base] = r;
}

extern "C" void kernel_launch(void* const* d_in, const int* in_sizes, int n_in,
                              void* d_out, int out_size, void* d_ws, size_t ws_size,
                              hipStream_t stream) {
    const float* x       = (const float*)d_in[0];
    const float* off_w0  = (const float*)d_in[1];
    const float* bn_g0   = (const float*)d_in[3];
    const float* bn_b0   = (const float*)d_in[4];
    const float* conv_w0 = (const float*)d_in[5];
    const float* conv_b0 = (const float*)d_in[6];
    const float* gn_g0   = (const float*)d_in[7];
    const float* gn_b0   = (const float*)d_in[8];
    const float* off_w1  = (const float*)d_in[9];
    const float* bn_g1   = (const float*)d_in[11];
    const float* bn_b1   = (const float*)d_in[12];
    const float* conv_w1 = (const float*)d_in[13];
    const float* conv_b1 = (const float*)d_in[14];
    const float* gn_g1   = (const float*)d_in[15];
    const float* gn_b1   = (const float*)d_in[16];

    char* ws = (char*)d_ws;
    unsigned short* xt2  = (unsigned short*)(ws + XT_OFF);
    unsigned short* wrh2 = (unsigned short*)(ws + WRH_OFF);
    unsigned short* woh  = (unsigned short*)(ws + WOH_OFF);
    float* off_raw = (float*)(ws + RAW_OFF);
    float* bn_stat = (float*)(ws + BNS_OFF);
    float* gnp     = (float*)(ws + GNP_OFF);   // also bnp (early phase, stream-ordered)
    float* gn_stat = (float*)(ws + GNS_OFF);
    float* out = (float*)d_out;

    cvt_x<<<512, 256, 0, stream>>>(x, xt2);
    repack_all<<<360, 256, 0, stream>>>(conv_w0, conv_w1, off_w0, off_w1, wrh2, woh);
    off_mfma<<<1024, 256, 0, stream>>>(xt2, woh, off_raw, gnp);
    bn_fin2<<<18, 256, 0, stream>>>(gnp, bn_stat);
    snake8<<<2048, 256, 0, stream>>>(xt2, wrh2, conv_b0, conv_b1, off_raw, bn_stat,
                                     bn_g0, bn_b0, bn_g1, bn_b1, out, gnp);
    gn_reduce<<<256, 256, 0, stream>>>(gnp, gn_stat);
    gn_apply<<<16384, 256, 0, stream>>>(out, gn_stat, gn_g0, gn_b0, gn_g1, gn_b1);
}

// Round 14
// 121.831 us; speedup vs baseline: 1.5693x; 1.1195x over previous
//
#include <hip/hip_runtime.h>
#include <hip/hip_bf16.h>

#define HW 16384
#define NB 8
#define CIN 64

// snake tile geometry
#define WIN_R 18
#define WIN_C 26
#define CELLS (WIN_R * WIN_C)     // 468
#define CHUNKS (CELLS * 4)        // 1872 x 16B per ci-half
#define BUFB (CELLS * 64)         // 29952 bytes (one ci-half window)
#define WSLAB 18432               // shorts per (br,half) weight slab (9*4*64*8)

typedef short short8 __attribute__((ext_vector_type(8)));
typedef float f32x4 __attribute__((ext_vector_type(4)));
typedef _Float16 half8 __attribute__((ext_vector_type(8)));

// ---------------- ws layout (BYTE offsets) ----------------
// xt2     : [8][2][HW][32] f16    0           16,777,216
// wrh3    : [2][2][9][4][64][8]   16777216    147,456   (lane-linear)
// woh2    : [18][2][64][8] f16    16924672    36,864    (lane-linear)
// off_raw : [16][9][HW] f32       17000448    9,437,184
// bn_stat : [18][2] f32           26437632    144
// gnp     : [16][512][16][2] f32  26439168    1,048,576 (aliased bnp early)
// gn_stat : [256][2] f32          27487744    2,048
#define XT_OFF   0
#define WRH_OFF  16777216
#define WOH_OFF  16924672
#define RAW_OFF  17000448
#define BNS_OFF  26437632
#define GNP_OFF  26439168
#define GNS_OFF  27487744

__device__ inline unsigned short f2h(float v) {
    _Float16 h = (_Float16)v;
    unsigned short u; __builtin_memcpy(&u, &h, 2);
    return u;
}

// x [b][ci][px] f32  ->  xt2 [b][half][px][32ci] f16
__global__ __launch_bounds__(256) void cvt_x(const float* __restrict__ x,
                                             unsigned short* __restrict__ xt2) {
    int blk = blockIdx.x;              // 512 = 8b * 64 tiles(256px)
    int b = blk >> 6;
    int px0 = (blk & 63) * 256;
    int t = threadIdx.x;
    __shared__ unsigned short lds[256][72];
    const float* xb = x + (size_t)b * CIN * HW + px0;
    for (int ci = 0; ci < 64; ++ci)
        lds[t][ci] = f2h(xb[ci * HW + t]);
    __syncthreads();
    int wv = t >> 6, l = t & 63;
    int chunk = l & 7;                 // 8 chunks of 8 ci
    int half = chunk >> 2, ci8 = chunk & 3;
    for (int it = 0; it < 8; ++it) {
        int row = it * 32 + wv * 8 + (l >> 3);
        short8 v = *(const short8*)&lds[row][chunk * 8];
        unsigned short* dst = xt2 + ((size_t)(b * 2 + half) * HW + px0 + row) * 32 + ci8 * 8;
        *(short8*)dst = v;
    }
}

// merged weight repack (f16), both lane-linear for conflict-free LDS reads:
// wrh3: short idx = (br*2+half)*WSLAB + ((k*4+nn)*64 + lane)*8 + e
//       holds w[co=nn*16+(lane&15)][ci=half*32+(lane>>4)*8+e][k]
// woh2: short idx = ((s*2+nn)*64 + lane)*8 + e   (s = tap*2+half)
__global__ __launch_bounds__(256) void repack_all(const float* __restrict__ cw0,
                                                  const float* __restrict__ cw1,
                                                  const float* __restrict__ ow0,
                                                  const float* __restrict__ ow1,
                                                  unsigned short* __restrict__ wrh3,
                                                  unsigned short* __restrict__ woh2) {
    int i = blockIdx.x * 256 + threadIdx.x;
    if (i < 2 * 2 * WSLAB) {
        int slab = i / WSLAB;          // br*2 + half
        int br = slab >> 1, chalf = slab & 1;
        int rem = i - slab * WSLAB;
        int e = rem & 7;
        int lane = (rem >> 3) & 63;
        int nnk = rem >> 9;
        int nn = nnk & 3, k = nnk >> 2;
        int co = nn * 16 + (lane & 15);
        int ci = chalf * 32 + (lane >> 4) * 8 + e;
        const float* w = br ? cw1 : cw0;
        wrh3[i] = f2h(w[(co * 64 + ci) * 9 + k]);
    }
    int j = i - 2 * 2 * WSLAB;
    if (j >= 0 && j < 18 * 2 * 64 * 8) {
        int e = j & 7;
        int lane = (j >> 3) & 63;
        int nn = (j >> 9) & 1;
        int s = j >> 10;               // tap*2 + half
        int tap = s >> 1, chalf = s & 1;
        int co = nn * 16 + (lane & 15);
        int ci = chalf * 32 + (lane >> 4) * 8 + e;
        float v = 0.f;
        if (co < 9)       v = ow0[(co * 64 + ci) * 9 + tap];
        else if (co < 18) v = ow1[(co * 64 + ci) * 9 + tap];
        woh2[j] = f2h(v);
    }
}

// offset 3x3 conv MFMA (f16) + fused BN partials; weights staged to LDS.
__global__ __launch_bounds__(256, 4) void off_mfma(const unsigned short* __restrict__ xt2,
                                                   const unsigned short* __restrict__ woh2,
                                                   float* __restrict__ off_raw,
                                                   float* __restrict__ bnp) {
    __shared__ __align__(16) unsigned char wlds[36864];

    int b = blockIdx.x & 7;
    int tgrp = blockIdx.x >> 3;
    int t = threadIdx.x;
    int wid = t >> 6, l = t & 63;
    int tile = tgrp * 4 + wid;
    int l15 = l & 15, kg = l >> 4;
    int px0 = tile * 32;
    int h = px0 >> 7;
    int w0 = px0 & 127;

    // stage all weights (2304 chunks, linear)
#pragma unroll
    for (int it = 0; it < 9; ++it) {
        int d = it * 256 + t;
        __builtin_amdgcn_global_load_lds(
            (const __attribute__((address_space(1))) unsigned int*)(woh2 + d * 8),
            (__attribute__((address_space(3))) unsigned int*)(&wlds[0] + (it * 256 + wid * 64) * 16),
            16, 0, 0);
    }
    __syncthreads();

    f32x4 acc[2][2];
#pragma unroll
    for (int m = 0; m < 2; ++m)
#pragma unroll
        for (int nn = 0; nn < 2; ++nn) acc[m][nn] = (f32x4)(0.f);

#pragma unroll
    for (int s = 0; s < 18; ++s) {
        const int tap = s >> 1, half = s & 1;
        const int dy = tap / 3 - 1, dx = tap % 3 - 1;
        const unsigned short* plane = xt2 + (size_t)(b * 2 + half) * HW * 32;
        int y = h + dy;
        bool yok = (unsigned)y < 128u;
        int yc = min(max(y, 0), 127);
        half8 af[2];
#pragma unroll
        for (int m = 0; m < 2; ++m) {
            int xx = w0 + m * 16 + l15 + dx;
            bool ok = yok && ((unsigned)xx < 128u);
            int xc = min(max(xx, 0), 127);
            int o = yc * 128 + xc;
            half8 a = *(const half8*)&plane[(size_t)o * 32 + kg * 8];
            if (!ok) a = (half8)((_Float16)0.f);
            af[m] = a;
        }
        half8 bf[2];
#pragma unroll
        for (int nn = 0; nn < 2; ++nn)
            bf[nn] = *(const half8*)(wlds + ((s * 2 + nn) * 64 + l) * 16);
#pragma unroll
        for (int m = 0; m < 2; ++m)
#pragma unroll
            for (int nn = 0; nn < 2; ++nn)
                acc[m][nn] = __builtin_amdgcn_mfma_f32_16x16x32_f16(af[m], bf[nn], acc[m][nn], 0, 0, 0);
    }

    float s1[2] = {0.f, 0.f}, s2[2] = {0.f, 0.f};
#pragma unroll
    for (int m = 0; m < 2; ++m)
#pragma unroll
        for (int nn = 0; nn < 2; ++nn) {
            int co = nn * 16 + l15;
            f32x4 v = acc[m][nn];
            s1[nn] += v.x + v.y + v.z + v.w;
            s2[nn] += v.x * v.x + v.y * v.y + v.z * v.z + v.w * v.w;
            if (co < 18) {
                int br = co < 9 ? 0 : 1;
                int k = co - br * 9;
                int plane = (br * 8 + b) * 9 + k;
                int px = px0 + m * 16 + kg * 4;
                *(f32x4*)&off_raw[(size_t)plane * HW + px] = v;
            }
        }
#pragma unroll
    for (int off = 16; off <= 32; off <<= 1)
#pragma unroll
        for (int nn = 0; nn < 2; ++nn) {
            s1[nn] += __shfl_xor(s1[nn], off);
            s2[nn] += __shfl_xor(s2[nn], off);
        }
    if (l < 16) {
        int idx = ((l15 * 8 + b) * 512 + tile) * 2;
        bnp[idx] = s1[0]; bnp[idx + 1] = s2[0];
        if (l15 < 2) {
            int idx2 = (((16 + l15) * 8 + b) * 512 + tile) * 2;
            bnp[idx2] = s1[1]; bnp[idx2 + 1] = s2[1];
        }
    }
}

__device__ inline void block_reduce2(float& s1, float& s2) {
    __shared__ float sh[4][2];
#pragma unroll
    for (int o = 32; o > 0; o >>= 1) {
        s1 += __shfl_down(s1, o);
        s2 += __shfl_down(s2, o);
    }
    int wid = threadIdx.x >> 6, lane = threadIdx.x & 63;
    if (lane == 0) { sh[wid][0] = s1; sh[wid][1] = s2; }
    __syncthreads();
    if (threadIdx.x == 0)
        for (int i = 1; i < 4; ++i) { s1 += sh[i][0]; s2 += sh[i][1]; }
}

__global__ __launch_bounds__(256) void bn_fin2(const float* __restrict__ bnp,
                                               float* __restrict__ bn_stat) {
    int c = blockIdx.x;
    float s1 = 0.f, s2 = 0.f;
    for (int i = threadIdx.x; i < 4096; i += 256) {
        s1 += bnp[(c * 4096 + i) * 2];
        s2 += bnp[(c * 4096 + i) * 2 + 1];
    }
    block_reduce2(s1, s2);
    if (threadIdx.x == 0) {
        const float N = 8.f * 16384.f;
        float m = s1 / N;
        float var = s2 / N - m * m;
        bn_stat[c * 2] = m;
        bn_stat[c * 2 + 1] = rsqrtf(var + 1e-5f);
    }
}

// ---------------- snake conv: all-LDS loop, conflict-tuned --------------------
// R13: lane-linear weight slab (0-conflict reads, linear staging) + window
// swizzle g(c)=(c>>1)&3 (consecutive cells -> 8 banks, 2-way = free).
__global__ __launch_bounds__(256) void snake8(const unsigned short* __restrict__ xt2,
                                              const unsigned short* __restrict__ wrh3,
                                              const float* __restrict__ cb0,
                                              const float* __restrict__ cb1,
                                              const float* __restrict__ off_raw,
                                              const float* __restrict__ bn_stat,
                                              const float* __restrict__ bng0,
                                              const float* __restrict__ bnb0,
                                              const float* __restrict__ bng1,
                                              const float* __restrict__ bnb1,
                                              float* __restrict__ out,
                                              float* __restrict__ gnp) {
    __shared__ __align__(16) unsigned char winbuf[BUFB];      // 29952
    __shared__ __align__(16) unsigned char wbuf[36864];       // weights, one half
    __shared__ __align__(16) float fw_tab[4][9][32];          // 4608
    __shared__ int cell_tab[4][9][32];                        // 4608

    int n = blockIdx.x;
    int b = n & 7;
    int rest = n >> 3;
    int br = rest >> 7;
    int tile = rest & 127;
    int h0 = (tile >> 3) * 8;
    int w0 = (tile & 7) * 16;
    int t = threadIdx.x;
    int wv = t >> 6, l = t & 63;
    int l15 = l & 15, kg = l >> 4;
    int lp = l & 31;                   // own pixel (lanes 32-63 duplicate)

    int hrow = h0 + 2 * wv + (lp >> 4);
    int wcol = w0 + (lp & 15);
    int pxo = hrow * 128 + wcol;
    const float* bng = br ? bng1 : bng0;
    const float* bnb = br ? bnb1 : bnb0;

    f32x4 acc00 = (f32x4)(0.f), acc01 = (f32x4)(0.f), acc02 = (f32x4)(0.f), acc03 = (f32x4)(0.f);
    f32x4 acc10 = (f32x4)(0.f), acc11 = (f32x4)(0.f), acc12 = (f32x4)(0.f), acc13 = (f32x4)(0.f);

#pragma unroll 1
    for (int half = 0; half < 2; ++half) {
        if (half == 1) __syncthreads();          // all reads of prev LDS done

        // ---- stage this ci-half window (async, swizzled source g(c)=(c>>1)&3) ----
        {
            const unsigned short* plane = xt2 + (size_t)(b * 2 + half) * HW * 32;
#pragma unroll
            for (int it = 0; it < 8; ++it) {
                int d = it * 256 + wv * 64 + l;
                if (d < CHUNKS) {
                    int cell = d >> 2;
                    int ci8 = (d & 3) ^ ((cell >> 1) & 3);   // inverse swizzle on source
                    int s = cell / WIN_C;
                    int c = cell - s * WIN_C;
                    int row = min(max(h0 - 5 + s, 0), 127);
                    int col = min(max(w0 - 5 + c, 0), 127);
                    const unsigned short* src = plane + ((size_t)(row * 128 + col)) * 32 + ci8 * 8;
                    __builtin_amdgcn_global_load_lds(
                        (const __attribute__((address_space(1))) unsigned int*)src,
                        (__attribute__((address_space(3))) unsigned int*)(&winbuf[0] + (it * 256 + wv * 64) * 16),
                        16, 0, 0);
                }
            }
        }
        // ---- stage this ci-half weight slab (linear, 2304 chunks = 9 exact iters) ----
        {
            const unsigned short* slab = wrh3 + (size_t)(br * 2 + half) * WSLAB;
#pragma unroll
            for (int it = 0; it < 9; ++it) {
                int d = it * 256 + wv * 64 + l;
                __builtin_amdgcn_global_load_lds(
                    (const __attribute__((address_space(1))) unsigned int*)(slab + d * 8),
                    (__attribute__((address_space(3))) unsigned int*)(&wbuf[0] + (it * 256 + wv * 64) * 16),
                    16, 0, 0);
            }
        }

        // ---- prologue (first half only): offsets -> LDS desc tables ----
        if (half == 0) {
            float tt[9];
#pragma unroll
            for (int k = 0; k < 9; ++k) {
                float raw = off_raw[(size_t)((br * 8 + b) * 9 + k) * HW + pxo];
                float mn = bn_stat[(br * 9 + k) * 2];
                float rs = bn_stat[(br * 9 + k) * 2 + 1];
                int ch = br ? k + 9 : k;
                tt[k] = tanhf((raw - mn) * rs * bng[ch] + bnb[ch]);
            }
            float cum[9];
            cum[4] = 0.f;
            cum[3] = tt[3]; cum[2] = tt[2] + cum[3]; cum[1] = tt[1] + cum[2]; cum[0] = tt[0] + cum[1];
            cum[5] = tt[5]; cum[6] = cum[5] + tt[6]; cum[7] = cum[6] + tt[7]; cum[8] = cum[7] + tt[8];
#pragma unroll
            for (int k = 0; k < 9; ++k) {
                int cell0, cell1; float fw;
                if (br == 0) {
                    int col = min(max(wcol + k - 4, 0), 127);
                    float yc = fminf(fmaxf((float)hrow + cum[k], 0.f), 127.f);
                    int y0 = (int)floorf(yc);
                    int y1 = min(y0 + 1, 127);
                    fw = yc - (float)y0;
                    int cs = col - (w0 - 5);
                    cell0 = (y0 - (h0 - 5)) * WIN_C + cs;
                    cell1 = (y1 - (h0 - 5)) * WIN_C + cs;
                } else {
                    int row = min(max(h0 + (lp >> 4) * 0 + hrow - hrow + hrow + k - 4 - hrow + hrow, 0), 127);
                    // (kept simple below; the line above is never used)
                    row = min(max(hrow + k - 4, 0), 127);
                    float xcf = fminf(fmaxf((float)wcol + cum[k], 0.f), 127.f);
                    int x0 = (int)floorf(xcf);
                    int x1 = min(x0 + 1, 127);
                    fw = xcf - (float)x0;
                    int rs = (row - (h0 - 5)) * WIN_C;
                    cell0 = rs + (x0 - (w0 - 5));
                    cell1 = rs + (x1 - (w0 - 5));
                }
                if (l < 32) {
                    cell_tab[wv][k][lp] = cell0 | (cell1 << 16);
                    fw_tab[wv][k][lp] = fw;
                }
            }
        }

        __syncthreads();   // staging + (half0) desc tables complete

        // preload k=0 cell pair
        int cm0 = cell_tab[wv][0][l15];
        int cm1 = cell_tab[wv][0][l15 + 16];

#pragma unroll 1
        for (int k = 0; k < 9; ++k) {
            int kn = (k < 8) ? k + 1 : 8;
            int nc0 = cell_tab[wv][kn][l15];
            int nc1 = cell_tab[wv][kn][l15 + 16];

            float fw0 = fw_tab[wv][k][l15];
            float fw1 = fw_tab[wv][k][l15 + 16];
            half8 f0s = (half8)((_Float16)fw0);
            half8 f0c = (half8)((_Float16)(1.f - fw0));
            half8 f1s = (half8)((_Float16)fw1);
            half8 f1c = (half8)((_Float16)(1.f - fw1));

            int c00 = cm0 & 0xffff, c01 = ((unsigned)cm0) >> 16;
            int c10 = cm1 & 0xffff, c11 = ((unsigned)cm1) >> 16;
            int o00 = c00 * 64 + ((kg ^ ((c00 >> 1) & 3)) << 4);
            int o01 = c01 * 64 + ((kg ^ ((c01 >> 1) & 3)) << 4);
            int o10 = c10 * 64 + ((kg ^ ((c10 >> 1) & 3)) << 4);
            int o11 = c11 * 64 + ((kg ^ ((c11 >> 1) & 3)) << 4);

            half8 a00 = *(const half8*)(winbuf + o00);
            half8 a01 = *(const half8*)(winbuf + o01);
            half8 a10 = *(const half8*)(winbuf + o10);
            half8 a11 = *(const half8*)(winbuf + o11);
            half8 af00 = a00 * f0c;
            half8 af01 = a01 * f0s;
            half8 af10 = a10 * f1c;
            half8 af11 = a11 * f1s;

            // lane-linear weights: 0 conflicts, lane-constant addresses
            const unsigned char* wkb = wbuf + (k << 12) + l * 16;
            half8 bf0 = *(const half8*)(wkb + 0 * 1024);
            half8 bf1 = *(const half8*)(wkb + 1 * 1024);
            half8 bf2 = *(const half8*)(wkb + 2 * 1024);
            half8 bf3 = *(const half8*)(wkb + 3 * 1024);

            acc00 = __builtin_amdgcn_mfma_f32_16x16x32_f16(af00, bf0, acc00, 0, 0, 0);
            acc01 = __builtin_amdgcn_mfma_f32_16x16x32_f16(af00, bf1, acc01, 0, 0, 0);
            acc02 = __builtin_amdgcn_mfma_f32_16x16x32_f16(af00, bf2, acc02, 0, 0, 0);
            acc03 = __builtin_amdgcn_mfma_f32_16x16x32_f16(af00, bf3, acc03, 0, 0, 0);
            acc00 = __builtin_amdgcn_mfma_f32_16x16x32_f16(af01, bf0, acc00, 0, 0, 0);
            acc01 = __builtin_amdgcn_mfma_f32_16x16x32_f16(af01, bf1, acc01, 0, 0, 0);
            acc02 = __builtin_amdgcn_mfma_f32_16x16x32_f16(af01, bf2, acc02, 0, 0, 0);
            acc03 = __builtin_amdgcn_mfma_f32_16x16x32_f16(af01, bf3, acc03, 0, 0, 0);
            acc10 = __builtin_amdgcn_mfma_f32_16x16x32_f16(af10, bf0, acc10, 0, 0, 0);
            acc11 = __builtin_amdgcn_mfma_f32_16x16x32_f16(af10, bf1, acc11, 0, 0, 0);
            acc12 = __builtin_amdgcn_mfma_f32_16x16x32_f16(af10, bf2, acc12, 0, 0, 0);
            acc13 = __builtin_amdgcn_mfma_f32_16x16x32_f16(af10, bf3, acc13, 0, 0, 0);
            acc10 = __builtin_amdgcn_mfma_f32_16x16x32_f16(af11, bf0, acc10, 0, 0, 0);
            acc11 = __builtin_amdgcn_mfma_f32_16x16x32_f16(af11, bf1, acc11, 0, 0, 0);
            acc12 = __builtin_amdgcn_mfma_f32_16x16x32_f16(af11, bf2, acc12, 0, 0, 0);
            acc13 = __builtin_amdgcn_mfma_f32_16x16x32_f16(af11, bf3, acc13, 0, 0, 0);

            cm0 = nc0;
            cm1 = nc1;
        }
    }

    // epilogue: bias, store, GN partials
    f32x4 accA[2][4] = {{acc00, acc01, acc02, acc03}, {acc10, acc11, acc12, acc13}};
    const float* cb = br ? cb1 : cb0;
    float s1[4], s2[4];
#pragma unroll
    for (int nn = 0; nn < 4; ++nn) { s1[nn] = 0.f; s2[nn] = 0.f; }
#pragma unroll
    for (int m = 0; m < 2; ++m) {
        int hm = h0 + 2 * wv + m;
#pragma unroll
        for (int nn = 0; nn < 4; ++nn) {
            int co = nn * 16 + l15;
            float bias = cb[co];
            f32x4 v = accA[m][nn];
            f32x4 r;
            r.x = v.x + bias; r.y = v.y + bias; r.z = v.z + bias; r.w = v.w + bias;
            s1[nn] += r.x + r.y + r.z + r.w;
            s2[nn] += r.x * r.x + r.y * r.y + r.z * r.z + r.w * r.w;
            size_t base = ((size_t)(b * 128 + br * 64 + co) << 14) + hm * 128 + w0 + kg * 4;
            *(f32x4*)&out[base] = r;
        }
    }
#pragma unroll
    for (int off = 16; off <= 32; off <<= 1)
#pragma unroll
        for (int nn = 0; nn < 4; ++nn) {
            s1[nn] += __shfl_xor(s1[nn], off);
            s2[nn] += __shfl_xor(s2[nn], off);
        }
#pragma unroll
    for (int off = 1; off <= 2; off <<= 1)
#pragma unroll
        for (int nn = 0; nn < 4; ++nn) {
            s1[nn] += __shfl_xor(s1[nn], off);
            s2[nn] += __shfl_xor(s2[nn], off);
        }
    if ((l & 0x33) == 0) {             // lanes 0,4,8,12
#pragma unroll
        for (int nn = 0; nn < 4; ++nn) {
            int g = nn * 4 + (l >> 2);
            size_t gi = ((size_t)((br * 8 + b) * 512 + tile * 4 + wv)) * 32 + g * 2;
            gnp[gi] = s1[nn];
            gnp[gi + 1] = s2[nn];
        }
    }
}

__global__ __launch_bounds__(256) void gn_reduce(const float* __restrict__ gnp,
                                                 float* __restrict__ gn_stat) {
    int sid = blockIdx.x;              // (br*8+b)*16+g
    int bb = sid >> 4;
    int g = sid & 15;
    float s1 = 0.f, s2 = 0.f;
    int t = threadIdx.x;
#pragma unroll
    for (int j = 0; j < 2; ++j) {
        size_t gi = ((size_t)(bb * 512 + t * 2 + j)) * 32 + g * 2;
        s1 += gnp[gi];
        s2 += gnp[gi + 1];
    }
    block_reduce2(s1, s2);
    if (t == 0) {
        const float N = 4.f * 16384.f;
        float m = s1 / N;
        float var = s2 / N - m * m;
        gn_stat[sid * 2] = m;
        gn_stat[sid * 2 + 1] = rsqrtf(var + 1e-5f);
    }
}

__global__ __launch_bounds__(256) void gn_apply(float* __restrict__ out,
                                                const float* __restrict__ gn_stat,
                                                const float* __restrict__ g0,
                                                const float* __restrict__ b0,
                                                const float* __restrict__ g1,
                                                const float* __restrict__ b1) {
    int i = blockIdx.x * 256 + threadIdx.x;
    size_t base = (size_t)i * 4;
    int c = (int)((base >> 14) & 127);
    int b = (int)(base >> 21);
    int br = c >> 6;
    int co = c & 63;
    int sid = (br * 8 + b) * 16 + (co >> 2);
    float m = gn_stat[sid * 2];
    float rs = gn_stat[sid * 2 + 1];
    const float* gg = br ? g1 : g0;
    const float* bb = br ? b1 : b0;
    float ga = gg[co] * rs, be = bb[co] - m * gg[co] * rs;
    f32x4 v = *(f32x4*)&out[base];
    f32x4 r;
    r.x = fmaxf(fmaf(v.x, ga, be), 0.f);
    r.y = fmaxf(fmaf(v.y, ga, be), 0.f);
    r.z = fmaxf(fmaf(v.z, ga, be), 0.f);
    r.w = fmaxf(fmaf(v.w, ga, be), 0.f);
    *(f32x4*)&out[base] = r;
}

extern "C" void kernel_launch(void* const* d_in, const int* in_sizes, int n_in,
                              void* d_out, int out_size, void* d_ws, size_t ws_size,
                              hipStream_t stream) {
    const float* x       = (const float*)d_in[0];
    const float* off_w0  = (const float*)d_in[1];
    const float* bn_g0   = (const float*)d_in[3];
    const float* bn_b0   = (const float*)d_in[4];
    const float* conv_w0 = (const float*)d_in[5];
    const float* conv_b0 = (const float*)d_in[6];
    const float* gn_g0   = (const float*)d_in[7];
    const float* gn_b0   = (const float*)d_in[8];
    const float* off_w1  = (const float*)d_in[9];
    const float* bn_g1   = (const float*)d_in[11];
    const float* bn_b1   = (const float*)d_in[12];
    const float* conv_w1 = (const float*)d_in[13];
    const float* conv_b1 = (const float*)d_in[14];
    const float* gn_g1   = (const float*)d_in[15];
    const float* gn_b1   = (const float*)d_in[16];

    char* ws = (char*)d_ws;
    unsigned short* xt2  = (unsigned short*)(ws + XT_OFF);
    unsigned short* wrh3 = (unsigned short*)(ws + WRH_OFF);
    unsigned short* woh2 = (unsigned short*)(ws + WOH_OFF);
    float* off_raw = (float*)(ws + RAW_OFF);
    float* bn_stat = (float*)(ws + BNS_OFF);
    float* gnp     = (float*)(ws + GNP_OFF);   // also bnp (early phase, stream-ordered)
    float* gn_stat = (float*)(ws + GNS_OFF);
    float* out = (float*)d_out;

    cvt_x<<<512, 256, 0, stream>>>(x, xt2);
    repack_all<<<360, 256, 0, stream>>>(conv_w0, conv_w1, off_w0, off_w1, wrh3, woh2);
    off_mfma<<<1024, 256, 0, stream>>>(xt2, woh2, off_raw, gnp);
    bn_fin2<<<18, 256, 0, stream>>>(gnp, bn_stat);
    snake8<<<2048, 256, 0, stream>>>(xt2, wrh3, conv_b0, conv_b1, off_raw, bn_stat,
                                     bn_g0, bn_b0, bn_g1, bn_b1, out, gnp);
    gn_reduce<<<256, 256, 0, stream>>>(gnp, gn_stat);
    gn_apply<<<16384, 256, 0, stream>>>(out, gn_stat, gn_g0, gn_b0, gn_g1, gn_b1);
}

// Round 15
// 114.912 us; speedup vs baseline: 1.6638x; 1.0602x over previous
//
#include <hip/hip_runtime.h>
#include <hip/hip_bf16.h>

#define HW 16384
#define NB 8
#define CIN 64

// snake tile geometry
#define WIN_R 18
#define WIN_C 26
#define CELLS (WIN_R * WIN_C)     // 468
#define CHUNKS (CELLS * 4)        // 1872 x 16B per ci-half
#define BUFB (CELLS * 64)         // 29952 bytes (one ci-half window)
#define WSLAB 18432               // shorts per (br,half) weight slab (9*4*64*8)

typedef short short8 __attribute__((ext_vector_type(8)));
typedef float f32x4 __attribute__((ext_vector_type(4)));
typedef _Float16 half8 __attribute__((ext_vector_type(8)));

// ---------------- ws layout (BYTE offsets) ----------------
// xt2     : [8][2][HW][32] f16    0           16,777,216
// wrh3    : [2][2][9][4][64][8]   16777216    147,456   (lane-linear)
// woh2    : [18][2][64][8] f16    16924672    36,864    (lane-linear)
// off_raw : [16][9][HW] f32       17000448    9,437,184
// bn_stat : [18][2] f32           26437632    144
// gnp     : [16][512][16][2] f32  26439168    1,048,576 (aliased bnp early)
// gn_stat : [256][2] f32          27487744    2,048
#define XT_OFF   0
#define WRH_OFF  16777216
#define WOH_OFF  16924672
#define RAW_OFF  17000448
#define BNS_OFF  26437632
#define GNP_OFF  26439168
#define GNS_OFF  27487744

__device__ inline unsigned short f2h(float v) {
    _Float16 h = (_Float16)v;
    unsigned short u; __builtin_memcpy(&u, &h, 2);
    return u;
}

// x [b][ci][px] f32  ->  xt2 [b][half][px][32ci] f16
__global__ __launch_bounds__(256) void cvt_x(const float* __restrict__ x,
                                             unsigned short* __restrict__ xt2) {
    int blk = blockIdx.x;              // 512 = 8b * 64 tiles(256px)
    int b = blk >> 6;
    int px0 = (blk & 63) * 256;
    int t = threadIdx.x;
    __shared__ unsigned short lds[256][72];
    const float* xb = x + (size_t)b * CIN * HW + px0;
    for (int ci = 0; ci < 64; ++ci)
        lds[t][ci] = f2h(xb[ci * HW + t]);
    __syncthreads();
    int wv = t >> 6, l = t & 63;
    int chunk = l & 7;                 // 8 chunks of 8 ci
    int half = chunk >> 2, ci8 = chunk & 3;
    for (int it = 0; it < 8; ++it) {
        int row = it * 32 + wv * 8 + (l >> 3);
        short8 v = *(const short8*)&lds[row][chunk * 8];
        unsigned short* dst = xt2 + ((size_t)(b * 2 + half) * HW + px0 + row) * 32 + ci8 * 8;
        *(short8*)dst = v;
    }
}

// merged weight repack (f16), both lane-linear:
// wrh3: short idx = (br*2+half)*WSLAB + ((k*4+nn)*64 + lane)*8 + e
//       holds w[co=nn*16+(lane&15)][ci=half*32+(lane>>4)*8+e][k]
// woh2: short idx = ((s*2+nn)*64 + lane)*8 + e   (s = tap*2+half)
__global__ __launch_bounds__(256) void repack_all(const float* __restrict__ cw0,
                                                  const float* __restrict__ cw1,
                                                  const float* __restrict__ ow0,
                                                  const float* __restrict__ ow1,
                                                  unsigned short* __restrict__ wrh3,
                                                  unsigned short* __restrict__ woh2) {
    int i = blockIdx.x * 256 + threadIdx.x;
    if (i < 2 * 2 * WSLAB) {
        int slab = i / WSLAB;          // br*2 + half
        int br = slab >> 1, chalf = slab & 1;
        int rem = i - slab * WSLAB;
        int e = rem & 7;
        int lane = (rem >> 3) & 63;
        int nnk = rem >> 9;
        int nn = nnk & 3, k = nnk >> 2;
        int co = nn * 16 + (lane & 15);
        int ci = chalf * 32 + (lane >> 4) * 8 + e;
        const float* w = br ? cw1 : cw0;
        wrh3[i] = f2h(w[(co * 64 + ci) * 9 + k]);
    }
    int j = i - 2 * 2 * WSLAB;
    if (j >= 0 && j < 18 * 2 * 64 * 8) {
        int e = j & 7;
        int lane = (j >> 3) & 63;
        int nn = (j >> 9) & 1;
        int s = j >> 10;               // tap*2 + half
        int tap = s >> 1, chalf = s & 1;
        int co = nn * 16 + (lane & 15);
        int ci = chalf * 32 + (lane >> 4) * 8 + e;
        float v = 0.f;
        if (co < 9)       v = ow0[(co * 64 + ci) * 9 + tap];
        else if (co < 18) v = ow1[(co * 64 + ci) * 9 + tap];
        woh2[j] = f2h(v);
    }
}

// offset 3x3 conv MFMA (f16) + fused BN partials; weights staged to LDS.
__global__ __launch_bounds__(256, 4) void off_mfma(const unsigned short* __restrict__ xt2,
                                                   const unsigned short* __restrict__ woh2,
                                                   float* __restrict__ off_raw,
                                                   float* __restrict__ bnp) {
    __shared__ __align__(16) unsigned char wlds[36864];

    int b = blockIdx.x & 7;
    int tgrp = blockIdx.x >> 3;
    int t = threadIdx.x;
    int wid = t >> 6, l = t & 63;
    int tile = tgrp * 4 + wid;
    int l15 = l & 15, kg = l >> 4;
    int px0 = tile * 32;
    int h = px0 >> 7;
    int w0 = px0 & 127;

    // stage all weights (2304 chunks, linear)
#pragma unroll
    for (int it = 0; it < 9; ++it) {
        int d = it * 256 + t;
        __builtin_amdgcn_global_load_lds(
            (const __attribute__((address_space(1))) unsigned int*)(woh2 + d * 8),
            (__attribute__((address_space(3))) unsigned int*)(&wlds[0] + (it * 256 + wid * 64) * 16),
            16, 0, 0);
    }
    __syncthreads();

    f32x4 acc[2][2];
#pragma unroll
    for (int m = 0; m < 2; ++m)
#pragma unroll
        for (int nn = 0; nn < 2; ++nn) acc[m][nn] = (f32x4)(0.f);

#pragma unroll
    for (int s = 0; s < 18; ++s) {
        const int tap = s >> 1, half = s & 1;
        const int dy = tap / 3 - 1, dx = tap % 3 - 1;
        const unsigned short* plane = xt2 + (size_t)(b * 2 + half) * HW * 32;
        int y = h + dy;
        bool yok = (unsigned)y < 128u;
        int yc = min(max(y, 0), 127);
        half8 af[2];
#pragma unroll
        for (int m = 0; m < 2; ++m) {
            int xx = w0 + m * 16 + l15 + dx;
            bool ok = yok && ((unsigned)xx < 128u);
            int xc = min(max(xx, 0), 127);
            int o = yc * 128 + xc;
            half8 a = *(const half8*)&plane[(size_t)o * 32 + kg * 8];
            if (!ok) a = (half8)((_Float16)0.f);
            af[m] = a;
        }
        half8 bf[2];
#pragma unroll
        for (int nn = 0; nn < 2; ++nn)
            bf[nn] = *(const half8*)(wlds + ((s * 2 + nn) * 64 + l) * 16);
#pragma unroll
        for (int m = 0; m < 2; ++m)
#pragma unroll
            for (int nn = 0; nn < 2; ++nn)
                acc[m][nn] = __builtin_amdgcn_mfma_f32_16x16x32_f16(af[m], bf[nn], acc[m][nn], 0, 0, 0);
    }

    float s1[2] = {0.f, 0.f}, s2[2] = {0.f, 0.f};
#pragma unroll
    for (int m = 0; m < 2; ++m)
#pragma unroll
        for (int nn = 0; nn < 2; ++nn) {
            int co = nn * 16 + l15;
            f32x4 v = acc[m][nn];
            s1[nn] += v.x + v.y + v.z + v.w;
            s2[nn] += v.x * v.x + v.y * v.y + v.z * v.z + v.w * v.w;
            if (co < 18) {
                int br = co < 9 ? 0 : 1;
                int k = co - br * 9;
                int plane = (br * 8 + b) * 9 + k;
                int px = px0 + m * 16 + kg * 4;
                *(f32x4*)&off_raw[(size_t)plane * HW + px] = v;
            }
        }
#pragma unroll
    for (int off = 16; off <= 32; off <<= 1)
#pragma unroll
        for (int nn = 0; nn < 2; ++nn) {
            s1[nn] += __shfl_xor(s1[nn], off);
            s2[nn] += __shfl_xor(s2[nn], off);
        }
    if (l < 16) {
        int idx = ((l15 * 8 + b) * 512 + tile) * 2;
        bnp[idx] = s1[0]; bnp[idx + 1] = s2[0];
        if (l15 < 2) {
            int idx2 = (((16 + l15) * 8 + b) * 512 + tile) * 2;
            bnp[idx2] = s1[1]; bnp[idx2 + 1] = s2[1];
        }
    }
}

__device__ inline void block_reduce2(float& s1, float& s2) {
    __shared__ float sh[4][2];
#pragma unroll
    for (int o = 32; o > 0; o >>= 1) {
        s1 += __shfl_down(s1, o);
        s2 += __shfl_down(s2, o);
    }
    int wid = threadIdx.x >> 6, lane = threadIdx.x & 63;
    if (lane == 0) { sh[wid][0] = s1; sh[wid][1] = s2; }
    __syncthreads();
    if (threadIdx.x == 0)
        for (int i = 1; i < 4; ++i) { s1 += sh[i][0]; s2 += sh[i][1]; }
}

__global__ __launch_bounds__(256) void bn_fin2(const float* __restrict__ bnp,
                                               float* __restrict__ bn_stat) {
    int c = blockIdx.x;
    float s1 = 0.f, s2 = 0.f;
    for (int i = threadIdx.x; i < 4096; i += 256) {
        s1 += bnp[(c * 4096 + i) * 2];
        s2 += bnp[(c * 4096 + i) * 2 + 1];
    }
    block_reduce2(s1, s2);
    if (threadIdx.x == 0) {
        const float N = 8.f * 16384.f;
        float m = s1 / N;
        float var = s2 / N - m * m;
        bn_stat[c * 2] = m;
        bn_stat[c * 2 + 1] = rsqrtf(var + 1e-5f);
    }
}

// ---------------- snake conv: slim-LDS, register-prefetched weights ----------
// R14: weight slab removed from LDS (was 36.9KB). B-fragments for iteration
// (half,k+1) are prefetched into registers from global (lane-linear, coalesced)
// while (half,k) computes -> L2 latency hidden, LDS = 39.2KB -> 4 blocks/CU.
__global__ __launch_bounds__(256) void snake9(const unsigned short* __restrict__ xt2,
                                              const unsigned short* __restrict__ wrh3,
                                              const float* __restrict__ cb0,
                                              const float* __restrict__ cb1,
                                              const float* __restrict__ off_raw,
                                              const float* __restrict__ bn_stat,
                                              const float* __restrict__ bng0,
                                              const float* __restrict__ bnb0,
                                              const float* __restrict__ bng1,
                                              const float* __restrict__ bnb1,
                                              float* __restrict__ out,
                                              float* __restrict__ gnp) {
    __shared__ __align__(16) unsigned char winbuf[BUFB];      // 29952
    __shared__ __align__(16) float fw_tab[4][9][32];          // 4608
    __shared__ int cell_tab[4][9][32];                        // 4608

    int n = blockIdx.x;
    int b = n & 7;
    int rest = n >> 3;
    int br = rest >> 7;
    int tile = rest & 127;
    int h0 = (tile >> 3) * 8;
    int w0 = (tile & 7) * 16;
    int t = threadIdx.x;
    int wv = t >> 6, l = t & 63;
    int l15 = l & 15, kg = l >> 4;
    int lp = l & 31;                   // own pixel (lanes 32-63 duplicate)

    int hrow = h0 + 2 * wv + (lp >> 4);
    int wcol = w0 + (lp & 15);
    int pxo = hrow * 128 + wcol;
    const float* bng = br ? bng1 : bng0;
    const float* bnb = br ? bnb1 : bnb0;

    f32x4 acc00 = (f32x4)(0.f), acc01 = (f32x4)(0.f), acc02 = (f32x4)(0.f), acc03 = (f32x4)(0.f);
    f32x4 acc10 = (f32x4)(0.f), acc11 = (f32x4)(0.f), acc12 = (f32x4)(0.f), acc13 = (f32x4)(0.f);

    // initial weight prefetch: (half=0, k=0)
    const unsigned short* wbase = wrh3 + (size_t)(br * 2) * WSLAB;
    half8 nb0 = *(const half8*)(wbase + 0 * 512 + l * 8);
    half8 nb1 = *(const half8*)(wbase + 1 * 512 + l * 8);
    half8 nb2 = *(const half8*)(wbase + 2 * 512 + l * 8);
    half8 nb3 = *(const half8*)(wbase + 3 * 512 + l * 8);

#pragma unroll 1
    for (int half = 0; half < 2; ++half) {
        if (half == 1) __syncthreads();          // all reads of prev window done

        // ---- stage this ci-half window (async, swizzled source g(c)=(c>>1)&3) ----
        {
            const unsigned short* plane = xt2 + (size_t)(b * 2 + half) * HW * 32;
#pragma unroll
            for (int it = 0; it < 8; ++it) {
                int d = it * 256 + wv * 64 + l;
                if (d < CHUNKS) {
                    int cell = d >> 2;
                    int ci8 = (d & 3) ^ ((cell >> 1) & 3);   // inverse swizzle on source
                    int s = cell / WIN_C;
                    int c = cell - s * WIN_C;
                    int row = min(max(h0 - 5 + s, 0), 127);
                    int col = min(max(w0 - 5 + c, 0), 127);
                    const unsigned short* src = plane + ((size_t)(row * 128 + col)) * 32 + ci8 * 8;
                    __builtin_amdgcn_global_load_lds(
                        (const __attribute__((address_space(1))) unsigned int*)src,
                        (__attribute__((address_space(3))) unsigned int*)(&winbuf[0] + (it * 256 + wv * 64) * 16),
                        16, 0, 0);
                }
            }
        }

        // ---- prologue (first half only): offsets -> LDS desc tables ----
        if (half == 0) {
            float tt[9];
#pragma unroll
            for (int k = 0; k < 9; ++k) {
                float raw = off_raw[(size_t)((br * 8 + b) * 9 + k) * HW + pxo];
                float mn = bn_stat[(br * 9 + k) * 2];
                float rs = bn_stat[(br * 9 + k) * 2 + 1];
                int ch = br ? k + 9 : k;
                tt[k] = tanhf((raw - mn) * rs * bng[ch] + bnb[ch]);
            }
            float cum[9];
            cum[4] = 0.f;
            cum[3] = tt[3]; cum[2] = tt[2] + cum[3]; cum[1] = tt[1] + cum[2]; cum[0] = tt[0] + cum[1];
            cum[5] = tt[5]; cum[6] = cum[5] + tt[6]; cum[7] = cum[6] + tt[7]; cum[8] = cum[7] + tt[8];
#pragma unroll
            for (int k = 0; k < 9; ++k) {
                int cell0, cell1; float fw;
                if (br == 0) {
                    int col = min(max(wcol + k - 4, 0), 127);
                    float yc = fminf(fmaxf((float)hrow + cum[k], 0.f), 127.f);
                    int y0 = (int)floorf(yc);
                    int y1 = min(y0 + 1, 127);
                    fw = yc - (float)y0;
                    int cs = col - (w0 - 5);
                    cell0 = (y0 - (h0 - 5)) * WIN_C + cs;
                    cell1 = (y1 - (h0 - 5)) * WIN_C + cs;
                } else {
                    int row = min(max(hrow + k - 4, 0), 127);
                    float xcf = fminf(fmaxf((float)wcol + cum[k], 0.f), 127.f);
                    int x0 = (int)floorf(xcf);
                    int x1 = min(x0 + 1, 127);
                    fw = xcf - (float)x0;
                    int rs = (row - (h0 - 5)) * WIN_C;
                    cell0 = rs + (x0 - (w0 - 5));
                    cell1 = rs + (x1 - (w0 - 5));
                }
                if (l < 32) {
                    cell_tab[wv][k][lp] = cell0 | (cell1 << 16);
                    fw_tab[wv][k][lp] = fw;
                }
            }
        }

        __syncthreads();   // staging + (half0) desc tables complete

        // preload k=0 cell pair
        int cm0 = cell_tab[wv][0][l15];
        int cm1 = cell_tab[wv][0][l15 + 16];

#pragma unroll 1
        for (int k = 0; k < 9; ++k) {
            // current weights = prefetched
            half8 cb0f = nb0, cb1f = nb1, cb2f = nb2, cb3f = nb3;

            // issue next-iteration weight prefetch (crosses half boundary)
            int kn2 = (k < 8) ? k + 1 : ((half == 0) ? 0 : 8);
            int hn2 = (k < 8) ? half : 1;
            const unsigned short* wn = wrh3 + (size_t)(br * 2 + hn2) * WSLAB
                                     + (size_t)(kn2 * 4) * 512 + l * 8;
            nb0 = *(const half8*)(wn + 0 * 512);
            nb1 = *(const half8*)(wn + 1 * 512);
            nb2 = *(const half8*)(wn + 2 * 512);
            nb3 = *(const half8*)(wn + 3 * 512);

            // next-k cell prefetch
            int knc = (k < 8) ? k + 1 : 8;
            int nc0 = cell_tab[wv][knc][l15];
            int nc1 = cell_tab[wv][knc][l15 + 16];

            float fw0 = fw_tab[wv][k][l15];
            float fw1 = fw_tab[wv][k][l15 + 16];
            half8 f0s = (half8)((_Float16)fw0);
            half8 f0c = (half8)((_Float16)(1.f - fw0));
            half8 f1s = (half8)((_Float16)fw1);
            half8 f1c = (half8)((_Float16)(1.f - fw1));

            int c00 = cm0 & 0xffff, c01 = ((unsigned)cm0) >> 16;
            int c10 = cm1 & 0xffff, c11 = ((unsigned)cm1) >> 16;
            int o00 = c00 * 64 + ((kg ^ ((c00 >> 1) & 3)) << 4);
            int o01 = c01 * 64 + ((kg ^ ((c01 >> 1) & 3)) << 4);
            int o10 = c10 * 64 + ((kg ^ ((c10 >> 1) & 3)) << 4);
            int o11 = c11 * 64 + ((kg ^ ((c11 >> 1) & 3)) << 4);

            half8 a00 = *(const half8*)(winbuf + o00);
            half8 a01 = *(const half8*)(winbuf + o01);
            half8 a10 = *(const half8*)(winbuf + o10);
            half8 a11 = *(const half8*)(winbuf + o11);
            half8 af00 = a00 * f0c;
            half8 af01 = a01 * f0s;
            half8 af10 = a10 * f1c;
            half8 af11 = a11 * f1s;

            acc00 = __builtin_amdgcn_mfma_f32_16x16x32_f16(af00, cb0f, acc00, 0, 0, 0);
            acc01 = __builtin_amdgcn_mfma_f32_16x16x32_f16(af00, cb1f, acc01, 0, 0, 0);
            acc02 = __builtin_amdgcn_mfma_f32_16x16x32_f16(af00, cb2f, acc02, 0, 0, 0);
            acc03 = __builtin_amdgcn_mfma_f32_16x16x32_f16(af00, cb3f, acc03, 0, 0, 0);
            acc00 = __builtin_amdgcn_mfma_f32_16x16x32_f16(af01, cb0f, acc00, 0, 0, 0);
            acc01 = __builtin_amdgcn_mfma_f32_16x16x32_f16(af01, cb1f, acc01, 0, 0, 0);
            acc02 = __builtin_amdgcn_mfma_f32_16x16x32_f16(af01, cb2f, acc02, 0, 0, 0);
            acc03 = __builtin_amdgcn_mfma_f32_16x16x32_f16(af01, cb3f, acc03, 0, 0, 0);
            acc10 = __builtin_amdgcn_mfma_f32_16x16x32_f16(af10, cb0f, acc10, 0, 0, 0);
            acc11 = __builtin_amdgcn_mfma_f32_16x16x32_f16(af10, cb1f, acc11, 0, 0, 0);
            acc12 = __builtin_amdgcn_mfma_f32_16x16x32_f16(af10, cb2f, acc12, 0, 0, 0);
            acc13 = __builtin_amdgcn_mfma_f32_16x16x32_f16(af10, cb3f, acc13, 0, 0, 0);
            acc10 = __builtin_amdgcn_mfma_f32_16x16x32_f16(af11, cb0f, acc10, 0, 0, 0);
            acc11 = __builtin_amdgcn_mfma_f32_16x16x32_f16(af11, cb1f, acc11, 0, 0, 0);
            acc12 = __builtin_amdgcn_mfma_f32_16x16x32_f16(af11, cb2f, acc12, 0, 0, 0);
            acc13 = __builtin_amdgcn_mfma_f32_16x16x32_f16(af11, cb3f, acc13, 0, 0, 0);

            cm0 = nc0;
            cm1 = nc1;
        }
    }

    // epilogue: bias, store, GN partials
    f32x4 accA[2][4] = {{acc00, acc01, acc02, acc03}, {acc10, acc11, acc12, acc13}};
    const float* cb = br ? cb1 : cb0;
    float s1[4], s2[4];
#pragma unroll
    for (int nn = 0; nn < 4; ++nn) { s1[nn] = 0.f; s2[nn] = 0.f; }
#pragma unroll
    for (int m = 0; m < 2; ++m) {
        int hm = h0 + 2 * wv + m;
#pragma unroll
        for (int nn = 0; nn < 4; ++nn) {
            int co = nn * 16 + l15;
            float bias = cb[co];
            f32x4 v = accA[m][nn];
            f32x4 r;
            r.x = v.x + bias; r.y = v.y + bias; r.z = v.z + bias; r.w = v.w + bias;
            s1[nn] += r.x + r.y + r.z + r.w;
            s2[nn] += r.x * r.x + r.y * r.y + r.z * r.z + r.w * r.w;
            size_t base = ((size_t)(b * 128 + br * 64 + co) << 14) + hm * 128 + w0 + kg * 4;
            *(f32x4*)&out[base] = r;
        }
    }
#pragma unroll
    for (int off = 16; off <= 32; off <<= 1)
#pragma unroll
        for (int nn = 0; nn < 4; ++nn) {
            s1[nn] += __shfl_xor(s1[nn], off);
            s2[nn] += __shfl_xor(s2[nn], off);
        }
#pragma unroll
    for (int off = 1; off <= 2; off <<= 1)
#pragma unroll
        for (int nn = 0; nn < 4; ++nn) {
            s1[nn] += __shfl_xor(s1[nn], off);
            s2[nn] += __shfl_xor(s2[nn], off);
        }
    if ((l & 0x33) == 0) {             // lanes 0,4,8,12
#pragma unroll
        for (int nn = 0; nn < 4; ++nn) {
            int g = nn * 4 + (l >> 2);
            size_t gi = ((size_t)((br * 8 + b) * 512 + tile * 4 + wv)) * 32 + g * 2;
            gnp[gi] = s1[nn];
            gnp[gi + 1] = s2[nn];
        }
    }
}

__global__ __launch_bounds__(256) void gn_reduce(const float* __restrict__ gnp,
                                                 float* __restrict__ gn_stat) {
    int sid = blockIdx.x;              // (br*8+b)*16+g
    int bb = sid >> 4;
    int g = sid & 15;
    float s1 = 0.f, s2 = 0.f;
    int t = threadIdx.x;
#pragma unroll
    for (int j = 0; j < 2; ++j) {
        size_t gi = ((size_t)(bb * 512 + t * 2 + j)) * 32 + g * 2;
        s1 += gnp[gi];
        s2 += gnp[gi + 1];
    }
    block_reduce2(s1, s2);
    if (t == 0) {
        const float N = 4.f * 16384.f;
        float m = s1 / N;
        float var = s2 / N - m * m;
        gn_stat[sid * 2] = m;
        gn_stat[sid * 2 + 1] = rsqrtf(var + 1e-5f);
    }
}

__global__ __launch_bounds__(256) void gn_apply(float* __restrict__ out,
                                                const float* __restrict__ gn_stat,
                                                const float* __restrict__ g0,
                                                const float* __restrict__ b0,
                                                const float* __restrict__ g1,
                                                const float* __restrict__ b1) {
    int i = blockIdx.x * 256 + threadIdx.x;
    size_t base = (size_t)i * 4;
    int c = (int)((base >> 14) & 127);
    int b = (int)(base >> 21);
    int br = c >> 6;
    int co = c & 63;
    int sid = (br * 8 + b) * 16 + (co >> 2);
    float m = gn_stat[sid * 2];
    float rs = gn_stat[sid * 2 + 1];
    const float* gg = br ? g1 : g0;
    const float* bb = br ? b1 : b0;
    float ga = gg[co] * rs, be = bb[co] - m * gg[co] * rs;
    f32x4 v = *(f32x4*)&out[base];
    f32x4 r;
    r.x = fmaxf(fmaf(v.x, ga, be), 0.f);
    r.y = fmaxf(fmaf(v.y, ga, be), 0.f);
    r.z = fmaxf(fmaf(v.z, ga, be), 0.f);
    r.w = fmaxf(fmaf(v.w, ga, be), 0.f);
    *(f32x4*)&out[base] = r;
}

extern "C" void kernel_launch(void* const* d_in, const int* in_sizes, int n_in,
                              void* d_out, int out_size, void* d_ws, size_t ws_size,
                              hipStream_t stream) {
    const float* x       = (const float*)d_in[0];
    const float* off_w0  = (const float*)d_in[1];
    const float* bn_g0   = (const float*)d_in[3];
    const float* bn_b0   = (const float*)d_in[4];
    const float* conv_w0 = (const float*)d_in[5];
    const float* conv_b0 = (const float*)d_in[6];
    const float* gn_g0   = (const float*)d_in[7];
    const float* gn_b0   = (const float*)d_in[8];
    const float* off_w1  = (const float*)d_in[9];
    const float* bn_g1   = (const float*)d_in[11];
    const float* bn_b1   = (const float*)d_in[12];
    const float* conv_w1 = (const float*)d_in[13];
    const float* conv_b1 = (const float*)d_in[14];
    const float* gn_g1   = (const float*)d_in[15];
    const float* gn_b1   = (const float*)d_in[16];

    char* ws = (char*)d_ws;
    unsigned short* xt2  = (unsigned short*)(ws + XT_OFF);
    unsigned short* wrh3 = (unsigned short*)(ws + WRH_OFF);
    unsigned short* woh2 = (unsigned short*)(ws + WOH_OFF);
    float* off_raw = (float*)(ws + RAW_OFF);
    float* bn_stat = (float*)(ws + BNS_OFF);
    float* gnp     = (float*)(ws + GNP_OFF);   // also bnp (early phase, stream-ordered)
    float* gn_stat = (float*)(ws + GNS_OFF);
    float* out = (float*)d_out;

    cvt_x<<<512, 256, 0, stream>>>(x, xt2);
    repack_all<<<360, 256, 0, stream>>>(conv_w0, conv_w1, off_w0, off_w1, wrh3, woh2);
    off_mfma<<<1024, 256, 0, stream>>>(xt2, woh2, off_raw, gnp);
    bn_fin2<<<18, 256, 0, stream>>>(gnp, bn_stat);
    snake9<<<2048, 256, 0, stream>>>(xt2, wrh3, conv_b0, conv_b1, off_raw, bn_stat,
                                     bn_g0, bn_b0, bn_g1, bn_b1, out, gnp);
    gn_reduce<<<256, 256, 0, stream>>>(gnp, gn_stat);
    gn_apply<<<16384, 256, 0, stream>>>(out, gn_stat, gn_g0, gn_b0, gn_g1, gn_b1);
}

// Round 16
// 110.925 us; speedup vs baseline: 1.7236x; 1.0359x over previous
//
#include <hip/hip_runtime.h>
#include <hip/hip_bf16.h>

#define HW 16384
#define NB 8
#define CIN 64

// snake tile geometry
#define WIN_R 18
#define WIN_C 26
#define CELLS (WIN_R * WIN_C)     // 468
#define CHUNKS (CELLS * 4)        // 1872 x 16B per ci-half
#define BUFB (CELLS * 64)         // 29952 bytes (one ci-half window)
#define WSLAB 18432               // shorts per (br,half) weight slab (9*4*64*8)

typedef short short8 __attribute__((ext_vector_type(8)));
typedef float f32x4 __attribute__((ext_vector_type(4)));
typedef _Float16 half8 __attribute__((ext_vector_type(8)));

// ---------------- ws layout (BYTE offsets) ----------------
#define XT_OFF   0
#define WRH_OFF  16777216
#define WOH_OFF  16924672
#define RAW_OFF  17000448
#define BNS_OFF  26437632
#define GNP_OFF  26439168
#define GNS_OFF  27487744

__device__ inline unsigned short f2h(float v) {
    _Float16 h = (_Float16)v;
    unsigned short u; __builtin_memcpy(&u, &h, 2);
    return u;
}

// x [b][ci][px] f32  ->  xt2 [b][half][px][32ci] f16
__global__ __launch_bounds__(256) void cvt_x(const float* __restrict__ x,
                                             unsigned short* __restrict__ xt2) {
    int blk = blockIdx.x;              // 512 = 8b * 64 tiles(256px)
    int b = blk >> 6;
    int px0 = (blk & 63) * 256;
    int t = threadIdx.x;
    __shared__ unsigned short lds[256][72];
    const float* xb = x + (size_t)b * CIN * HW + px0;
    for (int ci = 0; ci < 64; ++ci)
        lds[t][ci] = f2h(xb[ci * HW + t]);
    __syncthreads();
    int wv = t >> 6, l = t & 63;
    int chunk = l & 7;                 // 8 chunks of 8 ci
    int half = chunk >> 2, ci8 = chunk & 3;
    for (int it = 0; it < 8; ++it) {
        int row = it * 32 + wv * 8 + (l >> 3);
        short8 v = *(const short8*)&lds[row][chunk * 8];
        unsigned short* dst = xt2 + ((size_t)(b * 2 + half) * HW + px0 + row) * 32 + ci8 * 8;
        *(short8*)dst = v;
    }
}

// merged weight repack (f16), both lane-linear:
// wrh3: short idx = (br*2+half)*WSLAB + ((k*4+nn)*64 + lane)*8 + e
// woh2: short idx = ((s*2+nn)*64 + lane)*8 + e   (s = tap*2+half)
__global__ __launch_bounds__(256) void repack_all(const float* __restrict__ cw0,
                                                  const float* __restrict__ cw1,
                                                  const float* __restrict__ ow0,
                                                  const float* __restrict__ ow1,
                                                  unsigned short* __restrict__ wrh3,
                                                  unsigned short* __restrict__ woh2) {
    int i = blockIdx.x * 256 + threadIdx.x;
    if (i < 2 * 2 * WSLAB) {
        int slab = i / WSLAB;          // br*2 + half
        int br = slab >> 1, chalf = slab & 1;
        int rem = i - slab * WSLAB;
        int e = rem & 7;
        int lane = (rem >> 3) & 63;
        int nnk = rem >> 9;
        int nn = nnk & 3, k = nnk >> 2;
        int co = nn * 16 + (lane & 15);
        int ci = chalf * 32 + (lane >> 4) * 8 + e;
        const float* w = br ? cw1 : cw0;
        wrh3[i] = f2h(w[(co * 64 + ci) * 9 + k]);
    }
    int j = i - 2 * 2 * WSLAB;
    if (j >= 0 && j < 18 * 2 * 64 * 8) {
        int e = j & 7;
        int lane = (j >> 3) & 63;
        int nn = (j >> 9) & 1;
        int s = j >> 10;               // tap*2 + half
        int tap = s >> 1, chalf = s & 1;
        int co = nn * 16 + (lane & 15);
        int ci = chalf * 32 + (lane >> 4) * 8 + e;
        float v = 0.f;
        if (co < 9)       v = ow0[(co * 64 + ci) * 9 + tap];
        else if (co < 18) v = ow1[(co * 64 + ci) * 9 + tap];
        woh2[j] = f2h(v);
    }
}

// offset 3x3 conv MFMA (f16) + fused BN partials; weights staged to LDS.
__global__ __launch_bounds__(256, 4) void off_mfma(const unsigned short* __restrict__ xt2,
                                                   const unsigned short* __restrict__ woh2,
                                                   float* __restrict__ off_raw,
                                                   float* __restrict__ bnp) {
    __shared__ __align__(16) unsigned char wlds[36864];

    int b = blockIdx.x & 7;
    int tgrp = blockIdx.x >> 3;
    int t = threadIdx.x;
    int wid = t >> 6, l = t & 63;
    int tile = tgrp * 4 + wid;
    int l15 = l & 15, kg = l >> 4;
    int px0 = tile * 32;
    int h = px0 >> 7;
    int w0 = px0 & 127;

    // stage all weights (2304 chunks, linear)
#pragma unroll
    for (int it = 0; it < 9; ++it) {
        int d = it * 256 + t;
        __builtin_amdgcn_global_load_lds(
            (const __attribute__((address_space(1))) unsigned int*)(woh2 + d * 8),
            (__attribute__((address_space(3))) unsigned int*)(&wlds[0] + (it * 256 + wid * 64) * 16),
            16, 0, 0);
    }
    __syncthreads();

    f32x4 acc[2][2];
#pragma unroll
    for (int m = 0; m < 2; ++m)
#pragma unroll
        for (int nn = 0; nn < 2; ++nn) acc[m][nn] = (f32x4)(0.f);

#pragma unroll
    for (int s = 0; s < 18; ++s) {
        const int tap = s >> 1, half = s & 1;
        const int dy = tap / 3 - 1, dx = tap % 3 - 1;
        const unsigned short* plane = xt2 + (size_t)(b * 2 + half) * HW * 32;
        int y = h + dy;
        bool yok = (unsigned)y < 128u;
        int yc = min(max(y, 0), 127);
        half8 af[2];
#pragma unroll
        for (int m = 0; m < 2; ++m) {
            int xx = w0 + m * 16 + l15 + dx;
            bool ok = yok && ((unsigned)xx < 128u);
            int xc = min(max(xx, 0), 127);
            int o = yc * 128 + xc;
            half8 a = *(const half8*)&plane[(size_t)o * 32 + kg * 8];
            if (!ok) a = (half8)((_Float16)0.f);
            af[m] = a;
        }
        half8 bf[2];
#pragma unroll
        for (int nn = 0; nn < 2; ++nn)
            bf[nn] = *(const half8*)(wlds + ((s * 2 + nn) * 64 + l) * 16);
#pragma unroll
        for (int m = 0; m < 2; ++m)
#pragma unroll
            for (int nn = 0; nn < 2; ++nn)
                acc[m][nn] = __builtin_amdgcn_mfma_f32_16x16x32_f16(af[m], bf[nn], acc[m][nn], 0, 0, 0);
    }

    float s1[2] = {0.f, 0.f}, s2[2] = {0.f, 0.f};
#pragma unroll
    for (int m = 0; m < 2; ++m)
#pragma unroll
        for (int nn = 0; nn < 2; ++nn) {
            int co = nn * 16 + l15;
            f32x4 v = acc[m][nn];
            s1[nn] += v.x + v.y + v.z + v.w;
            s2[nn] += v.x * v.x + v.y * v.y + v.z * v.z + v.w * v.w;
            if (co < 18) {
                int br = co < 9 ? 0 : 1;
                int k = co - br * 9;
                int plane = (br * 8 + b) * 9 + k;
                int px = px0 + m * 16 + kg * 4;
                *(f32x4*)&off_raw[(size_t)plane * HW + px] = v;
            }
        }
#pragma unroll
    for (int off = 16; off <= 32; off <<= 1)
#pragma unroll
        for (int nn = 0; nn < 2; ++nn) {
            s1[nn] += __shfl_xor(s1[nn], off);
            s2[nn] += __shfl_xor(s2[nn], off);
        }
    if (l < 16) {
        int idx = ((l15 * 8 + b) * 512 + tile) * 2;
        bnp[idx] = s1[0]; bnp[idx + 1] = s2[0];
        if (l15 < 2) {
            int idx2 = (((16 + l15) * 8 + b) * 512 + tile) * 2;
            bnp[idx2] = s1[1]; bnp[idx2 + 1] = s2[1];
        }
    }
}

__device__ inline void block_reduce2(float& s1, float& s2) {
    __shared__ float sh[4][2];
#pragma unroll
    for (int o = 32; o > 0; o >>= 1) {
        s1 += __shfl_down(s1, o);
        s2 += __shfl_down(s2, o);
    }
    int wid = threadIdx.x >> 6, lane = threadIdx.x & 63;
    if (lane == 0) { sh[wid][0] = s1; sh[wid][1] = s2; }
    __syncthreads();
    if (threadIdx.x == 0)
        for (int i = 1; i < 4; ++i) { s1 += sh[i][0]; s2 += sh[i][1]; }
}

__global__ __launch_bounds__(256) void bn_fin2(const float* __restrict__ bnp,
                                               float* __restrict__ bn_stat) {
    int c = blockIdx.x;
    float s1 = 0.f, s2 = 0.f;
    for (int i = threadIdx.x; i < 4096; i += 256) {
        s1 += bnp[(c * 4096 + i) * 2];
        s2 += bnp[(c * 4096 + i) * 2 + 1];
    }
    block_reduce2(s1, s2);
    if (threadIdx.x == 0) {
        const float N = 8.f * 16384.f;
        float m = s1 / N;
        float var = s2 / N - m * m;
        bn_stat[c * 2] = m;
        bn_stat[c * 2 + 1] = rsqrtf(var + 1e-5f);
    }
}

// ---------------- snake conv: f16-lerped A, 8 MFMA/iter ------------------------
// R15: MFMA linearity -> lerp A in f16 (af = a0*(1-f) + a1*f, pk_mul+pk_fma)
// and issue ONE MFMA per (m,nn) instead of two. Halves MFMA count (288->144
// per wave) and shortens each accumulator's chain. Everything else = R14.
__global__ __launch_bounds__(256) void snake9(const unsigned short* __restrict__ xt2,
                                              const unsigned short* __restrict__ wrh3,
                                              const float* __restrict__ cb0,
                                              const float* __restrict__ cb1,
                                              const float* __restrict__ off_raw,
                                              const float* __restrict__ bn_stat,
                                              const float* __restrict__ bng0,
                                              const float* __restrict__ bnb0,
                                              const float* __restrict__ bng1,
                                              const float* __restrict__ bnb1,
                                              float* __restrict__ out,
                                              float* __restrict__ gnp) {
    __shared__ __align__(16) unsigned char winbuf[BUFB];      // 29952
    __shared__ __align__(16) float fw_tab[4][9][32];          // 4608
    __shared__ int cell_tab[4][9][32];                        // 4608

    int n = blockIdx.x;
    int b = n & 7;
    int rest = n >> 3;
    int br = rest >> 7;
    int tile = rest & 127;
    int h0 = (tile >> 3) * 8;
    int w0 = (tile & 7) * 16;
    int t = threadIdx.x;
    int wv = t >> 6, l = t & 63;
    int l15 = l & 15, kg = l >> 4;
    int lp = l & 31;                   // own pixel (lanes 32-63 duplicate)

    int hrow = h0 + 2 * wv + (lp >> 4);
    int wcol = w0 + (lp & 15);
    int pxo = hrow * 128 + wcol;
    const float* bng = br ? bng1 : bng0;
    const float* bnb = br ? bnb1 : bnb0;

    f32x4 acc00 = (f32x4)(0.f), acc01 = (f32x4)(0.f), acc02 = (f32x4)(0.f), acc03 = (f32x4)(0.f);
    f32x4 acc10 = (f32x4)(0.f), acc11 = (f32x4)(0.f), acc12 = (f32x4)(0.f), acc13 = (f32x4)(0.f);

    // initial weight prefetch: (half=0, k=0)
    const unsigned short* wbase = wrh3 + (size_t)(br * 2) * WSLAB;
    half8 nb0 = *(const half8*)(wbase + 0 * 512 + l * 8);
    half8 nb1 = *(const half8*)(wbase + 1 * 512 + l * 8);
    half8 nb2 = *(const half8*)(wbase + 2 * 512 + l * 8);
    half8 nb3 = *(const half8*)(wbase + 3 * 512 + l * 8);

#pragma unroll 1
    for (int half = 0; half < 2; ++half) {
        if (half == 1) __syncthreads();          // all reads of prev window done

        // ---- stage this ci-half window (async, swizzled source g(c)=(c>>1)&3) ----
        {
            const unsigned short* plane = xt2 + (size_t)(b * 2 + half) * HW * 32;
#pragma unroll
            for (int it = 0; it < 8; ++it) {
                int d = it * 256 + wv * 64 + l;
                if (d < CHUNKS) {
                    int cell = d >> 2;
                    int ci8 = (d & 3) ^ ((cell >> 1) & 3);   // inverse swizzle on source
                    int s = cell / WIN_C;
                    int c = cell - s * WIN_C;
                    int row = min(max(h0 - 5 + s, 0), 127);
                    int col = min(max(w0 - 5 + c, 0), 127);
                    const unsigned short* src = plane + ((size_t)(row * 128 + col)) * 32 + ci8 * 8;
                    __builtin_amdgcn_global_load_lds(
                        (const __attribute__((address_space(1))) unsigned int*)src,
                        (__attribute__((address_space(3))) unsigned int*)(&winbuf[0] + (it * 256 + wv * 64) * 16),
                        16, 0, 0);
                }
            }
        }

        // ---- prologue (first half only): offsets -> LDS desc tables ----
        if (half == 0) {
            float tt[9];
#pragma unroll
            for (int k = 0; k < 9; ++k) {
                float raw = off_raw[(size_t)((br * 8 + b) * 9 + k) * HW + pxo];
                float mn = bn_stat[(br * 9 + k) * 2];
                float rs = bn_stat[(br * 9 + k) * 2 + 1];
                int ch = br ? k + 9 : k;
                tt[k] = tanhf((raw - mn) * rs * bng[ch] + bnb[ch]);
            }
            float cum[9];
            cum[4] = 0.f;
            cum[3] = tt[3]; cum[2] = tt[2] + cum[3]; cum[1] = tt[1] + cum[2]; cum[0] = tt[0] + cum[1];
            cum[5] = tt[5]; cum[6] = cum[5] + tt[6]; cum[7] = cum[6] + tt[7]; cum[8] = cum[7] + tt[8];
#pragma unroll
            for (int k = 0; k < 9; ++k) {
                int cell0, cell1; float fw;
                if (br == 0) {
                    int col = min(max(wcol + k - 4, 0), 127);
                    float yc = fminf(fmaxf((float)hrow + cum[k], 0.f), 127.f);
                    int y0 = (int)floorf(yc);
                    int y1 = min(y0 + 1, 127);
                    fw = yc - (float)y0;
                    int cs = col - (w0 - 5);
                    cell0 = (y0 - (h0 - 5)) * WIN_C + cs;
                    cell1 = (y1 - (h0 - 5)) * WIN_C + cs;
                } else {
                    int row = min(max(hrow + k - 4, 0), 127);
                    float xcf = fminf(fmaxf((float)wcol + cum[k], 0.f), 127.f);
                    int x0 = (int)floorf(xcf);
                    int x1 = min(x0 + 1, 127);
                    fw = xcf - (float)x0;
                    int rs = (row - (h0 - 5)) * WIN_C;
                    cell0 = rs + (x0 - (w0 - 5));
                    cell1 = rs + (x1 - (w0 - 5));
                }
                if (l < 32) {
                    cell_tab[wv][k][lp] = cell0 | (cell1 << 16);
                    fw_tab[wv][k][lp] = fw;
                }
            }
        }

        __syncthreads();   // staging + (half0) desc tables complete

        // preload k=0 cell pair
        int cm0 = cell_tab[wv][0][l15];
        int cm1 = cell_tab[wv][0][l15 + 16];

#pragma unroll 1
        for (int k = 0; k < 9; ++k) {
            // current weights = prefetched
            half8 cb0f = nb0, cb1f = nb1, cb2f = nb2, cb3f = nb3;

            // issue next-iteration weight prefetch (crosses half boundary)
            int kn2 = (k < 8) ? k + 1 : ((half == 0) ? 0 : 8);
            int hn2 = (k < 8) ? half : 1;
            const unsigned short* wn = wrh3 + (size_t)(br * 2 + hn2) * WSLAB
                                     + (size_t)(kn2 * 4) * 512 + l * 8;
            nb0 = *(const half8*)(wn + 0 * 512);
            nb1 = *(const half8*)(wn + 1 * 512);
            nb2 = *(const half8*)(wn + 2 * 512);
            nb3 = *(const half8*)(wn + 3 * 512);

            // next-k cell prefetch
            int knc = (k < 8) ? k + 1 : 8;
            int nc0 = cell_tab[wv][knc][l15];
            int nc1 = cell_tab[wv][knc][l15 + 16];

            float fw0 = fw_tab[wv][k][l15];
            float fw1 = fw_tab[wv][k][l15 + 16];
            half8 f0s = (half8)((_Float16)fw0);
            half8 f0c = (half8)((_Float16)(1.f - fw0));
            half8 f1s = (half8)((_Float16)fw1);
            half8 f1c = (half8)((_Float16)(1.f - fw1));

            int c00 = cm0 & 0xffff, c01 = ((unsigned)cm0) >> 16;
            int c10 = cm1 & 0xffff, c11 = ((unsigned)cm1) >> 16;
            int o00 = c00 * 64 + ((kg ^ ((c00 >> 1) & 3)) << 4);
            int o01 = c01 * 64 + ((kg ^ ((c01 >> 1) & 3)) << 4);
            int o10 = c10 * 64 + ((kg ^ ((c10 >> 1) & 3)) << 4);
            int o11 = c11 * 64 + ((kg ^ ((c11 >> 1) & 3)) << 4);

            half8 a00 = *(const half8*)(winbuf + o00);
            half8 a01 = *(const half8*)(winbuf + o01);
            half8 a10 = *(const half8*)(winbuf + o10);
            half8 a11 = *(const half8*)(winbuf + o11);
            // f16 lerp: ONE A-fragment per m (MFMA linearity) -> 8 MFMA/iter
            half8 af0 = a00 * f0c + a01 * f0s;
            half8 af1 = a10 * f1c + a11 * f1s;

            acc00 = __builtin_amdgcn_mfma_f32_16x16x32_f16(af0, cb0f, acc00, 0, 0, 0);
            acc01 = __builtin_amdgcn_mfma_f32_16x16x32_f16(af0, cb1f, acc01, 0, 0, 0);
            acc02 = __builtin_amdgcn_mfma_f32_16x16x32_f16(af0, cb2f, acc02, 0, 0, 0);
            acc03 = __builtin_amdgcn_mfma_f32_16x16x32_f16(af0, cb3f, acc03, 0, 0, 0);
            acc10 = __builtin_amdgcn_mfma_f32_16x16x32_f16(af1, cb0f, acc10, 0, 0, 0);
            acc11 = __builtin_amdgcn_mfma_f32_16x16x32_f16(af1, cb1f, acc11, 0, 0, 0);
            acc12 = __builtin_amdgcn_mfma_f32_16x16x32_f16(af1, cb2f, acc12, 0, 0, 0);
            acc13 = __builtin_amdgcn_mfma_f32_16x16x32_f16(af1, cb3f, acc13, 0, 0, 0);

            cm0 = nc0;
            cm1 = nc1;
        }
    }

    // epilogue: bias, store, GN partials
    f32x4 accA[2][4] = {{acc00, acc01, acc02, acc03}, {acc10, acc11, acc12, acc13}};
    const float* cb = br ? cb1 : cb0;
    float s1[4], s2[4];
#pragma unroll
    for (int nn = 0; nn < 4; ++nn) { s1[nn] = 0.f; s2[nn] = 0.f; }
#pragma unroll
    for (int m = 0; m < 2; ++m) {
        int hm = h0 + 2 * wv + m;
#pragma unroll
        for (int nn = 0; nn < 4; ++nn) {
            int co = nn * 16 + l15;
            float bias = cb[co];
            f32x4 v = accA[m][nn];
            f32x4 r;
            r.x = v.x + bias; r.y = v.y + bias; r.z = v.z + bias; r.w = v.w + bias;
            s1[nn] += r.x + r.y + r.z + r.w;
            s2[nn] += r.x * r.x + r.y * r.y + r.z * r.z + r.w * r.w;
            size_t base = ((size_t)(b * 128 + br * 64 + co) << 14) + hm * 128 + w0 + kg * 4;
            *(f32x4*)&out[base] = r;
        }
    }
#pragma unroll
    for (int off = 16; off <= 32; off <<= 1)
#pragma unroll
        for (int nn = 0; nn < 4; ++nn) {
            s1[nn] += __shfl_xor(s1[nn], off);
            s2[nn] += __shfl_xor(s2[nn], off);
        }
#pragma unroll
    for (int off = 1; off <= 2; off <<= 1)
#pragma unroll
        for (int nn = 0; nn < 4; ++nn) {
            s1[nn] += __shfl_xor(s1[nn], off);
            s2[nn] += __shfl_xor(s2[nn], off);
        }
    if ((l & 0x33) == 0) {             // lanes 0,4,8,12
#pragma unroll
        for (int nn = 0; nn < 4; ++nn) {
            int g = nn * 4 + (l >> 2);
            size_t gi = ((size_t)((br * 8 + b) * 512 + tile * 4 + wv)) * 32 + g * 2;
            gnp[gi] = s1[nn];
            gnp[gi + 1] = s2[nn];
        }
    }
}

__global__ __launch_bounds__(256) void gn_reduce(const float* __restrict__ gnp,
                                                 float* __restrict__ gn_stat) {
    int sid = blockIdx.x;              // (br*8+b)*16+g
    int bb = sid >> 4;
    int g = sid & 15;
    float s1 = 0.f, s2 = 0.f;
    int t = threadIdx.x;
#pragma unroll
    for (int j = 0; j < 2; ++j) {
        size_t gi = ((size_t)(bb * 512 + t * 2 + j)) * 32 + g * 2;
        s1 += gnp[gi];
        s2 += gnp[gi + 1];
    }
    block_reduce2(s1, s2);
    if (t == 0) {
        const float N = 4.f * 16384.f;
        float m = s1 / N;
        float var = s2 / N - m * m;
        gn_stat[sid * 2] = m;
        gn_stat[sid * 2 + 1] = rsqrtf(var + 1e-5f);
    }
}

__global__ __launch_bounds__(256) void gn_apply(float* __restrict__ out,
                                                const float* __restrict__ gn_stat,
                                                const float* __restrict__ g0,
                                                const float* __restrict__ b0,
                                                const float* __restrict__ g1,
                                                const float* __restrict__ b1) {
    int i = blockIdx.x * 256 + threadIdx.x;
    size_t base = (size_t)i * 4;
    int c = (int)((base >> 14) & 127);
    int b = (int)(base >> 21);
    int br = c >> 6;
    int co = c & 63;
    int sid = (br * 8 + b) * 16 + (co >> 2);
    float m = gn_stat[sid * 2];
    float rs = gn_stat[sid * 2 + 1];
    const float* gg = br ? g1 : g0;
    const float* bb = br ? b1 : b0;
    float ga = gg[co] * rs, be = bb[co] - m * gg[co] * rs;
    f32x4 v = *(f32x4*)&out[base];
    f32x4 r;
    r.x = fmaxf(fmaf(v.x, ga, be), 0.f);
    r.y = fmaxf(fmaf(v.y, ga, be), 0.f);
    r.z = fmaxf(fmaf(v.z, ga, be), 0.f);
    r.w = fmaxf(fmaf(v.w, ga, be), 0.f);
    *(f32x4*)&out[base] = r;
}

extern "C" void kernel_launch(void* const* d_in, const int* in_sizes, int n_in,
                              void* d_out, int out_size, void* d_ws, size_t ws_size,
                              hipStream_t stream) {
    const float* x       = (const float*)d_in[0];
    const float* off_w0  = (const float*)d_in[1];
    const float* bn_g0   = (const float*)d_in[3];
    const float* bn_b0   = (const float*)d_in[4];
    const float* conv_w0 = (const float*)d_in[5];
    const float* conv_b0 = (const float*)d_in[6];
    const float* gn_g0   = (const float*)d_in[7];
    const float* gn_b0   = (const float*)d_in[8];
    const float* off_w1  = (const float*)d_in[9];
    const float* bn_g1   = (const float*)d_in[11];
    const float* bn_b1   = (const float*)d_in[12];
    const float* conv_w1 = (const float*)d_in[13];
    const float* conv_b1 = (const float*)d_in[14];
    const float* gn_g1   = (const float*)d_in[15];
    const float* gn_b1   = (const float*)d_in[16];

    char* ws = (char*)d_ws;
    unsigned short* xt2  = (unsigned short*)(ws + XT_OFF);
    unsigned short* wrh3 = (unsigned short*)(ws + WRH_OFF);
    unsigned short* woh2 = (unsigned short*)(ws + WOH_OFF);
    float* off_raw = (float*)(ws + RAW_OFF);
    float* bn_stat = (float*)(ws + BNS_OFF);
    float* gnp     = (float*)(ws + GNP_OFF);   // also bnp (early phase, stream-ordered)
    float* gn_stat = (float*)(ws + GNS_OFF);
    float* out = (float*)d_out;

    cvt_x<<<512, 256, 0, stream>>>(x, xt2);
    repack_all<<<360, 256, 0, stream>>>(conv_w0, conv_w1, off_w0, off_w1, wrh3, woh2);
    off_mfma<<<1024, 256, 0, stream>>>(xt2, woh2, off_raw, gnp);
    bn_fin2<<<18, 256, 0, stream>>>(gnp, bn_stat);
    snake9<<<2048, 256, 0, stream>>>(xt2, wrh3, conv_b0, conv_b1, off_raw, bn_stat,
                                     bn_g0, bn_b0, bn_g1, bn_b1, out, gnp);
    gn_reduce<<<256, 256, 0, stream>>>(gnp, gn_stat);
    gn_apply<<<16384, 256, 0, stream>>>(out, gn_stat, gn_g0, gn_b0, gn_g1, gn_b1);
}

// Round 17
// 105.744 us; speedup vs baseline: 1.8080x; 1.0490x over previous
//
#include <hip/hip_runtime.h>
#include <hip/hip_bf16.h>

#define HW 16384
#define NB 8
#define CIN 64

// snake tile geometry
#define WIN_R 18
#define WIN_C 26
#define CELLS (WIN_R * WIN_C)     // 468
#define CHUNKS (CELLS * 4)        // 1872 x 16B per ci-half
#define BUFB (CELLS * 64)         // 29952 bytes (one ci-half window)
#define WSLAB 18432               // shorts per (br,half) weight slab

typedef short short8 __attribute__((ext_vector_type(8)));
typedef short short4v __attribute__((ext_vector_type(4)));
typedef float f32x4 __attribute__((ext_vector_type(4)));
typedef _Float16 half8 __attribute__((ext_vector_type(8)));

// ---------------- ws layout (BYTE offsets) ----------------
#define XT_OFF   0
#define WRH_OFF  16777216
#define WOH_OFF  16924672
#define RAW_OFF  17000448
#define BNS_OFF  26437632
#define GNP_OFF  26439168
#define GNS_OFF  27487744
#define CVOUT_OFF 27489792
#define WS_NEED_F16 (27489792ull + 33554432ull)   // cvout: 16.7M f16

__device__ inline unsigned short f2h(float v) {
    _Float16 h = (_Float16)v;
    unsigned short u; __builtin_memcpy(&u, &h, 2);
    return u;
}
__device__ inline float h2f(unsigned short u) {
    _Float16 h; __builtin_memcpy(&h, &u, 2);
    return (float)h;
}

// x [b][ci][px] f32  ->  xt2 [b][half][px][32ci] f16.  R16: pad 72->74 (8-way conflict fix)
__global__ __launch_bounds__(256) void cvt_x(const float* __restrict__ x,
                                             unsigned short* __restrict__ xt2) {
    int blk = blockIdx.x;              // 512 = 8b * 64 tiles(256px)
    int b = blk >> 6;
    int px0 = (blk & 63) * 256;
    int t = threadIdx.x;
    __shared__ unsigned short lds[256][74];
    const float* xb = x + (size_t)b * CIN * HW + px0;
    for (int ci = 0; ci < 64; ++ci)
        lds[t][ci] = f2h(xb[ci * HW + t]);
    __syncthreads();
    int wv = t >> 6, l = t & 63;
    int chunk = l & 7;                 // 8 chunks of 8 ci
    int half = chunk >> 2, ci8 = chunk & 3;
    for (int it = 0; it < 8; ++it) {
        int row = it * 32 + wv * 8 + (l >> 3);
        short8 v = *(const short8*)&lds[row][chunk * 8];
        unsigned short* dst = xt2 + ((size_t)(b * 2 + half) * HW + px0 + row) * 32 + ci8 * 8;
        *(short8*)dst = v;
    }
}

// merged weight repack (f16), both lane-linear
__global__ __launch_bounds__(256) void repack_all(const float* __restrict__ cw0,
                                                  const float* __restrict__ cw1,
                                                  const float* __restrict__ ow0,
                                                  const float* __restrict__ ow1,
                                                  unsigned short* __restrict__ wrh3,
                                                  unsigned short* __restrict__ woh2) {
    int i = blockIdx.x * 256 + threadIdx.x;
    if (i < 2 * 2 * WSLAB) {
        int slab = i / WSLAB;          // br*2 + half
        int br = slab >> 1, chalf = slab & 1;
        int rem = i - slab * WSLAB;
        int e = rem & 7;
        int lane = (rem >> 3) & 63;
        int nnk = rem >> 9;
        int nn = nnk & 3, k = nnk >> 2;
        int co = nn * 16 + (lane & 15);
        int ci = chalf * 32 + (lane >> 4) * 8 + e;
        const float* w = br ? cw1 : cw0;
        wrh3[i] = f2h(w[(co * 64 + ci) * 9 + k]);
    }
    int j = i - 2 * 2 * WSLAB;
    if (j >= 0 && j < 18 * 2 * 64 * 8) {
        int e = j & 7;
        int lane = (j >> 3) & 63;
        int nn = (j >> 9) & 1;
        int s = j >> 10;               // tap*2 + half
        int tap = s >> 1, chalf = s & 1;
        int co = nn * 16 + (lane & 15);
        int ci = chalf * 32 + (lane >> 4) * 8 + e;
        float v = 0.f;
        if (co < 9)       v = ow0[(co * 64 + ci) * 9 + tap];
        else if (co < 18) v = ow1[(co * 64 + ci) * 9 + tap];
        woh2[j] = f2h(v);
    }
}

// offset 3x3 conv MFMA (f16) + fused BN partials; weights staged to LDS.
__global__ __launch_bounds__(256, 4) void off_mfma(const unsigned short* __restrict__ xt2,
                                                   const unsigned short* __restrict__ woh2,
                                                   float* __restrict__ off_raw,
                                                   float* __restrict__ bnp) {
    __shared__ __align__(16) unsigned char wlds[36864];

    int b = blockIdx.x & 7;
    int tgrp = blockIdx.x >> 3;
    int t = threadIdx.x;
    int wid = t >> 6, l = t & 63;
    int tile = tgrp * 4 + wid;
    int l15 = l & 15, kg = l >> 4;
    int px0 = tile * 32;
    int h = px0 >> 7;
    int w0 = px0 & 127;

#pragma unroll
    for (int it = 0; it < 9; ++it) {
        int d = it * 256 + t;
        __builtin_amdgcn_global_load_lds(
            (const __attribute__((address_space(1))) unsigned int*)(woh2 + d * 8),
            (__attribute__((address_space(3))) unsigned int*)(&wlds[0] + (it * 256 + wid * 64) * 16),
            16, 0, 0);
    }
    __syncthreads();

    f32x4 acc[2][2];
#pragma unroll
    for (int m = 0; m < 2; ++m)
#pragma unroll
        for (int nn = 0; nn < 2; ++nn) acc[m][nn] = (f32x4)(0.f);

#pragma unroll
    for (int s = 0; s < 18; ++s) {
        const int tap = s >> 1, half = s & 1;
        const int dy = tap / 3 - 1, dx = tap % 3 - 1;
        const unsigned short* plane = xt2 + (size_t)(b * 2 + half) * HW * 32;
        int y = h + dy;
        bool yok = (unsigned)y < 128u;
        int yc = min(max(y, 0), 127);
        half8 af[2];
#pragma unroll
        for (int m = 0; m < 2; ++m) {
            int xx = w0 + m * 16 + l15 + dx;
            bool ok = yok && ((unsigned)xx < 128u);
            int xc = min(max(xx, 0), 127);
            int o = yc * 128 + xc;
            half8 a = *(const half8*)&plane[(size_t)o * 32 + kg * 8];
            if (!ok) a = (half8)((_Float16)0.f);
            af[m] = a;
        }
        half8 bf[2];
#pragma unroll
        for (int nn = 0; nn < 2; ++nn)
            bf[nn] = *(const half8*)(wlds + ((s * 2 + nn) * 64 + l) * 16);
#pragma unroll
        for (int m = 0; m < 2; ++m)
#pragma unroll
            for (int nn = 0; nn < 2; ++nn)
                acc[m][nn] = __builtin_amdgcn_mfma_f32_16x16x32_f16(af[m], bf[nn], acc[m][nn], 0, 0, 0);
    }

    float s1[2] = {0.f, 0.f}, s2[2] = {0.f, 0.f};
#pragma unroll
    for (int m = 0; m < 2; ++m)
#pragma unroll
        for (int nn = 0; nn < 2; ++nn) {
            int co = nn * 16 + l15;
            f32x4 v = acc[m][nn];
            s1[nn] += v.x + v.y + v.z + v.w;
            s2[nn] += v.x * v.x + v.y * v.y + v.z * v.z + v.w * v.w;
            if (co < 18) {
                int br = co < 9 ? 0 : 1;
                int k = co - br * 9;
                int plane = (br * 8 + b) * 9 + k;
                int px = px0 + m * 16 + kg * 4;
                *(f32x4*)&off_raw[(size_t)plane * HW + px] = v;
            }
        }
#pragma unroll
    for (int off = 16; off <= 32; off <<= 1)
#pragma unroll
        for (int nn = 0; nn < 2; ++nn) {
            s1[nn] += __shfl_xor(s1[nn], off);
            s2[nn] += __shfl_xor(s2[nn], off);
        }
    if (l < 16) {
        int idx = ((l15 * 8 + b) * 512 + tile) * 2;
        bnp[idx] = s1[0]; bnp[idx + 1] = s2[0];
        if (l15 < 2) {
            int idx2 = (((16 + l15) * 8 + b) * 512 + tile) * 2;
            bnp[idx2] = s1[1]; bnp[idx2 + 1] = s2[1];
        }
    }
}

__device__ inline void block_reduce2(float& s1, float& s2) {
    __shared__ float sh[4][2];
#pragma unroll
    for (int o = 32; o > 0; o >>= 1) {
        s1 += __shfl_down(s1, o);
        s2 += __shfl_down(s2, o);
    }
    int wid = threadIdx.x >> 6, lane = threadIdx.x & 63;
    if (lane == 0) { sh[wid][0] = s1; sh[wid][1] = s2; }
    __syncthreads();
    if (threadIdx.x == 0)
        for (int i = 1; i < 4; ++i) { s1 += sh[i][0]; s2 += sh[i][1]; }
}

__global__ __launch_bounds__(256) void bn_fin2(const float* __restrict__ bnp,
                                               float* __restrict__ bn_stat) {
    int c = blockIdx.x;
    float s1 = 0.f, s2 = 0.f;
    for (int i = threadIdx.x; i < 4096; i += 256) {
        s1 += bnp[(c * 4096 + i) * 2];
        s2 += bnp[(c * 4096 + i) * 2 + 1];
    }
    block_reduce2(s1, s2);
    if (threadIdx.x == 0) {
        const float N = 8.f * 16384.f;
        float m = s1 / N;
        float var = s2 / N - m * m;
        bn_stat[c * 2] = m;
        bn_stat[c * 2 + 1] = rsqrtf(var + 1e-5f);
    }
}

// ---------------- snake conv (R15 structure); R16: optional f16 conv-out ------
template <bool F16OUT>
__global__ __launch_bounds__(256) void snake9(const unsigned short* __restrict__ xt2,
                                              const unsigned short* __restrict__ wrh3,
                                              const float* __restrict__ cb0,
                                              const float* __restrict__ cb1,
                                              const float* __restrict__ off_raw,
                                              const float* __restrict__ bn_stat,
                                              const float* __restrict__ bng0,
                                              const float* __restrict__ bnb0,
                                              const float* __restrict__ bng1,
                                              const float* __restrict__ bnb1,
                                              float* __restrict__ out,
                                              unsigned short* __restrict__ cvout,
                                              float* __restrict__ gnp) {
    __shared__ __align__(16) unsigned char winbuf[BUFB];
    __shared__ __align__(16) float fw_tab[4][9][32];
    __shared__ int cell_tab[4][9][32];

    int n = blockIdx.x;
    int b = n & 7;
    int rest = n >> 3;
    int br = rest >> 7;
    int tile = rest & 127;
    int h0 = (tile >> 3) * 8;
    int w0 = (tile & 7) * 16;
    int t = threadIdx.x;
    int wv = t >> 6, l = t & 63;
    int l15 = l & 15, kg = l >> 4;
    int lp = l & 31;

    int hrow = h0 + 2 * wv + (lp >> 4);
    int wcol = w0 + (lp & 15);
    int pxo = hrow * 128 + wcol;
    const float* bng = br ? bng1 : bng0;
    const float* bnb = br ? bnb1 : bnb0;

    f32x4 acc00 = (f32x4)(0.f), acc01 = (f32x4)(0.f), acc02 = (f32x4)(0.f), acc03 = (f32x4)(0.f);
    f32x4 acc10 = (f32x4)(0.f), acc11 = (f32x4)(0.f), acc12 = (f32x4)(0.f), acc13 = (f32x4)(0.f);

    const unsigned short* wbase = wrh3 + (size_t)(br * 2) * WSLAB;
    half8 nb0 = *(const half8*)(wbase + 0 * 512 + l * 8);
    half8 nb1 = *(const half8*)(wbase + 1 * 512 + l * 8);
    half8 nb2 = *(const half8*)(wbase + 2 * 512 + l * 8);
    half8 nb3 = *(const half8*)(wbase + 3 * 512 + l * 8);

#pragma unroll 1
    for (int half = 0; half < 2; ++half) {
        if (half == 1) __syncthreads();

        {
            const unsigned short* plane = xt2 + (size_t)(b * 2 + half) * HW * 32;
#pragma unroll
            for (int it = 0; it < 8; ++it) {
                int d = it * 256 + wv * 64 + l;
                if (d < CHUNKS) {
                    int cell = d >> 2;
                    int ci8 = (d & 3) ^ ((cell >> 1) & 3);
                    int s = cell / WIN_C;
                    int c = cell - s * WIN_C;
                    int row = min(max(h0 - 5 + s, 0), 127);
                    int col = min(max(w0 - 5 + c, 0), 127);
                    const unsigned short* src = plane + ((size_t)(row * 128 + col)) * 32 + ci8 * 8;
                    __builtin_amdgcn_global_load_lds(
                        (const __attribute__((address_space(1))) unsigned int*)src,
                        (__attribute__((address_space(3))) unsigned int*)(&winbuf[0] + (it * 256 + wv * 64) * 16),
                        16, 0, 0);
                }
            }
        }

        if (half == 0) {
            float tt[9];
#pragma unroll
            for (int k = 0; k < 9; ++k) {
                float raw = off_raw[(size_t)((br * 8 + b) * 9 + k) * HW + pxo];
                float mn = bn_stat[(br * 9 + k) * 2];
                float rs = bn_stat[(br * 9 + k) * 2 + 1];
                int ch = br ? k + 9 : k;
                tt[k] = tanhf((raw - mn) * rs * bng[ch] + bnb[ch]);
            }
            float cum[9];
            cum[4] = 0.f;
            cum[3] = tt[3]; cum[2] = tt[2] + cum[3]; cum[1] = tt[1] + cum[2]; cum[0] = tt[0] + cum[1];
            cum[5] = tt[5]; cum[6] = cum[5] + tt[6]; cum[7] = cum[6] + tt[7]; cum[8] = cum[7] + tt[8];
#pragma unroll
            for (int k = 0; k < 9; ++k) {
                int cell0, cell1; float fw;
                if (br == 0) {
                    int col = min(max(wcol + k - 4, 0), 127);
                    float yc = fminf(fmaxf((float)hrow + cum[k], 0.f), 127.f);
                    int y0 = (int)floorf(yc);
                    int y1 = min(y0 + 1, 127);
                    fw = yc - (float)y0;
                    int cs = col - (w0 - 5);
                    cell0 = (y0 - (h0 - 5)) * WIN_C + cs;
                    cell1 = (y1 - (h0 - 5)) * WIN_C + cs;
                } else {
                    int row = min(max(hrow + k - 4, 0), 127);
                    float xcf = fminf(fmaxf((float)wcol + cum[k], 0.f), 127.f);
                    int x0 = (int)floorf(xcf);
                    int x1 = min(x0 + 1, 127);
                    fw = xcf - (float)x0;
                    int rs = (row - (h0 - 5)) * WIN_C;
                    cell0 = rs + (x0 - (w0 - 5));
                    cell1 = rs + (x1 - (w0 - 5));
                }
                if (l < 32) {
                    cell_tab[wv][k][lp] = cell0 | (cell1 << 16);
                    fw_tab[wv][k][lp] = fw;
                }
            }
        }

        __syncthreads();

        int cm0 = cell_tab[wv][0][l15];
        int cm1 = cell_tab[wv][0][l15 + 16];

#pragma unroll 1
        for (int k = 0; k < 9; ++k) {
            half8 cb0f = nb0, cb1f = nb1, cb2f = nb2, cb3f = nb3;

            int kn2 = (k < 8) ? k + 1 : ((half == 0) ? 0 : 8);
            int hn2 = (k < 8) ? half : 1;
            const unsigned short* wn = wrh3 + (size_t)(br * 2 + hn2) * WSLAB
                                     + (size_t)(kn2 * 4) * 512 + l * 8;
            nb0 = *(const half8*)(wn + 0 * 512);
            nb1 = *(const half8*)(wn + 1 * 512);
            nb2 = *(const half8*)(wn + 2 * 512);
            nb3 = *(const half8*)(wn + 3 * 512);

            int knc = (k < 8) ? k + 1 : 8;
            int nc0 = cell_tab[wv][knc][l15];
            int nc1 = cell_tab[wv][knc][l15 + 16];

            float fw0 = fw_tab[wv][k][l15];
            float fw1 = fw_tab[wv][k][l15 + 16];
            half8 f0s = (half8)((_Float16)fw0);
            half8 f0c = (half8)((_Float16)(1.f - fw0));
            half8 f1s = (half8)((_Float16)fw1);
            half8 f1c = (half8)((_Float16)(1.f - fw1));

            int c00 = cm0 & 0xffff, c01 = ((unsigned)cm0) >> 16;
            int c10 = cm1 & 0xffff, c11 = ((unsigned)cm1) >> 16;
            int o00 = c00 * 64 + ((kg ^ ((c00 >> 1) & 3)) << 4);
            int o01 = c01 * 64 + ((kg ^ ((c01 >> 1) & 3)) << 4);
            int o10 = c10 * 64 + ((kg ^ ((c10 >> 1) & 3)) << 4);
            int o11 = c11 * 64 + ((kg ^ ((c11 >> 1) & 3)) << 4);

            half8 a00 = *(const half8*)(winbuf + o00);
            half8 a01 = *(const half8*)(winbuf + o01);
            half8 a10 = *(const half8*)(winbuf + o10);
            half8 a11 = *(const half8*)(winbuf + o11);
            half8 af0 = a00 * f0c + a01 * f0s;
            half8 af1 = a10 * f1c + a11 * f1s;

            acc00 = __builtin_amdgcn_mfma_f32_16x16x32_f16(af0, cb0f, acc00, 0, 0, 0);
            acc01 = __builtin_amdgcn_mfma_f32_16x16x32_f16(af0, cb1f, acc01, 0, 0, 0);
            acc02 = __builtin_amdgcn_mfma_f32_16x16x32_f16(af0, cb2f, acc02, 0, 0, 0);
            acc03 = __builtin_amdgcn_mfma_f32_16x16x32_f16(af0, cb3f, acc03, 0, 0, 0);
            acc10 = __builtin_amdgcn_mfma_f32_16x16x32_f16(af1, cb0f, acc10, 0, 0, 0);
            acc11 = __builtin_amdgcn_mfma_f32_16x16x32_f16(af1, cb1f, acc11, 0, 0, 0);
            acc12 = __builtin_amdgcn_mfma_f32_16x16x32_f16(af1, cb2f, acc12, 0, 0, 0);
            acc13 = __builtin_amdgcn_mfma_f32_16x16x32_f16(af1, cb3f, acc13, 0, 0, 0);

            cm0 = nc0;
            cm1 = nc1;
        }
    }

    // epilogue: bias, store (f32 or f16), GN partials (always from f32)
    f32x4 accA[2][4] = {{acc00, acc01, acc02, acc03}, {acc10, acc11, acc12, acc13}};
    const float* cb = br ? cb1 : cb0;
    float s1[4], s2[4];
#pragma unroll
    for (int nn = 0; nn < 4; ++nn) { s1[nn] = 0.f; s2[nn] = 0.f; }
#pragma unroll
    for (int m = 0; m < 2; ++m) {
        int hm = h0 + 2 * wv + m;
#pragma unroll
        for (int nn = 0; nn < 4; ++nn) {
            int co = nn * 16 + l15;
            float bias = cb[co];
            f32x4 v = accA[m][nn];
            f32x4 r;
            r.x = v.x + bias; r.y = v.y + bias; r.z = v.z + bias; r.w = v.w + bias;
            s1[nn] += r.x + r.y + r.z + r.w;
            s2[nn] += r.x * r.x + r.y * r.y + r.z * r.z + r.w * r.w;
            size_t base = ((size_t)(b * 128 + br * 64 + co) << 14) + hm * 128 + w0 + kg * 4;
            if (F16OUT) {
                short4v p;
                p[0] = (short)f2h(r.x); p[1] = (short)f2h(r.y);
                p[2] = (short)f2h(r.z); p[3] = (short)f2h(r.w);
                *(short4v*)&cvout[base] = p;
            } else {
                *(f32x4*)&out[base] = r;
            }
        }
    }
#pragma unroll
    for (int off = 16; off <= 32; off <<= 1)
#pragma unroll
        for (int nn = 0; nn < 4; ++nn) {
            s1[nn] += __shfl_xor(s1[nn], off);
            s2[nn] += __shfl_xor(s2[nn], off);
        }
#pragma unroll
    for (int off = 1; off <= 2; off <<= 1)
#pragma unroll
        for (int nn = 0; nn < 4; ++nn) {
            s1[nn] += __shfl_xor(s1[nn], off);
            s2[nn] += __shfl_xor(s2[nn], off);
        }
    if ((l & 0x33) == 0) {
#pragma unroll
        for (int nn = 0; nn < 4; ++nn) {
            int g = nn * 4 + (l >> 2);
            size_t gi = ((size_t)((br * 8 + b) * 512 + tile * 4 + wv)) * 32 + g * 2;
            gnp[gi] = s1[nn];
            gnp[gi + 1] = s2[nn];
        }
    }
}

__global__ __launch_bounds__(256) void gn_reduce(const float* __restrict__ gnp,
                                                 float* __restrict__ gn_stat) {
    int sid = blockIdx.x;
    int bb = sid >> 4;
    int g = sid & 15;
    float s1 = 0.f, s2 = 0.f;
    int t = threadIdx.x;
#pragma unroll
    for (int j = 0; j < 2; ++j) {
        size_t gi = ((size_t)(bb * 512 + t * 2 + j)) * 32 + g * 2;
        s1 += gnp[gi];
        s2 += gnp[gi + 1];
    }
    block_reduce2(s1, s2);
    if (t == 0) {
        const float N = 4.f * 16384.f;
        float m = s1 / N;
        float var = s2 / N - m * m;
        gn_stat[sid * 2] = m;
        gn_stat[sid * 2 + 1] = rsqrtf(var + 1e-5f);
    }
}

template <bool F16IN>
__global__ __launch_bounds__(256) void gn_apply(float* __restrict__ out,
                                                const unsigned short* __restrict__ cvout,
                                                const float* __restrict__ gn_stat,
                                                const float* __restrict__ g0,
                                                const float* __restrict__ b0,
                                                const float* __restrict__ g1,
                                                const float* __restrict__ b1) {
    int i = blockIdx.x * 256 + threadIdx.x;
    size_t base = (size_t)i * 4;
    int c = (int)((base >> 14) & 127);
    int b = (int)(base >> 21);
    int br = c >> 6;
    int co = c & 63;
    int sid = (br * 8 + b) * 16 + (co >> 2);
    float m = gn_stat[sid * 2];
    float rs = gn_stat[sid * 2 + 1];
    const float* gg = br ? g1 : g0;
    const float* bb = br ? b1 : b0;
    float ga = gg[co] * rs, be = bb[co] - m * gg[co] * rs;
    f32x4 v;
    if (F16IN) {
        short4v p = *(const short4v*)&cvout[base];
        v.x = h2f((unsigned short)p[0]); v.y = h2f((unsigned short)p[1]);
        v.z = h2f((unsigned short)p[2]); v.w = h2f((unsigned short)p[3]);
    } else {
        v = *(f32x4*)&out[base];
    }
    f32x4 r;
    r.x = fmaxf(fmaf(v.x, ga, be), 0.f);
    r.y = fmaxf(fmaf(v.y, ga, be), 0.f);
    r.z = fmaxf(fmaf(v.z, ga, be), 0.f);
    r.w = fmaxf(fmaf(v.w, ga, be), 0.f);
    *(f32x4*)&out[base] = r;
}

extern "C" void kernel_launch(void* const* d_in, const int* in_sizes, int n_in,
                              void* d_out, int out_size, void* d_ws, size_t ws_size,
                              hipStream_t stream) {
    const float* x       = (const float*)d_in[0];
    const float* off_w0  = (const float*)d_in[1];
    const float* bn_g0   = (const float*)d_in[3];
    const float* bn_b0   = (const float*)d_in[4];
    const float* conv_w0 = (const float*)d_in[5];
    const float* conv_b0 = (const float*)d_in[6];
    const float* gn_g0   = (const float*)d_in[7];
    const float* gn_b0   = (const float*)d_in[8];
    const float* off_w1  = (const float*)d_in[9];
    const float* bn_g1   = (const float*)d_in[11];
    const float* bn_b1   = (const float*)d_in[12];
    const float* conv_w1 = (const float*)d_in[13];
    const float* conv_b1 = (const float*)d_in[14];
    const float* gn_g1   = (const float*)d_in[15];
    const float* gn_b1   = (const float*)d_in[16];

    char* ws = (char*)d_ws;
    unsigned short* xt2   = (unsigned short*)(ws + XT_OFF);
    unsigned short* wrh3  = (unsigned short*)(ws + WRH_OFF);
    unsigned short* woh2  = (unsigned short*)(ws + WOH_OFF);
    float* off_raw = (float*)(ws + RAW_OFF);
    float* bn_stat = (float*)(ws + BNS_OFF);
    float* gnp     = (float*)(ws + GNP_OFF);
    float* gn_stat = (float*)(ws + GNS_OFF);
    unsigned short* cvout = (unsigned short*)(ws + CVOUT_OFF);
    float* out = (float*)d_out;

    bool f16path = (ws_size >= WS_NEED_F16);

    cvt_x<<<512, 256, 0, stream>>>(x, xt2);
    repack_all<<<360, 256, 0, stream>>>(conv_w0, conv_w1, off_w0, off_w1, wrh3, woh2);
    off_mfma<<<1024, 256, 0, stream>>>(xt2, woh2, off_raw, gnp);
    bn_fin2<<<18, 256, 0, stream>>>(gnp, bn_stat);
    if (f16path) {
        snake9<true><<<2048, 256, 0, stream>>>(xt2, wrh3, conv_b0, conv_b1, off_raw, bn_stat,
                                               bn_g0, bn_b0, bn_g1, bn_b1, out, cvout, gnp);
        gn_reduce<<<256, 256, 0, stream>>>(gnp, gn_stat);
        gn_apply<true><<<16384, 256, 0, stream>>>(out, cvout, gn_stat, gn_g0, gn_b0, gn_g1, gn_b1);
    } else {
        snake9<false><<<2048, 256, 0, stream>>>(xt2, wrh3, conv_b0, conv_b1, off_raw, bn_stat,
                                                bn_g0, bn_b0, bn_g1, bn_b1, out, cvout, gnp);
        gn_reduce<<<256, 256, 0, stream>>>(gnp, gn_stat);
        gn_apply<false><<<16384, 256, 0, stream>>>(out, cvout, gn_stat, gn_g0, gn_b0, gn_g1, gn_b1);
    }
}